// Round 9
// baseline (468.886 us; speedup 1.0000x reference)
//
#include <hip/hip_runtime.h>
#include <cstddef>

#define TPB 256

typedef __attribute__((ext_vector_type(8))) short short8;
typedef __attribute__((ext_vector_type(4))) float f32x4;

__device__ inline unsigned short f2bf(float f) {
    unsigned int u = __builtin_bit_cast(unsigned int, f);
    u += 0x7fffu + ((u >> 16) & 1u);
    return (unsigned short)(u >> 16);
}
__device__ inline float bf2f(unsigned short h) {
    unsigned int u = ((unsigned int)h) << 16;
    return __builtin_bit_cast(float, u);
}

struct TapOffs { int o[9]; };

// ---------------------------------------------------------------------------
// 3x3 conv GEMM: block = 64 px x 64 n, 4 waves m-split. A direct from global
// (channels-last, pad ring valid). B staged per-tap in LDS (fragment order,
// lane*16B conflict-free), double-buffered. (unchanged from R8)
// ---------------------------------------------------------------------------
template<int CHUNKS>   // input channels = CHUNKS*64
__global__ __launch_bounds__(TPB) void k_conv3f(
    const unsigned short* __restrict__ A0, const unsigned short* __restrict__ Wf,
    const float* __restrict__ bias, unsigned short* __restrict__ O0,
    int AP, int tilesX, int OMS, int OP, int NTtot)
{
    constexpr int Cs  = CHUNKS * 64;
    constexpr int KC2 = CHUNKS * 2;
    __shared__ unsigned short Bs[2][CHUNKS * 4096];

    int lane = threadIdx.x & 63, wave = threadIdx.x >> 6;
    int ml = lane & 15, kq = lane >> 4;
    int nb = blockIdx.y;
    int tileX = blockIdx.x % tilesX, gy = blockIdx.x / tilesX;
    int gx0 = tileX * 64 + wave * 16;

    const unsigned short* Abase = A0 + (size_t)(gy - 1) * AP
                                     + (size_t)(gx0 + ml - 1) * Cs + kq * 8;

    f32x4 acc[4];
    #pragma unroll
    for (int nt = 0; nt < 4; ++nt) acc[nt] = (f32x4){0.f, 0.f, 0.f, 0.f};

    auto stageB = [&](int tap, int buf) {
        unsigned short* bd = Bs[buf];
        #pragma unroll
        for (int it = 0; it < CHUNKS * 2; ++it) {
            int u = threadIdx.x + it * TPB;
            int e = u * 8;
            int ch = e >> 12;
            int rem = e & 4095;
            int q = rem >> 11;
            int rem2 = rem & 2047;
            int ntg = rem2 >> 9;
            int r = rem2 & 511;
            const unsigned short* src = Wf
                + ((size_t)(tap * KC2 + ch * 2 + q) * NTtot + nb * 4 + ntg) * 512 + r;
            *(int4*)&bd[e] = *(const int4*)src;
        }
    };

    stageB(0, 0);
    __syncthreads();
    #pragma unroll
    for (int tap = 0; tap < 9; ++tap) {
        if (tap < 8) stageB(tap + 1, (tap + 1) & 1);
        int ky = tap / 3, kx = tap - (tap / 3) * 3;
        const unsigned short* Ar = Abase + (size_t)ky * AP + kx * Cs;
        const unsigned short* Bb = &Bs[tap & 1][lane * 8];
        #pragma unroll
        for (int ch = 0; ch < CHUNKS; ++ch) {
            #pragma unroll
            for (int q = 0; q < 2; ++q) {
                short8 b[4];
                #pragma unroll
                for (int nt = 0; nt < 4; ++nt)
                    b[nt] = *(const short8*)(Bb + ch * 4096 + q * 2048 + nt * 512);
                short8 a = *(const short8*)(Ar + ch * 64 + q * 32);
                #pragma unroll
                for (int nt = 0; nt < 4; ++nt)
                    acc[nt] = __builtin_amdgcn_mfma_f32_16x16x32_bf16(a, b[nt], acc[nt], 0, 0, 0);
            }
        }
        __syncthreads();
    }

    unsigned short* Orow = O0 + (size_t)gy * OP + (size_t)nb * 64;
    int gx = gx0 + kq * 4;
    #pragma unroll
    for (int nt = 0; nt < 4; ++nt) {
        float bv = bias[nb * 64 + nt * 16 + ml];
        #pragma unroll
        for (int r = 0; r < 4; ++r) {
            float v = fmaxf(acc[nt][r] + bv, 0.f);
            Orow[(size_t)(gx + r) * OMS + nt * 16 + ml] = f2bf(v);
        }
    }
}

// ---------------------------------------------------------------------------
// K-split GEMM: block = 64m x 64n, 4 waves each K/4, LDS cross-wave reduce
// (rotated slice order so own slice is acc[0]).
// AGGF=1: the 4-neighbor grid aggregation (66x66, node-major) is fused into
// the A-fragment load: a = bf16( (self + mask*nbrs) * inv_deg ). Masks and
// inv_deg are loop-invariant per fragment. Out-of-range neighbor rows read
// adjacent arena memory (finite, mask=0) and only affect rows >= 4356,
// which are never consumed.
// ct=1: blockIdx.z = tap, parity-shifted output (convT).
// ---------------------------------------------------------------------------
template<int KCW, int AGGF>   // k32-steps per wave; K = KCW*128
__global__ __launch_bounds__(TPB) void k_gemmS(
    const unsigned short* __restrict__ A0, const unsigned short* __restrict__ Wf,
    const float* __restrict__ bias, const unsigned short* __restrict__ resid,
    unsigned short* __restrict__ O0, int NTtot,
    int AP, int Wimg, int OMS, int OP, int relu, int ct, int ctDy, int ctDx)
{
    constexpr int K = KCW * 128;
    __shared__ float red[12 * 4 * 64 * 4];   // 49,152 B
    int lane = threadIdx.x & 63, wave = threadIdx.x >> 6;
    int ml = lane & 15, kq = lane >> 4;
    int m0 = blockIdx.x * 64, nb = blockIdx.y;

    const unsigned short* Wb = Wf;
    unsigned short* Ob = O0;
    if (ct) {
        int tp = blockIdx.z;
        Wb += (size_t)(tp * KCW * 4) * NTtot * 512;
        int dy = 1 - (tp >> 1), dx = 1 - (tp & 1);   // jax conv_transpose tap flip
        Ob += (size_t)dy * ctDy + (size_t)dx * ctDx;
    }

    const unsigned short* Ap[4];
    float mU[4], mD[4], mL[4], mR[4], inv[4];
    #pragma unroll
    for (int i = 0; i < 4; ++i) {
        int mf = (wave + i) & 3;
        int m = m0 + mf * 16;
        if (AGGF) {
            int n = m + ml;                      // node index (Wimg huge)
            int ir = n / 66, jc = n - ir * 66;
            mU[i] = (ir > 0)  ? 1.f : 0.f;
            mD[i] = (ir < 65) ? 1.f : 0.f;
            mL[i] = (jc > 0)  ? 1.f : 0.f;
            mR[i] = (jc < 65) ? 1.f : 0.f;
            inv[i] = 1.f / (1.f + mU[i] + mD[i] + mL[i] + mR[i]);
            Ap[i] = A0 + (size_t)n * K + wave * (KCW * 32) + kq * 8;
        } else {
            int y = m / Wimg, x = m - y * Wimg;
            Ap[i] = A0 + (size_t)y * AP + (size_t)(x + ml) * K + wave * (KCW * 32) + kq * 8;
        }
    }
    const unsigned short* Bp = Wb + ((size_t)(wave * KCW) * NTtot + nb * 4) * 512 + lane * 8;

    f32x4 acc[4][4];
    #pragma unroll
    for (int i = 0; i < 4; ++i)
        #pragma unroll
        for (int nt = 0; nt < 4; ++nt) acc[i][nt] = (f32x4){0.f, 0.f, 0.f, 0.f};

    #pragma unroll
    for (int q = 0; q < KCW; ++q) {
        short8 b[4];
        #pragma unroll
        for (int nt = 0; nt < 4; ++nt)
            b[nt] = *(const short8*)(Bp + ((size_t)q * NTtot + nt) * 512);
        short8 a[4];
        #pragma unroll
        for (int i = 0; i < 4; ++i) {
            const unsigned short* p = Ap[i] + q * 32;
            if (!AGGF) {
                a[i] = *(const short8*)p;
            } else {
                short8 s0 = *(const short8*)p;
                short8 s1 = *(const short8*)(p - (size_t)66 * K);
                short8 s2 = *(const short8*)(p + (size_t)66 * K);
                short8 s3 = *(const short8*)(p - K);
                short8 s4 = *(const short8*)(p + K);
                short8 o;
                #pragma unroll
                for (int e = 0; e < 8; ++e) {
                    float v = bf2f((unsigned short)s0[e]);
                    v = fmaf(mU[i], bf2f((unsigned short)s1[e]), v);
                    v = fmaf(mD[i], bf2f((unsigned short)s2[e]), v);
                    v = fmaf(mL[i], bf2f((unsigned short)s3[e]), v);
                    v = fmaf(mR[i], bf2f((unsigned short)s4[e]), v);
                    o[e] = (short)f2bf(v * inv[i]);
                }
                a[i] = o;
            }
        }
        #pragma unroll
        for (int i = 0; i < 4; ++i)
            #pragma unroll
            for (int nt = 0; nt < 4; ++nt)
                acc[i][nt] = __builtin_amdgcn_mfma_f32_16x16x32_bf16(a[i], b[nt], acc[i][nt], 0, 0, 0);
    }

    #pragma unroll
    for (int i = 1; i < 4; ++i) {
        int s = wave * 3 + (i - 1);
        #pragma unroll
        for (int nt = 0; nt < 4; ++nt)
            *(f32x4*)&red[(((s * 4 + nt) * 64) + lane) * 4] = acc[i][nt];
    }
    __syncthreads();
    #pragma unroll
    for (int w2 = 0; w2 < 4; ++w2) {
        if (w2 == wave) continue;
        int i = (wave - w2) & 3;
        int s = w2 * 3 + (i - 1);
        #pragma unroll
        for (int nt = 0; nt < 4; ++nt) {
            f32x4 v = *(const f32x4*)&red[(((s * 4 + nt) * 64) + lane) * 4];
            acc[0][nt] += v;
        }
    }

    int mrow = m0 + wave * 16 + kq * 4;
    int y = mrow / Wimg, x = mrow - y * Wimg;
    unsigned short* Ot = Ob + (size_t)y * OP + (size_t)x * OMS + nb * 64;
    const unsigned short* Rt = resid ? resid + (size_t)mrow * OMS + nb * 64 : nullptr;
    #pragma unroll
    for (int nt = 0; nt < 4; ++nt) {
        float bv = bias[nb * 64 + nt * 16 + ml];
        #pragma unroll
        for (int r = 0; r < 4; ++r) {
            float v = acc[0][nt][r] + bv;
            if (relu) v = fmaxf(v, 0.f);
            if (Rt) v += bf2f(Rt[(size_t)r * OMS + nt * 16 + ml]);
            Ot[(size_t)r * OMS + nt * 16 + ml] = f2bf(v);
        }
    }
}

// ---------------------------------------------------------------------------
// No-split GEMM (K<=128 shapes: convT u4t): block = 64m x 64n, 4 waves
// m-split, whole K per wave, B direct from global (L1-hot), no LDS/barriers.
// ---------------------------------------------------------------------------
template<int KC>   // q-steps; K = KC*32
__global__ __launch_bounds__(TPB) void k_gemmN(
    const unsigned short* __restrict__ A0, const unsigned short* __restrict__ Wf,
    const float* __restrict__ bias, unsigned short* __restrict__ O0,
    int Cs, int AP, int Wimg, int OMS, int OP, int NTtot, int relu,
    int ct, int ctDy, int ctDx)
{
    int lane = threadIdx.x & 63, wave = threadIdx.x >> 6;
    int ml = lane & 15, kq = lane >> 4;
    int nb = blockIdx.y;

    const unsigned short* Wb = Wf;
    unsigned short* Ob = O0;
    if (ct) {
        int tp = blockIdx.z;
        Wb += (size_t)(tp * KC) * NTtot * 512;
        int dy = 1 - (tp >> 1), dx = 1 - (tp & 1);
        Ob += (size_t)dy * ctDy + (size_t)dx * ctDx;
    }
    int m0 = blockIdx.x * 64 + wave * 16;
    int y = m0 / Wimg, x = m0 - y * Wimg;
    const unsigned short* Arow = A0 + (size_t)y * AP + (size_t)(x + ml) * Cs + kq * 8;
    const unsigned short* Bp = Wb + (size_t)(nb * 4) * 512 + lane * 8;

    f32x4 acc[4];
    #pragma unroll
    for (int nt = 0; nt < 4; ++nt) acc[nt] = (f32x4){0.f, 0.f, 0.f, 0.f};

    #pragma unroll
    for (int q = 0; q < KC; ++q) {
        short8 b[4];
        #pragma unroll
        for (int nt = 0; nt < 4; ++nt)
            b[nt] = *(const short8*)(Bp + ((size_t)q * NTtot + nt) * 512);
        short8 a = *(const short8*)(Arow + q * 32);
        #pragma unroll
        for (int nt = 0; nt < 4; ++nt)
            acc[nt] = __builtin_amdgcn_mfma_f32_16x16x32_bf16(a, b[nt], acc[nt], 0, 0, 0);
    }

    unsigned short* Ot = Ob + (size_t)y * OP + (size_t)(x + kq * 4) * OMS + (size_t)nb * 64;
    #pragma unroll
    for (int nt = 0; nt < 4; ++nt) {
        float bv = bias[nb * 64 + nt * 16 + ml];
        #pragma unroll
        for (int r = 0; r < 4; ++r) {
            float v = acc[nt][r] + bv;
            if (relu) v = fmaxf(v, 0.f);
            Ot[(size_t)r * OMS + nt * 16 + ml] = f2bf(v);
        }
    }
}

// ---------------------------------------------------------------------------
// Generic MFMA GEMM (global-direct) — used only for conv1 (K=32 im2col).
// ---------------------------------------------------------------------------
template<int MW, int KC>
__global__ __launch_bounds__(TPB) void k_gemm(
    const unsigned short* __restrict__ A0, const unsigned short* __restrict__ Wf,
    const float* __restrict__ bias, unsigned short* __restrict__ O0,
    int Cs, int AP, int Wimg, int OMS, int OP,
    int T, TapOffs toffs, int NTtot, int relu)
{
    int lane = threadIdx.x & 63, wave = threadIdx.x >> 6;
    int ml = lane & 15, kq = lane >> 4;
    int nb = blockIdx.y;
    const unsigned short* WbB = Wf + (size_t)(nb * 4) * 512 + lane * 8;

    int fy[MW], fx[MW];
    const unsigned short* Af[MW];
    #pragma unroll
    for (int f = 0; f < MW; ++f) {
        int mf = (blockIdx.x * 4 + wave) * (16 * MW) + f * 16;
        int y = mf / Wimg, x = mf - y * Wimg;
        fy[f] = y; fx[f] = x;
        Af[f] = A0 + (size_t)y * AP + (size_t)(x + ml) * Cs + kq * 8;
    }

    f32x4 acc[MW][4];
    #pragma unroll
    for (int f = 0; f < MW; ++f)
        #pragma unroll
        for (int nt = 0; nt < 4; ++nt) acc[f][nt] = (f32x4){0.f, 0.f, 0.f, 0.f};

    for (int tp = 0; tp < T; ++tp) {
        int toff = toffs.o[tp];
        const unsigned short* Wt = WbB + (size_t)(tp * KC) * NTtot * 512;
        #pragma unroll
        for (int q = 0; q < KC; ++q) {
            short8 b[4];
            #pragma unroll
            for (int nt = 0; nt < 4; ++nt)
                b[nt] = *(const short8*)(Wt + (size_t)q * NTtot * 512 + nt * 512);
            short8 a[MW];
            #pragma unroll
            for (int f = 0; f < MW; ++f)
                a[f] = *(const short8*)(Af[f] + toff + q * 32);
            #pragma unroll
            for (int f = 0; f < MW; ++f)
                #pragma unroll
                for (int nt = 0; nt < 4; ++nt)
                    acc[f][nt] = __builtin_amdgcn_mfma_f32_16x16x32_bf16(a[f], b[nt], acc[f][nt], 0, 0, 0);
        }
    }

    #pragma unroll
    for (int f = 0; f < MW; ++f) {
        unsigned short* Ot = O0 + (size_t)fy[f] * OP + (size_t)(fx[f] + kq * 4) * OMS + (size_t)nb * 64;
        #pragma unroll
        for (int nt = 0; nt < 4; ++nt) {
            float bv = bias[nb * 64 + nt * 16 + ml];
            #pragma unroll
            for (int r = 0; r < 4; ++r) {
                float v = acc[f][nt][r] + bv;
                if (relu) v = fmaxf(v, 0.f);
                Ot[(size_t)r * OMS + nt * 16 + ml] = f2bf(v);
            }
        }
    }
}

// ---------------- fused weight packing (all 15 tensors, one dispatch) -------
struct PackArgs {
    const float* w[15];
    int cum[16];
    int mode[15], KC[15], NT[15], K[15], N[15];
};
__global__ __launch_bounds__(TPB) void k_pack_all(
    PackArgs pa, unsigned short* __restrict__ dst, int total)
{
    int idx = blockIdx.x * TPB + threadIdx.x;
    if (idx >= total) return;
    int e = 0;
    #pragma unroll
    for (int i = 1; i < 15; ++i) e += (idx >= pa.cum[i]);
    int local = idx - pa.cum[e];
    const float* w = pa.w[e];
    int KC = pa.KC[e], NT = pa.NT[e], K = pa.K[e], N = pa.N[e], mode = pa.mode[e];

    int j = local & 7, l = (local >> 3) & 63;
    int r = local >> 9;
    int ntg = r % NT; int r2 = r / NT;
    int q = r2 % KC; int tp = r2 / KC;
    int k = q * 32 + (l >> 4) * 8 + j;
    int n = ntg * 16 + (l & 15);
    float v = 0.f;
    if (mode == 0) { int ky = tp / 3, kx = tp % 3; v = w[(size_t)(n * K + k) * 9 + ky * 3 + kx]; }
    else if (mode == 1) { v = w[(size_t)k * N + n]; }
    else if (mode == 2) { v = w[((size_t)tp * K + k) * N + n]; }
    else { if (k < 27) { int tap = k / 3, c = k % 3; int ky = tap / 3, kx = tap % 3;
                         v = w[((n * 3 + c) * 3 + ky) * 3 + kx]; } }
    dst[idx] = f2bf(v);
}

// ---------------- fused pad-ring zeroing (all buffers, one dispatch) --------
struct ZArgs { int off[10]; int cum[11]; int W2[10]; int H2[10]; int Cs[10]; };
__global__ __launch_bounds__(TPB) void k_zero_all(
    ZArgs za, unsigned short* __restrict__ W, int total)
{
    int idx = blockIdx.x * TPB + threadIdx.x;
    if (idx >= total) return;
    int e = 0;
    #pragma unroll
    for (int i = 1; i < 10; ++i) e += (idx >= za.cum[i]);
    int local = idx - za.cum[e];
    int W2 = za.W2[e], H2 = za.H2[e], Cs = za.Cs[e];
    int topbot = 2 * W2 * Cs;
    int iy, ix, c;
    if (local < topbot) {
        int row = local / (W2 * Cs); int rest = local - row * (W2 * Cs);
        iy = row ? (H2 - 1) : 0; ix = rest / Cs; c = rest - (rest / Cs) * Cs;
    } else {
        int idx2 = local - topbot;
        int per = (H2 - 2) * Cs;
        int side = idx2 / per; int rest = idx2 - side * per;
        iy = 1 + rest / Cs; ix = side ? (W2 - 1) : 0; c = rest - (rest / Cs) * Cs;
    }
    W[(size_t)za.off[e] + ((size_t)iy * W2 + ix) * Cs + c] = 0;
}

// ---------------- conv1 im2col: x fp32 [3][256][256] -> xcol bf16 [65536][32]
__global__ __launch_bounds__(TPB) void k_im2col(
    const float* __restrict__ x, unsigned short* __restrict__ xcol)
{
    int idx = blockIdx.x * TPB + threadIdx.x;
    if (idx >= 65536 * 32) return;
    int k = idx & 31, m = idx >> 5;
    int y = m >> 8, xx = m & 255;
    float v = 0.f;
    if (k < 27) {
        int tap = k / 3, c = k - tap * 3;
        int ty = tap / 3, tx = tap % 3;
        int yy = y + ty - 1, xp = xx + tx - 1;
        if (yy >= 0 && yy < 256 && xp >= 0 && xp < 256)
            v = x[c * 65536 + yy * 256 + xp];
    }
    xcol[idx] = f2bf(v);
}

// ---------------- maxpool 2x2 channels-last (strided in/out) ----------------
__global__ __launch_bounds__(TPB) void k_maxpool(
    const unsigned short* __restrict__ inI, unsigned short* __restrict__ outI,
    int Wo, int C4, int CsIn, int inPitch, int CsOut, int outPitch, int total)
{
    int idx = blockIdx.x * TPB + threadIdx.x;
    if (idx >= total) return;
    int c4 = idx % C4; int p = idx / C4;
    int x = p % Wo, y = p / Wo;
    const unsigned short* ip = inI + (size_t)(2 * y) * inPitch + (size_t)(2 * x) * CsIn + c4 * 4;
    ushort4 a = *(const ushort4*)(ip);
    ushort4 b = *(const ushort4*)(ip + CsIn);
    ushort4 c = *(const ushort4*)(ip + inPitch);
    ushort4 d = *(const ushort4*)(ip + inPitch + CsIn);
    ushort4 o;
    o.x = f2bf(fmaxf(fmaxf(bf2f(a.x), bf2f(b.x)), fmaxf(bf2f(c.x), bf2f(d.x))));
    o.y = f2bf(fmaxf(fmaxf(bf2f(a.y), bf2f(b.y)), fmaxf(bf2f(c.y), bf2f(d.y))));
    o.z = f2bf(fmaxf(fmaxf(bf2f(a.z), bf2f(b.z)), fmaxf(bf2f(c.z), bf2f(d.z))));
    o.w = f2bf(fmaxf(fmaxf(bf2f(a.w), bf2f(b.w)), fmaxf(bf2f(c.w), bf2f(d.w))));
    *(ushort4*)(outI + (size_t)y * outPitch + (size_t)x * CsOut + c4 * 4) = o;
}

// ---------------- final conv 64->1, fp32 out --------------------------------
__global__ __launch_bounds__(TPB) void k_outconv(
    const unsigned short* __restrict__ vI, const float* __restrict__ ow,
    const float* __restrict__ ob, float* __restrict__ out)
{
    __shared__ float wl[576];
    for (int i = threadIdx.x; i < 576; i += TPB) wl[i] = ow[i];
    __syncthreads();
    int p = blockIdx.x * TPB + threadIdx.x;
    int y = p >> 8, x = p & 255;
    float acc = ob[0];
    #pragma unroll
    for (int ky = 0; ky < 3; ++ky)
        #pragma unroll
        for (int kx = 0; kx < 3; ++kx) {
            const unsigned short* ip = vI + (size_t)((y + ky - 1) * 258 + (x + kx - 1)) * 64;
            int wb = ky * 3 + kx;
            for (int c = 0; c < 64; c += 4) {
                ushort4 uv = *(const ushort4*)(ip + c);
                acc += bf2f(uv.x) * wl[c * 9 + wb] + bf2f(uv.y) * wl[(c + 1) * 9 + wb]
                     + bf2f(uv.z) * wl[(c + 2) * 9 + wb] + bf2f(uv.w) * wl[(c + 3) * 9 + wb];
            }
        }
    out[p] = acc;
}

static inline TapOffs zero_toffs() { TapOffs t = {}; return t; }

extern "C" void kernel_launch(void* const* d_in, const int* in_sizes, int n_in,
                              void* d_out, int out_size, void* d_ws, size_t ws_size,
                              hipStream_t stream) {
    const float* x    = (const float*)d_in[0];
    const float* d1w1 = (const float*)d_in[1];  const float* d1b1 = (const float*)d_in[2];
    const float* d1w2 = (const float*)d_in[3];  const float* d1b2 = (const float*)d_in[4];
    const float* d2w1 = (const float*)d_in[5];  const float* d2b1 = (const float*)d_in[6];
    const float* d2w2 = (const float*)d_in[7];  const float* d2b2 = (const float*)d_in[8];
    const float* md1w = (const float*)d_in[9];  const float* md1b = (const float*)d_in[10];
    const float* md2w = (const float*)d_in[11]; const float* md2b = (const float*)d_in[12];
    const float* mbw  = (const float*)d_in[13]; const float* mbb  = (const float*)d_in[14];
    const float* mu1w = (const float*)d_in[15]; const float* mu1b = (const float*)d_in[16];
    const float* mu2w = (const float*)d_in[17]; const float* mu2b = (const float*)d_in[18];
    const float* u3tw = (const float*)d_in[19]; const float* u3tb = (const float*)d_in[20];
    const float* u3w1 = (const float*)d_in[21]; const float* u3b1 = (const float*)d_in[22];
    const float* u3w2 = (const float*)d_in[23]; const float* u3b2 = (const float*)d_in[24];
    const float* u4tw = (const float*)d_in[25]; const float* u4tb = (const float*)d_in[26];
    const float* u4w1 = (const float*)d_in[27]; const float* u4b1 = (const float*)d_in[28];
    const float* u4w2 = (const float*)d_in[29]; const float* u4b2 = (const float*)d_in[30];
    const float* ow   = (const float*)d_in[31]; const float* ob   = (const float*)d_in[32];
    float* out = (float*)d_out;

    unsigned short* W = (unsigned short*)d_ws;

    // ---- flat arena (elem offsets, bf16) ----
    const size_t XCOL = 0;          // 2,097,152
    const size_t A1   = 2097152;    // 258*258*64
    const size_t CAT4 = 6357248;    // 258*258*128
    const size_t P1   = 14877440;   // 130*130*64
    const size_t T2   = 15959040;   // 130*130*128
    const size_t CAT3 = 18122240;   // 130*130*256
    const size_t X0   = 22448640;   // 66*66*128
    const size_t BP1  = 23006208;   // 4608*256
    const size_t BP2  = 24185856;   // 4608*512
    const size_t XB   = 26545152;   // 4608*1024
    const size_t XC   = 31263744;   // 4608*512
    const size_t XD   = 33623040;   // 4608*256
    const size_t V3A  = 34802688;   // 130*130*128
    const size_t V3B  = 36965888;   // 130*130*128
    const size_t V4A  = 39129088;   // 258*258*64
    const size_t V4B  = 43389184;   // 258*258*64
    const size_t WP   = 52367872;   // packed weights 2,320,384

    const size_t a1I   = A1 + 259 * 64;
    const size_t cat4I = CAT4 + 259 * 128;
    const size_t p1I   = P1 + 131 * 64;
    const size_t t2I   = T2 + 131 * 128;
    const size_t cat3I = CAT3 + 131 * 256;
    const size_t X0I   = X0 + 67 * 128;
    const size_t XdI   = XD + 67 * 256;
    const size_t v3aI  = V3A + 131 * 128;
    const size_t v3bI  = V3B + 131 * 128;
    const size_t v4aI  = V4A + 259 * 64;
    const size_t v4bI  = V4B + 259 * 64;

    dim3 blk(TPB);
    const int BIG = 1 << 28;

    // ---- fused pad-ring zeroing ----
    {
        ZArgs za;
        const int off[10] = {(int)A1,(int)CAT4,(int)P1,(int)T2,(int)CAT3,(int)V3A,(int)V3B,(int)V4A,(int)V4B,(int)X0};
        const int w2 [10] = {258,258,130,130,130,130,130,258,258,66};
        const int h2 [10] = {258,258,130,130,130,130,130,258,258,66};
        const int cs [10] = {64,128,64,128,256,128,128,64,64,128};
        int cum = 0;
        for (int i = 0; i < 10; ++i) {
            za.off[i]=off[i]; za.W2[i]=w2[i]; za.H2[i]=h2[i]; za.Cs[i]=cs[i];
            za.cum[i]=cum; cum += (w2[i]*h2[i] - (w2[i]-2)*(h2[i]-2))*cs[i];
        }
        za.cum[10]=cum;
        k_zero_all<<<dim3((cum + TPB - 1) / TPB), blk, 0, stream>>>(za, W, cum);
    }

    // ---- fused weight packing ----
    {
        PackArgs pa;
        const float* ws_[15] = {d1w1,d1w2,d2w1,d2w2,md1w,md2w,mbw,mu1w,mu2w,u3tw,u3w1,u3w2,u4tw,u4w1,u4w2};
        const int mode[15] = {3,0,0,0,1,1,1,1,1,2,0,0,2,0,0};
        const int kc [15] = {1,2,2,4,4,8,16,32,16,8,8,4,4,4,2};
        const int nt [15] = {4,4,8,8,16,32,64,32,16,8,8,8,4,4,4};
        const int kk [15] = {32,64,64,128,128,256,512,1024,512,256,256,128,128,128,64};
        const int nn [15] = {64,64,128,128,256,512,1024,512,256,128,128,128,64,64,64};
        const int tt [15] = {1,9,9,9,1,1,1,1,1,4,9,9,4,9,9};
        int cum = 0;
        for (int i = 0; i < 15; ++i) {
            pa.w[i]=ws_[i]; pa.mode[i]=mode[i]; pa.KC[i]=kc[i]; pa.NT[i]=nt[i];
            pa.K[i]=kk[i]; pa.N[i]=nn[i]; pa.cum[i]=cum;
            cum += tt[i]*kc[i]*nt[i]*512;
        }
        pa.cum[15]=cum;
        k_pack_all<<<dim3((cum + TPB - 1) / TPB), blk, 0, stream>>>(pa, W + WP, cum);
    }
    const size_t pw_d1w1=WP+0, pw_d1w2=WP+2048, pw_d2w1=WP+38912, pw_d2w2=WP+112640,
        pw_md1=WP+260096, pw_md2=WP+292864, pw_mb=WP+423936, pw_mu1=WP+948224,
        pw_mu2=WP+1472512, pw_u3t=WP+1603584, pw_u3w1=WP+1734656, pw_u3w2=WP+2029568,
        pw_u4t=WP+2177024, pw_u4w1=WP+2209792, pw_u4w2=WP+2283520;

    // ---- encoder ----
    k_im2col<<<dim3(8192), blk, 0, stream>>>(x, W + XCOL);
    k_gemm<2,1><<<dim3(512,1), blk, 0, stream>>>(W + XCOL, W + pw_d1w1, d1b1,
        W + a1I, 32, 8192, 256, 64, 258*64, 1, zero_toffs(), 4, 1);
    k_conv3f<1><<<dim3(1024,1), blk, 0, stream>>>(W + a1I, W + pw_d1w2, d1b2,
        W + cat4I, 258*64, 4, 128, 258*128, 4);
    k_maxpool<<<dim3(1024), blk, 0, stream>>>(W + cat4I, W + p1I, 128, 16, 128, 258*128, 64, 130*64, 128*128*16);
    k_conv3f<1><<<dim3(256,2), blk, 0, stream>>>(W + p1I, W + pw_d2w1, d2b1,
        W + t2I, 130*64, 2, 128, 130*128, 8);
    k_conv3f<2><<<dim3(256,2), blk, 0, stream>>>(W + t2I, W + pw_d2w2, d2b2,
        W + cat3I, 130*128, 2, 256, 130*256, 8);
    k_maxpool<<<dim3(512), blk, 0, stream>>>(W + cat3I, W + X0I, 64, 32, 256, 130*256, 128, 66*128, 64*64*32);

    // ---- GNN on 66x66 padded grid: aggregation fused into A-loads ----
    k_gemmS<1,1><<<dim3(72,4), blk, 0, stream>>>(W + X0, W + pw_md1, md1b, nullptr,
        W + BP1, 16, 0, BIG, 256, 0, 1, 0, 0, 0);
    k_gemmS<2,1><<<dim3(72,8), blk, 0, stream>>>(W + BP1, W + pw_md2, md2b, nullptr,
        W + BP2, 32, 0, BIG, 512, 0, 1, 0, 0, 0);
    k_gemmS<4,1><<<dim3(72,16), blk, 0, stream>>>(W + BP2, W + pw_mb, mbb, nullptr,
        W + XB, 64, 0, BIG, 1024, 0, 1, 0, 0, 0);
    k_gemmS<8,1><<<dim3(72,8), blk, 0, stream>>>(W + XB, W + pw_mu1, mu1b, W + BP2,
        W + XC, 32, 0, BIG, 512, 0, 1, 0, 0, 0);
    k_gemmS<4,1><<<dim3(72,4), blk, 0, stream>>>(W + XC, W + pw_mu2, mu2b, W + BP1,
        W + XD, 16, 0, BIG, 256, 0, 1, 0, 0, 0);

    // ---- decoder stage 3: convT (K-split, 4 taps via z) + 2 convs ----
    k_gemmS<2,0><<<dim3(64,2,4), blk, 0, stream>>>(W + XdI, W + pw_u3t, u3tb, nullptr,
        W + cat3I + 128, 8, 66*256, 64, 512, 2*130*256, 0, 1, 130*256, 256);
    k_conv3f<4><<<dim3(256,2), blk, 0, stream>>>(W + cat3I, W + pw_u3w1, u3b1,
        W + v3aI, 130*256, 2, 128, 130*128, 8);
    k_conv3f<2><<<dim3(256,2), blk, 0, stream>>>(W + v3aI, W + pw_u3w2, u3b2,
        W + v3bI, 130*128, 2, 128, 130*128, 8);

    // ---- decoder stage 4: convT (no-split, 4 taps via z) + 2 convs ----
    k_gemmN<4><<<dim3(256,1,4), blk, 0, stream>>>(W + v3bI, W + pw_u4t, u4tb,
        W + cat4I + 64, 128, 130*128, 128, 256, 2*258*128, 4, 0, 1, 258*128, 128);
    k_conv3f<2><<<dim3(1024,1), blk, 0, stream>>>(W + cat4I, W + pw_u4w1, u4b1,
        W + v4aI, 258*128, 4, 64, 258*64, 4);
    k_conv3f<1><<<dim3(1024,1), blk, 0, stream>>>(W + v4aI, W + pw_u4w2, u4b2,
        W + v4bI, 258*64, 4, 64, 258*64, 4);

    // ---- output conv 64->1, fp32 ----
    k_outconv<<<dim3(256), blk, 0, stream>>>(W + v4bI, ow, ob, out);
}

// Round 10
// 451.880 us; speedup vs baseline: 1.0376x; 1.0376x over previous
//
#include <hip/hip_runtime.h>
#include <cstddef>

#define TPB 256

typedef __attribute__((ext_vector_type(8))) short short8;
typedef __attribute__((ext_vector_type(4))) float f32x4;
typedef __attribute__((ext_vector_type(16))) float f32x16;

__device__ inline unsigned short f2bf(float f) {
    unsigned int u = __builtin_bit_cast(unsigned int, f);
    u += 0x7fffu + ((u >> 16) & 1u);
    return (unsigned short)(u >> 16);
}
__device__ inline float bf2f(unsigned short h) {
    unsigned int u = ((unsigned int)h) << 16;
    return __builtin_bit_cast(float, u);
}

struct TapOffs { int o[9]; };

// ---------------------------------------------------------------------------
// 3x3 conv GEMM on 32x32x16 MFMA: block = 64 px x 64 n, 4 waves as 2x2
// fragment grid (wave = (mi,ni): 32-px m-frag x 32-col n-frag). Per k16-step:
// 1 A global load + 1 B LDS read + 1 MFMA (16384 MACs) -> half the per-MAC
// load traffic of the 16x16 version (which was load-pipe-bound at ~15-20%
// MfmaUtil). B staged per-tap in LDS (fragment order, lane*16B), dbuf.
// 32x32x16 layouts: A[m=lane&31][k=(lane>>5)*8+j], B[k same][n=lane&31],
// D: col=lane&31, row=(reg&3)+8*(reg>>2)+4*(lane>>5)  [HW-verified m101].
// ---------------------------------------------------------------------------
template<int CHUNKS>   // input channels = CHUNKS*64
__global__ __launch_bounds__(TPB) void k_conv32(
    const unsigned short* __restrict__ A0, const unsigned short* __restrict__ Wf,
    const float* __restrict__ bias, unsigned short* __restrict__ O0,
    int AP, int tilesX, int OMS, int OP, int NT32)
{
    constexpr int Cs   = CHUNKS * 64;
    constexpr int KC16 = CHUNKS * 4;             // k16-steps per tap (whole K)
    __shared__ unsigned short Bs[2][CHUNKS * 4096];

    int lane = threadIdx.x & 63, wave = threadIdx.x >> 6;
    int ml = lane & 31, kh = lane >> 5;
    int mi = wave >> 1, ni = wave & 1;
    int nb = blockIdx.y;
    int tileX = blockIdx.x % tilesX, gy = blockIdx.x / tilesX;
    int gx0 = tileX * 64 + mi * 32;

    const unsigned short* Abase = A0 + (size_t)(gy - 1) * AP
                                     + (size_t)(gx0 + ml - 1) * Cs + kh * 8;

    f32x16 acc;
    #pragma unroll
    for (int i = 0; i < 16; ++i) acc[i] = 0.f;

    auto stageB = [&](int tap, int buf) {
        unsigned short* bd = Bs[buf];
        #pragma unroll
        for (int it = 0; it < CHUNKS * 2; ++it) {
            int u = threadIdx.x + it * TPB;
            int e = u * 8;
            int ch = e >> 12;
            int rem = e & 4095;
            int s = rem >> 10;
            int rem2 = rem & 1023;
            int nt = rem2 >> 9;
            int r = rem2 & 511;
            const unsigned short* src = Wf
                + ((size_t)(tap * KC16 + ch * 4 + s) * NT32 + nb * 2 + nt) * 512 + r;
            *(int4*)&bd[e] = *(const int4*)src;
        }
    };

    stageB(0, 0);
    __syncthreads();
    #pragma unroll
    for (int tap = 0; tap < 9; ++tap) {
        if (tap < 8) stageB(tap + 1, (tap + 1) & 1);
        int ky = tap / 3, kx = tap - (tap / 3) * 3;
        const unsigned short* Ar = Abase + (size_t)ky * AP + kx * Cs;
        const unsigned short* Bb = &Bs[tap & 1][ni * 512 + lane * 8];
        #pragma unroll
        for (int ch = 0; ch < CHUNKS; ++ch) {
            #pragma unroll
            for (int s = 0; s < 4; ++s) {
                short8 b = *(const short8*)(Bb + (ch * 4 + s) * 1024);
                short8 a = *(const short8*)(Ar + ch * 64 + s * 16);
                acc = __builtin_amdgcn_mfma_f32_32x32x16_bf16(a, b, acc, 0, 0, 0);
            }
        }
        __syncthreads();
    }

    int nbase = nb * 64 + ni * 32;
    unsigned short* Orow = O0 + (size_t)gy * OP + nbase + ml;
    float bv = bias[nbase + ml];
    #pragma unroll
    for (int r = 0; r < 16; ++r) {
        int row = (r & 3) + 8 * (r >> 2) + 4 * kh;
        float v = fmaxf(acc[r] + bv, 0.f);
        Orow[(size_t)(gx0 + row) * OMS] = f2bf(v);
    }
}

// ---------------------------------------------------------------------------
// K-split GEMM (GNN + convT u3t): block = 64m x 64n, 4 waves each K/4, LDS
// cross-wave reduce (rotated slice order so own slice is acc[0]). R8-proven.
// ---------------------------------------------------------------------------
template<int KCW>   // k32-steps per wave; K = KCW*128
__global__ __launch_bounds__(TPB) void k_gemmS(
    const unsigned short* __restrict__ A0, const unsigned short* __restrict__ Wf,
    const float* __restrict__ bias, const unsigned short* __restrict__ resid,
    unsigned short* __restrict__ O0, int NTtot,
    int AP, int Wimg, int OMS, int OP, int relu, int ct, int ctDy, int ctDx)
{
    constexpr int K = KCW * 128;
    __shared__ float red[12 * 4 * 64 * 4];   // 49,152 B
    int lane = threadIdx.x & 63, wave = threadIdx.x >> 6;
    int ml = lane & 15, kq = lane >> 4;
    int m0 = blockIdx.x * 64, nb = blockIdx.y;

    const unsigned short* Wb = Wf;
    unsigned short* Ob = O0;
    if (ct) {
        int tp = blockIdx.z;
        Wb += (size_t)(tp * KCW * 4) * NTtot * 512;
        int dy = 1 - (tp >> 1), dx = 1 - (tp & 1);   // jax conv_transpose tap flip
        Ob += (size_t)dy * ctDy + (size_t)dx * ctDx;
    }

    const unsigned short* Ap[4];
    #pragma unroll
    for (int i = 0; i < 4; ++i) {
        int mf = (wave + i) & 3;
        int m = m0 + mf * 16;
        int y = m / Wimg, x = m - y * Wimg;
        Ap[i] = A0 + (size_t)y * AP + (size_t)(x + ml) * K + wave * (KCW * 32) + kq * 8;
    }
    const unsigned short* Bp = Wb + ((size_t)(wave * KCW) * NTtot + nb * 4) * 512 + lane * 8;

    f32x4 acc[4][4];
    #pragma unroll
    for (int i = 0; i < 4; ++i)
        #pragma unroll
        for (int nt = 0; nt < 4; ++nt) acc[i][nt] = (f32x4){0.f, 0.f, 0.f, 0.f};

    #pragma unroll
    for (int q = 0; q < KCW; ++q) {
        short8 b[4];
        #pragma unroll
        for (int nt = 0; nt < 4; ++nt)
            b[nt] = *(const short8*)(Bp + ((size_t)q * NTtot + nt) * 512);
        short8 a[4];
        #pragma unroll
        for (int i = 0; i < 4; ++i)
            a[i] = *(const short8*)(Ap[i] + q * 32);
        #pragma unroll
        for (int i = 0; i < 4; ++i)
            #pragma unroll
            for (int nt = 0; nt < 4; ++nt)
                acc[i][nt] = __builtin_amdgcn_mfma_f32_16x16x32_bf16(a[i], b[nt], acc[i][nt], 0, 0, 0);
    }

    #pragma unroll
    for (int i = 1; i < 4; ++i) {
        int s = wave * 3 + (i - 1);
        #pragma unroll
        for (int nt = 0; nt < 4; ++nt)
            *(f32x4*)&red[(((s * 4 + nt) * 64) + lane) * 4] = acc[i][nt];
    }
    __syncthreads();
    #pragma unroll
    for (int w2 = 0; w2 < 4; ++w2) {
        if (w2 == wave) continue;
        int i = (wave - w2) & 3;
        int s = w2 * 3 + (i - 1);
        #pragma unroll
        for (int nt = 0; nt < 4; ++nt) {
            f32x4 v = *(const f32x4*)&red[(((s * 4 + nt) * 64) + lane) * 4];
            acc[0][nt] += v;
        }
    }

    int mrow = m0 + wave * 16 + kq * 4;
    int y = mrow / Wimg, x = mrow - y * Wimg;
    unsigned short* Ot = Ob + (size_t)y * OP + (size_t)x * OMS + nb * 64;
    const unsigned short* Rt = resid ? resid + (size_t)mrow * OMS + nb * 64 : nullptr;
    #pragma unroll
    for (int nt = 0; nt < 4; ++nt) {
        float bv = bias[nb * 64 + nt * 16 + ml];
        #pragma unroll
        for (int r = 0; r < 4; ++r) {
            float v = acc[0][nt][r] + bv;
            if (relu) v = fmaxf(v, 0.f);
            if (Rt) v += bf2f(Rt[(size_t)r * OMS + nt * 16 + ml]);
            Ot[(size_t)r * OMS + nt * 16 + ml] = f2bf(v);
        }
    }
}

// ---------------------------------------------------------------------------
// No-split GEMM (convT u4t): 4 waves m-split, whole K, B from global (L1).
// ---------------------------------------------------------------------------
template<int KC>   // q-steps; K = KC*32
__global__ __launch_bounds__(TPB) void k_gemmN(
    const unsigned short* __restrict__ A0, const unsigned short* __restrict__ Wf,
    const float* __restrict__ bias, unsigned short* __restrict__ O0,
    int Cs, int AP, int Wimg, int OMS, int OP, int NTtot, int relu,
    int ct, int ctDy, int ctDx)
{
    int lane = threadIdx.x & 63, wave = threadIdx.x >> 6;
    int ml = lane & 15, kq = lane >> 4;
    int nb = blockIdx.y;

    const unsigned short* Wb = Wf;
    unsigned short* Ob = O0;
    if (ct) {
        int tp = blockIdx.z;
        Wb += (size_t)(tp * KC) * NTtot * 512;
        int dy = 1 - (tp >> 1), dx = 1 - (tp & 1);
        Ob += (size_t)dy * ctDy + (size_t)dx * ctDx;
    }
    int m0 = blockIdx.x * 64 + wave * 16;
    int y = m0 / Wimg, x = m0 - y * Wimg;
    const unsigned short* Arow = A0 + (size_t)y * AP + (size_t)(x + ml) * Cs + kq * 8;
    const unsigned short* Bp = Wb + (size_t)(nb * 4) * 512 + lane * 8;

    f32x4 acc[4];
    #pragma unroll
    for (int nt = 0; nt < 4; ++nt) acc[nt] = (f32x4){0.f, 0.f, 0.f, 0.f};

    #pragma unroll
    for (int q = 0; q < KC; ++q) {
        short8 b[4];
        #pragma unroll
        for (int nt = 0; nt < 4; ++nt)
            b[nt] = *(const short8*)(Bp + ((size_t)q * NTtot + nt) * 512);
        short8 a = *(const short8*)(Arow + q * 32);
        #pragma unroll
        for (int nt = 0; nt < 4; ++nt)
            acc[nt] = __builtin_amdgcn_mfma_f32_16x16x32_bf16(a, b[nt], acc[nt], 0, 0, 0);
    }

    unsigned short* Ot = Ob + (size_t)y * OP + (size_t)(x + kq * 4) * OMS + (size_t)nb * 64;
    #pragma unroll
    for (int nt = 0; nt < 4; ++nt) {
        float bv = bias[nb * 64 + nt * 16 + ml];
        #pragma unroll
        for (int r = 0; r < 4; ++r) {
            float v = acc[nt][r] + bv;
            if (relu) v = fmaxf(v, 0.f);
            Ot[(size_t)r * OMS + nt * 16 + ml] = f2bf(v);
        }
    }
}

// ---------------------------------------------------------------------------
// Generic MFMA GEMM (global-direct) — used only for conv1 (K=32 im2col).
// ---------------------------------------------------------------------------
template<int MW, int KC>
__global__ __launch_bounds__(TPB) void k_gemm(
    const unsigned short* __restrict__ A0, const unsigned short* __restrict__ Wf,
    const float* __restrict__ bias, unsigned short* __restrict__ O0,
    int Cs, int AP, int Wimg, int OMS, int OP,
    int T, TapOffs toffs, int NTtot, int relu)
{
    int lane = threadIdx.x & 63, wave = threadIdx.x >> 6;
    int ml = lane & 15, kq = lane >> 4;
    int nb = blockIdx.y;
    const unsigned short* WbB = Wf + (size_t)(nb * 4) * 512 + lane * 8;

    int fy[MW], fx[MW];
    const unsigned short* Af[MW];
    #pragma unroll
    for (int f = 0; f < MW; ++f) {
        int mf = (blockIdx.x * 4 + wave) * (16 * MW) + f * 16;
        int y = mf / Wimg, x = mf - y * Wimg;
        fy[f] = y; fx[f] = x;
        Af[f] = A0 + (size_t)y * AP + (size_t)(x + ml) * Cs + kq * 8;
    }

    f32x4 acc[MW][4];
    #pragma unroll
    for (int f = 0; f < MW; ++f)
        #pragma unroll
        for (int nt = 0; nt < 4; ++nt) acc[f][nt] = (f32x4){0.f, 0.f, 0.f, 0.f};

    for (int tp = 0; tp < T; ++tp) {
        int toff = toffs.o[tp];
        const unsigned short* Wt = WbB + (size_t)(tp * KC) * NTtot * 512;
        #pragma unroll
        for (int q = 0; q < KC; ++q) {
            short8 b[4];
            #pragma unroll
            for (int nt = 0; nt < 4; ++nt)
                b[nt] = *(const short8*)(Wt + (size_t)q * NTtot * 512 + nt * 512);
            short8 a[MW];
            #pragma unroll
            for (int f = 0; f < MW; ++f)
                a[f] = *(const short8*)(Af[f] + toff + q * 32);
            #pragma unroll
            for (int f = 0; f < MW; ++f)
                #pragma unroll
                for (int nt = 0; nt < 4; ++nt)
                    acc[f][nt] = __builtin_amdgcn_mfma_f32_16x16x32_bf16(a[f], b[nt], acc[f][nt], 0, 0, 0);
        }
    }

    #pragma unroll
    for (int f = 0; f < MW; ++f) {
        unsigned short* Ot = O0 + (size_t)fy[f] * OP + (size_t)(fx[f] + kq * 4) * OMS + (size_t)nb * 64;
        #pragma unroll
        for (int nt = 0; nt < 4; ++nt) {
            float bv = bias[nb * 64 + nt * 16 + ml];
            #pragma unroll
            for (int r = 0; r < 4; ++r) {
                float v = acc[f][nt][r] + bv;
                if (relu) v = fmaxf(v, 0.f);
                Ot[(size_t)r * OMS + nt * 16 + ml] = f2bf(v);
            }
        }
    }
}

// ---------------- fused weight packing (all 15 tensors, one dispatch) -------
// modes: 0 conv OIHW 16x16-frag T=9 | 1 node [K][N] | 2 convT HWIO T=4 |
//        3 conv1 K=32 pad | 4 conv OIHW 32x32-frag T=9
struct PackArgs {
    const float* w[15];
    int cum[16];
    int mode[15], KC[15], NT[15], K[15], N[15];
};
__global__ __launch_bounds__(TPB) void k_pack_all(
    PackArgs pa, unsigned short* __restrict__ dst, int total)
{
    int idx = blockIdx.x * TPB + threadIdx.x;
    if (idx >= total) return;
    int e = 0;
    #pragma unroll
    for (int i = 1; i < 15; ++i) e += (idx >= pa.cum[i]);
    int local = idx - pa.cum[e];
    const float* w = pa.w[e];
    int KC = pa.KC[e], NT = pa.NT[e], K = pa.K[e], N = pa.N[e], mode = pa.mode[e];

    int j = local & 7, l = (local >> 3) & 63;
    int r = local >> 9;
    int ntg = r % NT; int r2 = r / NT;
    int q = r2 % KC; int tp = r2 / KC;
    float v = 0.f;
    if (mode == 4) {
        int k = q * 16 + (l >> 5) * 8 + j;
        int n = ntg * 32 + (l & 31);
        int ky = tp / 3, kx = tp % 3;
        v = w[(size_t)(n * K + k) * 9 + ky * 3 + kx];
    } else {
        int k = q * 32 + (l >> 4) * 8 + j;
        int n = ntg * 16 + (l & 15);
        if (mode == 0) { int ky = tp / 3, kx = tp % 3; v = w[(size_t)(n * K + k) * 9 + ky * 3 + kx]; }
        else if (mode == 1) { v = w[(size_t)k * N + n]; }
        else if (mode == 2) { v = w[((size_t)tp * K + k) * N + n]; }
        else { if (k < 27) { int tap = k / 3, c = k % 3; int ky = tap / 3, kx = tap % 3;
                             v = w[((n * 3 + c) * 3 + ky) * 3 + kx]; } }
    }
    dst[idx] = f2bf(v);
}

// ---------------- fused pad-ring zeroing (all buffers, one dispatch) --------
struct ZArgs { int off[10]; int cum[11]; int W2[10]; int H2[10]; int Cs[10]; };
__global__ __launch_bounds__(TPB) void k_zero_all(
    ZArgs za, unsigned short* __restrict__ W, int total)
{
    int idx = blockIdx.x * TPB + threadIdx.x;
    if (idx >= total) return;
    int e = 0;
    #pragma unroll
    for (int i = 1; i < 10; ++i) e += (idx >= za.cum[i]);
    int local = idx - za.cum[e];
    int W2 = za.W2[e], H2 = za.H2[e], Cs = za.Cs[e];
    int topbot = 2 * W2 * Cs;
    int iy, ix, c;
    if (local < topbot) {
        int row = local / (W2 * Cs); int rest = local - row * (W2 * Cs);
        iy = row ? (H2 - 1) : 0; ix = rest / Cs; c = rest - (rest / Cs) * Cs;
    } else {
        int idx2 = local - topbot;
        int per = (H2 - 2) * Cs;
        int side = idx2 / per; int rest = idx2 - side * per;
        iy = 1 + rest / Cs; ix = side ? (W2 - 1) : 0; c = rest - (rest / Cs) * Cs;
    }
    W[(size_t)za.off[e] + ((size_t)iy * W2 + ix) * Cs + c] = 0;
}

// ---------------- conv1 im2col: x fp32 [3][256][256] -> xcol bf16 [65536][32]
__global__ __launch_bounds__(TPB) void k_im2col(
    const float* __restrict__ x, unsigned short* __restrict__ xcol)
{
    int idx = blockIdx.x * TPB + threadIdx.x;
    if (idx >= 65536 * 32) return;
    int k = idx & 31, m = idx >> 5;
    int y = m >> 8, xx = m & 255;
    float v = 0.f;
    if (k < 27) {
        int tap = k / 3, c = k - tap * 3;
        int ty = tap / 3, tx = tap % 3;
        int yy = y + ty - 1, xp = xx + tx - 1;
        if (yy >= 0 && yy < 256 && xp >= 0 && xp < 256)
            v = x[c * 65536 + yy * 256 + xp];
    }
    xcol[idx] = f2bf(v);
}

// ---------------- maxpool 2x2 channels-last (strided in/out) ----------------
__global__ __launch_bounds__(TPB) void k_maxpool(
    const unsigned short* __restrict__ inI, unsigned short* __restrict__ outI,
    int Wo, int C4, int CsIn, int inPitch, int CsOut, int outPitch, int total)
{
    int idx = blockIdx.x * TPB + threadIdx.x;
    if (idx >= total) return;
    int c4 = idx % C4; int p = idx / C4;
    int x = p % Wo, y = p / Wo;
    const unsigned short* ip = inI + (size_t)(2 * y) * inPitch + (size_t)(2 * x) * CsIn + c4 * 4;
    ushort4 a = *(const ushort4*)(ip);
    ushort4 b = *(const ushort4*)(ip + CsIn);
    ushort4 c = *(const ushort4*)(ip + inPitch);
    ushort4 d = *(const ushort4*)(ip + inPitch + CsIn);
    ushort4 o;
    o.x = f2bf(fmaxf(fmaxf(bf2f(a.x), bf2f(b.x)), fmaxf(bf2f(c.x), bf2f(d.x))));
    o.y = f2bf(fmaxf(fmaxf(bf2f(a.y), bf2f(b.y)), fmaxf(bf2f(c.y), bf2f(d.y))));
    o.z = f2bf(fmaxf(fmaxf(bf2f(a.z), bf2f(b.z)), fmaxf(bf2f(c.z), bf2f(d.z))));
    o.w = f2bf(fmaxf(fmaxf(bf2f(a.w), bf2f(b.w)), fmaxf(bf2f(c.w), bf2f(d.w))));
    *(ushort4*)(outI + (size_t)y * outPitch + (size_t)x * CsOut + c4 * 4) = o;
}

// ---------------- graph aggregation on 66x66 grid, node-major bf16 ----------
__global__ __launch_bounds__(TPB) void k_gagg(
    const unsigned short* __restrict__ X, unsigned short* __restrict__ agg,
    int C, int total)
{
    int idx = blockIdx.x * TPB + threadIdx.x;
    if (idx >= total) return;
    int C4 = C >> 2;
    int c4 = idx % C4; int n = idx / C4;
    int i = n / 66, j = n - i * 66;
    size_t base = (size_t)n * C + c4 * 4;
    ushort4 s = *(const ushort4*)(X + base);
    float v0 = bf2f(s.x), v1 = bf2f(s.y), v2 = bf2f(s.z), v3 = bf2f(s.w);
    float cnt = 1.f;
    if (i > 0)  { ushort4 u = *(const ushort4*)(X + base - (size_t)66 * C);
                  v0 += bf2f(u.x); v1 += bf2f(u.y); v2 += bf2f(u.z); v3 += bf2f(u.w); cnt += 1.f; }
    if (i < 65) { ushort4 u = *(const ushort4*)(X + base + (size_t)66 * C);
                  v0 += bf2f(u.x); v1 += bf2f(u.y); v2 += bf2f(u.z); v3 += bf2f(u.w); cnt += 1.f; }
    if (j > 0)  { ushort4 u = *(const ushort4*)(X + base - C);
                  v0 += bf2f(u.x); v1 += bf2f(u.y); v2 += bf2f(u.z); v3 += bf2f(u.w); cnt += 1.f; }
    if (j < 65) { ushort4 u = *(const ushort4*)(X + base + C);
                  v0 += bf2f(u.x); v1 += bf2f(u.y); v2 += bf2f(u.z); v3 += bf2f(u.w); cnt += 1.f; }
    float inv = 1.f / cnt;
    ushort4 o;
    o.x = f2bf(v0 * inv); o.y = f2bf(v1 * inv); o.z = f2bf(v2 * inv); o.w = f2bf(v3 * inv);
    *(ushort4*)(agg + base) = o;
}

// ---------------- final conv 64->1, fp32 out --------------------------------
__global__ __launch_bounds__(TPB) void k_outconv(
    const unsigned short* __restrict__ vI, const float* __restrict__ ow,
    const float* __restrict__ ob, float* __restrict__ out)
{
    __shared__ float wl[576];
    for (int i = threadIdx.x; i < 576; i += TPB) wl[i] = ow[i];
    __syncthreads();
    int p = blockIdx.x * TPB + threadIdx.x;
    int y = p >> 8, x = p & 255;
    float acc = ob[0];
    #pragma unroll
    for (int ky = 0; ky < 3; ++ky)
        #pragma unroll
        for (int kx = 0; kx < 3; ++kx) {
            const unsigned short* ip = vI + (size_t)((y + ky - 1) * 258 + (x + kx - 1)) * 64;
            int wb = ky * 3 + kx;
            for (int c = 0; c < 64; c += 4) {
                ushort4 uv = *(const ushort4*)(ip + c);
                acc += bf2f(uv.x) * wl[c * 9 + wb] + bf2f(uv.y) * wl[(c + 1) * 9 + wb]
                     + bf2f(uv.z) * wl[(c + 2) * 9 + wb] + bf2f(uv.w) * wl[(c + 3) * 9 + wb];
            }
        }
    out[p] = acc;
}

static inline TapOffs zero_toffs() { TapOffs t = {}; return t; }

extern "C" void kernel_launch(void* const* d_in, const int* in_sizes, int n_in,
                              void* d_out, int out_size, void* d_ws, size_t ws_size,
                              hipStream_t stream) {
    const float* x    = (const float*)d_in[0];
    const float* d1w1 = (const float*)d_in[1];  const float* d1b1 = (const float*)d_in[2];
    const float* d1w2 = (const float*)d_in[3];  const float* d1b2 = (const float*)d_in[4];
    const float* d2w1 = (const float*)d_in[5];  const float* d2b1 = (const float*)d_in[6];
    const float* d2w2 = (const float*)d_in[7];  const float* d2b2 = (const float*)d_in[8];
    const float* md1w = (const float*)d_in[9];  const float* md1b = (const float*)d_in[10];
    const float* md2w = (const float*)d_in[11]; const float* md2b = (const float*)d_in[12];
    const float* mbw  = (const float*)d_in[13]; const float* mbb  = (const float*)d_in[14];
    const float* mu1w = (const float*)d_in[15]; const float* mu1b = (const float*)d_in[16];
    const float* mu2w = (const float*)d_in[17]; const float* mu2b = (const float*)d_in[18];
    const float* u3tw = (const float*)d_in[19]; const float* u3tb = (const float*)d_in[20];
    const float* u3w1 = (const float*)d_in[21]; const float* u3b1 = (const float*)d_in[22];
    const float* u3w2 = (const float*)d_in[23]; const float* u3b2 = (const float*)d_in[24];
    const float* u4tw = (const float*)d_in[25]; const float* u4tb = (const float*)d_in[26];
    const float* u4w1 = (const float*)d_in[27]; const float* u4b1 = (const float*)d_in[28];
    const float* u4w2 = (const float*)d_in[29]; const float* u4b2 = (const float*)d_in[30];
    const float* ow   = (const float*)d_in[31]; const float* ob   = (const float*)d_in[32];
    float* out = (float*)d_out;

    unsigned short* W = (unsigned short*)d_ws;

    // ---- flat arena (elem offsets, bf16) ----
    const size_t XCOL = 0;          // 2,097,152
    const size_t A1   = 2097152;    // 258*258*64
    const size_t CAT4 = 6357248;    // 258*258*128
    const size_t P1   = 14877440;   // 130*130*64
    const size_t T2   = 15959040;   // 130*130*128
    const size_t CAT3 = 18122240;   // 130*130*256
    const size_t X0   = 22448640;   // 66*66*128
    const size_t BP1  = 23006208;   // 4608*256
    const size_t BP2  = 24185856;   // 4608*512
    const size_t XB   = 26545152;   // 4608*1024
    const size_t XC   = 31263744;   // 4608*512
    const size_t XD   = 33623040;   // 4608*256
    const size_t V3A  = 34802688;   // 130*130*128
    const size_t V3B  = 36965888;   // 130*130*128
    const size_t V4A  = 39129088;   // 258*258*64
    const size_t V4B  = 43389184;   // 258*258*64
    const size_t AGG  = 47649280;   // 4608*1024
    const size_t WP   = 52367872;   // packed weights 2,320,384

    const size_t a1I   = A1 + 259 * 64;
    const size_t cat4I = CAT4 + 259 * 128;
    const size_t p1I   = P1 + 131 * 64;
    const size_t t2I   = T2 + 131 * 128;
    const size_t cat3I = CAT3 + 131 * 256;
    const size_t X0I   = X0 + 67 * 128;
    const size_t XdI   = XD + 67 * 256;
    const size_t v3aI  = V3A + 131 * 128;
    const size_t v3bI  = V3B + 131 * 128;
    const size_t v4aI  = V4A + 259 * 64;
    const size_t v4bI  = V4B + 259 * 64;

    dim3 blk(TPB);
    const int BIG = 1 << 28;

    // ---- fused pad-ring zeroing ----
    {
        ZArgs za;
        const int off[10] = {(int)A1,(int)CAT4,(int)P1,(int)T2,(int)CAT3,(int)V3A,(int)V3B,(int)V4A,(int)V4B,(int)X0};
        const int w2 [10] = {258,258,130,130,130,130,130,258,258,66};
        const int h2 [10] = {258,258,130,130,130,130,130,258,258,66};
        const int cs [10] = {64,128,64,128,256,128,128,64,64,128};
        int cum = 0;
        for (int i = 0; i < 10; ++i) {
            za.off[i]=off[i]; za.W2[i]=w2[i]; za.H2[i]=h2[i]; za.Cs[i]=cs[i];
            za.cum[i]=cum; cum += (w2[i]*h2[i] - (w2[i]-2)*(h2[i]-2))*cs[i];
        }
        za.cum[10]=cum;
        k_zero_all<<<dim3((cum + TPB - 1) / TPB), blk, 0, stream>>>(za, W, cum);
    }

    // ---- fused weight packing ----
    // conv 3x3 layers now use mode 4 (32x32 fragments): kc=K/16, nt=N/32.
    // total elems per tensor unchanged (9*K*N) -> offsets identical to R8.
    {
        PackArgs pa;
        const float* ws_[15] = {d1w1,d1w2,d2w1,d2w2,md1w,md2w,mbw,mu1w,mu2w,u3tw,u3w1,u3w2,u4tw,u4w1,u4w2};
        const int mode[15] = {3,4,4,4,1,1,1,1,1,2,4,4,2,4,4};
        const int kc [15] = {1,4,4,8,4,8,16,32,16,8,16,8,4,8,4};
        const int nt [15] = {4,2,4,4,16,32,64,32,16,8,4,4,4,2,2};
        const int kk [15] = {32,64,64,128,128,256,512,1024,512,256,256,128,128,128,64};
        const int nn [15] = {64,64,128,128,256,512,1024,512,256,128,128,128,64,64,64};
        const int tt [15] = {1,9,9,9,1,1,1,1,1,4,9,9,4,9,9};
        int cum = 0;
        for (int i = 0; i < 15; ++i) {
            pa.w[i]=ws_[i]; pa.mode[i]=mode[i]; pa.KC[i]=kc[i]; pa.NT[i]=nt[i];
            pa.K[i]=kk[i]; pa.N[i]=nn[i]; pa.cum[i]=cum;
            cum += tt[i]*kc[i]*nt[i]*512;
        }
        pa.cum[15]=cum;
        k_pack_all<<<dim3((cum + TPB - 1) / TPB), blk, 0, stream>>>(pa, W + WP, cum);
    }
    const size_t pw_d1w1=WP+0, pw_d1w2=WP+2048, pw_d2w1=WP+38912, pw_d2w2=WP+112640,
        pw_md1=WP+260096, pw_md2=WP+292864, pw_mb=WP+423936, pw_mu1=WP+948224,
        pw_mu2=WP+1472512, pw_u3t=WP+1603584, pw_u3w1=WP+1734656, pw_u3w2=WP+2029568,
        pw_u4t=WP+2177024, pw_u4w1=WP+2209792, pw_u4w2=WP+2283520;

    // ---- encoder ----
    k_im2col<<<dim3(8192), blk, 0, stream>>>(x, W + XCOL);
    k_gemm<2,1><<<dim3(512,1), blk, 0, stream>>>(W + XCOL, W + pw_d1w1, d1b1,
        W + a1I, 32, 8192, 256, 64, 258*64, 1, zero_toffs(), 4, 1);
    k_conv32<1><<<dim3(1024,1), blk, 0, stream>>>(W + a1I, W + pw_d1w2, d1b2,
        W + cat4I, 258*64, 4, 128, 258*128, 2);
    k_maxpool<<<dim3(1024), blk, 0, stream>>>(W + cat4I, W + p1I, 128, 16, 128, 258*128, 64, 130*64, 128*128*16);
    k_conv32<1><<<dim3(256,2), blk, 0, stream>>>(W + p1I, W + pw_d2w1, d2b1,
        W + t2I, 130*64, 2, 128, 130*128, 4);
    k_conv32<2><<<dim3(256,2), blk, 0, stream>>>(W + t2I, W + pw_d2w2, d2b2,
        W + cat3I, 130*128, 2, 256, 130*256, 4);
    k_maxpool<<<dim3(512), blk, 0, stream>>>(W + cat3I, W + X0I, 64, 32, 256, 130*256, 128, 66*128, 64*64*32);

    // ---- GNN on 66x66 padded grid (separate gagg + K-split GEMMs, R8) ----
    k_gagg<<<dim3(545), blk, 0, stream>>>(W + X0, W + AGG, 128, 4356*32);
    k_gemmS<1><<<dim3(72,4), blk, 0, stream>>>(W + AGG, W + pw_md1, md1b, nullptr,
        W + BP1, 16, 0, BIG, 256, 0, 1, 0, 0, 0);
    k_gagg<<<dim3(1089), blk, 0, stream>>>(W + BP1, W + AGG, 256, 4356*64);
    k_gemmS<2><<<dim3(72,8), blk, 0, stream>>>(W + AGG, W + pw_md2, md2b, nullptr,
        W + BP2, 32, 0, BIG, 512, 0, 1, 0, 0, 0);
    k_gagg<<<dim3(2178), blk, 0, stream>>>(W + BP2, W + AGG, 512, 4356*128);
    k_gemmS<4><<<dim3(72,16), blk, 0, stream>>>(W + AGG, W + pw_mb, mbb, nullptr,
        W + XB, 64, 0, BIG, 1024, 0, 1, 0, 0, 0);
    k_gagg<<<dim3(4356), blk, 0, stream>>>(W + XB, W + AGG, 1024, 4356*256);
    k_gemmS<8><<<dim3(72,8), blk, 0, stream>>>(W + AGG, W + pw_mu1, mu1b, W + BP2,
        W + XC, 32, 0, BIG, 512, 0, 1, 0, 0, 0);
    k_gagg<<<dim3(2178), blk, 0, stream>>>(W + XC, W + AGG, 512, 4356*128);
    k_gemmS<4><<<dim3(72,4), blk, 0, stream>>>(W + AGG, W + pw_mu2, mu2b, W + BP1,
        W + XD, 16, 0, BIG, 256, 0, 1, 0, 0, 0);

    // ---- decoder stage 3: convT (K-split, 4 taps via z) + 2 convs ----
    k_gemmS<2><<<dim3(64,2,4), blk, 0, stream>>>(W + XdI, W + pw_u3t, u3tb, nullptr,
        W + cat3I + 128, 8, 66*256, 64, 512, 2*130*256, 0, 1, 130*256, 256);
    k_conv32<4><<<dim3(256,2), blk, 0, stream>>>(W + cat3I, W + pw_u3w1, u3b1,
        W + v3aI, 130*256, 2, 128, 130*128, 4);
    k_conv32<2><<<dim3(256,2), blk, 0, stream>>>(W + v3aI, W + pw_u3w2, u3b2,
        W + v3bI, 130*128, 2, 128, 130*128, 4);

    // ---- decoder stage 4: convT (no-split, 4 taps via z) + 2 convs ----
    k_gemmN<4><<<dim3(256,1,4), blk, 0, stream>>>(W + v3bI, W + pw_u4t, u4tb,
        W + cat4I + 64, 128, 130*128, 128, 256, 2*258*128, 4, 0, 1, 258*128, 128);
    k_conv32<2><<<dim3(1024,1), blk, 0, stream>>>(W + cat4I, W + pw_u4w1, u4b1,
        W + v4aI, 258*128, 4, 64, 258*64, 2);
    k_conv32<1><<<dim3(1024,1), blk, 0, stream>>>(W + v4aI, W + pw_u4w2, u4b2,
        W + v4bI, 258*64, 4, 64, 258*64, 2);

    // ---- output conv 64->1, fp32 ----
    k_outconv<<<dim3(256), blk, 0, stream>>>(W + v4bI, ow, ob, out);
}

// Round 11
// 430.477 us; speedup vs baseline: 1.0892x; 1.0497x over previous
//
#include <hip/hip_runtime.h>
#include <cstddef>

#define TPB 256

typedef __attribute__((ext_vector_type(8))) short short8;
typedef __attribute__((ext_vector_type(4))) float f32x4;

__device__ inline unsigned short f2bf(float f) {
    unsigned int u = __builtin_bit_cast(unsigned int, f);
    u += 0x7fffu + ((u >> 16) & 1u);
    return (unsigned short)(u >> 16);
}
__device__ inline float bf2f(unsigned short h) {
    unsigned int u = ((unsigned int)h) << 16;
    return __builtin_bit_cast(float, u);
}

struct TapOffs { int o[9]; };

// ---------------------------------------------------------------------------
// Barrierless 3x3 conv GEMM: block = 64 px x 64 n, 4 waves m-split (wave =
// one 16-px m-frag). A direct from global (channels-last, pad ring valid).
// B direct from global in packed fragment order — all 4 waves read IDENTICAL
// B addresses (L1 broadcast; per-tap B = 4-16 KB << L1), so no LDS and,
// critically, NO BARRIERS: previous versions' per-tap __syncthreads forced a
// compiler-emitted s_waitcnt vmcnt(0) drain 9-18x per block, serializing all
// A-load latency with compute (convs stuck at 7-15% MfmaUtil, R6-R10).
// Straight-line unrolled loads+MFMAs let the compiler software-pipeline with
// fine-grained vmcnt. 4 independent accumulators per wave (MFMA ILP).
// mfma_f32_16x16x32_bf16: A[m=lane&15][k=(lane>>4)*8+j], B[k][n=lane&15],
// D: col(n)=lane&15, row(m)=(lane>>4)*4+reg.
// ---------------------------------------------------------------------------
template<int CHUNKS>   // input channels = CHUNKS*64
__global__ __launch_bounds__(TPB) void k_conv3n(
    const unsigned short* __restrict__ A0, const unsigned short* __restrict__ Wf,
    const float* __restrict__ bias, unsigned short* __restrict__ O0,
    int AP, int tilesX, int OMS, int OP, int NTtot)
{
    constexpr int Cs  = CHUNKS * 64;
    constexpr int KC2 = CHUNKS * 2;          // k32-steps per tap (whole K)

    int lane = threadIdx.x & 63, wave = threadIdx.x >> 6;
    int ml = lane & 15, kq = lane >> 4;
    int nb = blockIdx.y;
    int tileX = blockIdx.x % tilesX, gy = blockIdx.x / tilesX;
    int gx0 = tileX * 64 + wave * 16;

    const unsigned short* Abase = A0 + (size_t)(gy - 1) * AP
                                     + (size_t)(gx0 + ml - 1) * Cs + kq * 8;
    const unsigned short* Bp = Wf + (size_t)(nb * 4) * 512 + lane * 8;

    f32x4 acc[4];
    #pragma unroll
    for (int nt = 0; nt < 4; ++nt) acc[nt] = (f32x4){0.f, 0.f, 0.f, 0.f};

    #pragma unroll
    for (int tap = 0; tap < 9; ++tap) {
        int ky = tap / 3, kx = tap - (tap / 3) * 3;
        const unsigned short* Ar = Abase + (size_t)ky * AP + kx * Cs;
        const unsigned short* Bt = Bp + (size_t)(tap * KC2) * NTtot * 512;
        #pragma unroll
        for (int q = 0; q < KC2; ++q) {
            short8 b[4];
            #pragma unroll
            for (int nt = 0; nt < 4; ++nt)
                b[nt] = *(const short8*)(Bt + ((size_t)q * NTtot + nt) * 512);
            short8 a = *(const short8*)(Ar + q * 32);
            #pragma unroll
            for (int nt = 0; nt < 4; ++nt)
                acc[nt] = __builtin_amdgcn_mfma_f32_16x16x32_bf16(a, b[nt], acc[nt], 0, 0, 0);
        }
    }

    unsigned short* Orow = O0 + (size_t)gy * OP + (size_t)nb * 64;
    int gx = gx0 + kq * 4;
    #pragma unroll
    for (int nt = 0; nt < 4; ++nt) {
        float bv = bias[nb * 64 + nt * 16 + ml];
        #pragma unroll
        for (int r = 0; r < 4; ++r) {
            float v = fmaxf(acc[nt][r] + bv, 0.f);
            Orow[(size_t)(gx + r) * OMS + nt * 16 + ml] = f2bf(v);
        }
    }
}

// ---------------------------------------------------------------------------
// K-split GEMM (GNN + convT u3t): block = 64m x 64n, 4 waves each K/4, LDS
// cross-wave reduce (rotated slice order so own slice is acc[0]). R8-proven.
// ---------------------------------------------------------------------------
template<int KCW>   // k32-steps per wave; K = KCW*128
__global__ __launch_bounds__(TPB) void k_gemmS(
    const unsigned short* __restrict__ A0, const unsigned short* __restrict__ Wf,
    const float* __restrict__ bias, const unsigned short* __restrict__ resid,
    unsigned short* __restrict__ O0, int NTtot,
    int AP, int Wimg, int OMS, int OP, int relu, int ct, int ctDy, int ctDx)
{
    constexpr int K = KCW * 128;
    __shared__ float red[12 * 4 * 64 * 4];   // 49,152 B
    int lane = threadIdx.x & 63, wave = threadIdx.x >> 6;
    int ml = lane & 15, kq = lane >> 4;
    int m0 = blockIdx.x * 64, nb = blockIdx.y;

    const unsigned short* Wb = Wf;
    unsigned short* Ob = O0;
    if (ct) {
        int tp = blockIdx.z;
        Wb += (size_t)(tp * KCW * 4) * NTtot * 512;
        int dy = 1 - (tp >> 1), dx = 1 - (tp & 1);   // jax conv_transpose tap flip
        Ob += (size_t)dy * ctDy + (size_t)dx * ctDx;
    }

    const unsigned short* Ap[4];
    #pragma unroll
    for (int i = 0; i < 4; ++i) {
        int mf = (wave + i) & 3;
        int m = m0 + mf * 16;
        int y = m / Wimg, x = m - y * Wimg;
        Ap[i] = A0 + (size_t)y * AP + (size_t)(x + ml) * K + wave * (KCW * 32) + kq * 8;
    }
    const unsigned short* Bp = Wb + ((size_t)(wave * KCW) * NTtot + nb * 4) * 512 + lane * 8;

    f32x4 acc[4][4];
    #pragma unroll
    for (int i = 0; i < 4; ++i)
        #pragma unroll
        for (int nt = 0; nt < 4; ++nt) acc[i][nt] = (f32x4){0.f, 0.f, 0.f, 0.f};

    #pragma unroll
    for (int q = 0; q < KCW; ++q) {
        short8 b[4];
        #pragma unroll
        for (int nt = 0; nt < 4; ++nt)
            b[nt] = *(const short8*)(Bp + ((size_t)q * NTtot + nt) * 512);
        short8 a[4];
        #pragma unroll
        for (int i = 0; i < 4; ++i)
            a[i] = *(const short8*)(Ap[i] + q * 32);
        #pragma unroll
        for (int i = 0; i < 4; ++i)
            #pragma unroll
            for (int nt = 0; nt < 4; ++nt)
                acc[i][nt] = __builtin_amdgcn_mfma_f32_16x16x32_bf16(a[i], b[nt], acc[i][nt], 0, 0, 0);
    }

    #pragma unroll
    for (int i = 1; i < 4; ++i) {
        int s = wave * 3 + (i - 1);
        #pragma unroll
        for (int nt = 0; nt < 4; ++nt)
            *(f32x4*)&red[(((s * 4 + nt) * 64) + lane) * 4] = acc[i][nt];
    }
    __syncthreads();
    #pragma unroll
    for (int w2 = 0; w2 < 4; ++w2) {
        if (w2 == wave) continue;
        int i = (wave - w2) & 3;
        int s = w2 * 3 + (i - 1);
        #pragma unroll
        for (int nt = 0; nt < 4; ++nt) {
            f32x4 v = *(const f32x4*)&red[(((s * 4 + nt) * 64) + lane) * 4];
            acc[0][nt] += v;
        }
    }

    int mrow = m0 + wave * 16 + kq * 4;
    int y = mrow / Wimg, x = mrow - y * Wimg;
    unsigned short* Ot = Ob + (size_t)y * OP + (size_t)x * OMS + nb * 64;
    const unsigned short* Rt = resid ? resid + (size_t)mrow * OMS + nb * 64 : nullptr;
    #pragma unroll
    for (int nt = 0; nt < 4; ++nt) {
        float bv = bias[nb * 64 + nt * 16 + ml];
        #pragma unroll
        for (int r = 0; r < 4; ++r) {
            float v = acc[0][nt][r] + bv;
            if (relu) v = fmaxf(v, 0.f);
            if (Rt) v += bf2f(Rt[(size_t)r * OMS + nt * 16 + ml]);
            Ot[(size_t)r * OMS + nt * 16 + ml] = f2bf(v);
        }
    }
}

// ---------------------------------------------------------------------------
// No-split GEMM (convT u4t): 4 waves m-split, whole K, B from global (L1).
// ---------------------------------------------------------------------------
template<int KC>   // q-steps; K = KC*32
__global__ __launch_bounds__(TPB) void k_gemmN(
    const unsigned short* __restrict__ A0, const unsigned short* __restrict__ Wf,
    const float* __restrict__ bias, unsigned short* __restrict__ O0,
    int Cs, int AP, int Wimg, int OMS, int OP, int NTtot, int relu,
    int ct, int ctDy, int ctDx)
{
    int lane = threadIdx.x & 63, wave = threadIdx.x >> 6;
    int ml = lane & 15, kq = lane >> 4;
    int nb = blockIdx.y;

    const unsigned short* Wb = Wf;
    unsigned short* Ob = O0;
    if (ct) {
        int tp = blockIdx.z;
        Wb += (size_t)(tp * KC) * NTtot * 512;
        int dy = 1 - (tp >> 1), dx = 1 - (tp & 1);
        Ob += (size_t)dy * ctDy + (size_t)dx * ctDx;
    }
    int m0 = blockIdx.x * 64 + wave * 16;
    int y = m0 / Wimg, x = m0 - y * Wimg;
    const unsigned short* Arow = A0 + (size_t)y * AP + (size_t)(x + ml) * Cs + kq * 8;
    const unsigned short* Bp = Wb + (size_t)(nb * 4) * 512 + lane * 8;

    f32x4 acc[4];
    #pragma unroll
    for (int nt = 0; nt < 4; ++nt) acc[nt] = (f32x4){0.f, 0.f, 0.f, 0.f};

    #pragma unroll
    for (int q = 0; q < KC; ++q) {
        short8 b[4];
        #pragma unroll
        for (int nt = 0; nt < 4; ++nt)
            b[nt] = *(const short8*)(Bp + ((size_t)q * NTtot + nt) * 512);
        short8 a = *(const short8*)(Arow + q * 32);
        #pragma unroll
        for (int nt = 0; nt < 4; ++nt)
            acc[nt] = __builtin_amdgcn_mfma_f32_16x16x32_bf16(a, b[nt], acc[nt], 0, 0, 0);
    }

    unsigned short* Ot = Ob + (size_t)y * OP + (size_t)(x + kq * 4) * OMS + (size_t)nb * 64;
    #pragma unroll
    for (int nt = 0; nt < 4; ++nt) {
        float bv = bias[nb * 64 + nt * 16 + ml];
        #pragma unroll
        for (int r = 0; r < 4; ++r) {
            float v = acc[nt][r] + bv;
            if (relu) v = fmaxf(v, 0.f);
            Ot[(size_t)r * OMS + nt * 16 + ml] = f2bf(v);
        }
    }
}

// ---------------------------------------------------------------------------
// Generic MFMA GEMM (global-direct) — used only for conv1 (K=32 im2col).
// ---------------------------------------------------------------------------
template<int MW, int KC>
__global__ __launch_bounds__(TPB) void k_gemm(
    const unsigned short* __restrict__ A0, const unsigned short* __restrict__ Wf,
    const float* __restrict__ bias, unsigned short* __restrict__ O0,
    int Cs, int AP, int Wimg, int OMS, int OP,
    int T, TapOffs toffs, int NTtot, int relu)
{
    int lane = threadIdx.x & 63, wave = threadIdx.x >> 6;
    int ml = lane & 15, kq = lane >> 4;
    int nb = blockIdx.y;
    const unsigned short* WbB = Wf + (size_t)(nb * 4) * 512 + lane * 8;

    int fy[MW], fx[MW];
    const unsigned short* Af[MW];
    #pragma unroll
    for (int f = 0; f < MW; ++f) {
        int mf = (blockIdx.x * 4 + wave) * (16 * MW) + f * 16;
        int y = mf / Wimg, x = mf - y * Wimg;
        fy[f] = y; fx[f] = x;
        Af[f] = A0 + (size_t)y * AP + (size_t)(x + ml) * Cs + kq * 8;
    }

    f32x4 acc[MW][4];
    #pragma unroll
    for (int f = 0; f < MW; ++f)
        #pragma unroll
        for (int nt = 0; nt < 4; ++nt) acc[f][nt] = (f32x4){0.f, 0.f, 0.f, 0.f};

    for (int tp = 0; tp < T; ++tp) {
        int toff = toffs.o[tp];
        const unsigned short* Wt = WbB + (size_t)(tp * KC) * NTtot * 512;
        #pragma unroll
        for (int q = 0; q < KC; ++q) {
            short8 b[4];
            #pragma unroll
            for (int nt = 0; nt < 4; ++nt)
                b[nt] = *(const short8*)(Wt + (size_t)q * NTtot * 512 + nt * 512);
            short8 a[MW];
            #pragma unroll
            for (int f = 0; f < MW; ++f)
                a[f] = *(const short8*)(Af[f] + toff + q * 32);
            #pragma unroll
            for (int f = 0; f < MW; ++f)
                #pragma unroll
                for (int nt = 0; nt < 4; ++nt)
                    acc[f][nt] = __builtin_amdgcn_mfma_f32_16x16x32_bf16(a[f], b[nt], acc[f][nt], 0, 0, 0);
        }
    }

    #pragma unroll
    for (int f = 0; f < MW; ++f) {
        unsigned short* Ot = O0 + (size_t)fy[f] * OP + (size_t)(fx[f] + kq * 4) * OMS + (size_t)nb * 64;
        #pragma unroll
        for (int nt = 0; nt < 4; ++nt) {
            float bv = bias[nb * 64 + nt * 16 + ml];
            #pragma unroll
            for (int r = 0; r < 4; ++r) {
                float v = acc[f][nt][r] + bv;
                if (relu) v = fmaxf(v, 0.f);
                Ot[(size_t)r * OMS + nt * 16 + ml] = f2bf(v);
            }
        }
    }
}

// ---------------- fused weight packing (all 15 tensors, one dispatch) -------
struct PackArgs {
    const float* w[15];
    int cum[16];
    int mode[15], KC[15], NT[15], K[15], N[15];
};
__global__ __launch_bounds__(TPB) void k_pack_all(
    PackArgs pa, unsigned short* __restrict__ dst, int total)
{
    int idx = blockIdx.x * TPB + threadIdx.x;
    if (idx >= total) return;
    int e = 0;
    #pragma unroll
    for (int i = 1; i < 15; ++i) e += (idx >= pa.cum[i]);
    int local = idx - pa.cum[e];
    const float* w = pa.w[e];
    int KC = pa.KC[e], NT = pa.NT[e], K = pa.K[e], N = pa.N[e], mode = pa.mode[e];

    int j = local & 7, l = (local >> 3) & 63;
    int r = local >> 9;
    int ntg = r % NT; int r2 = r / NT;
    int q = r2 % KC; int tp = r2 / KC;
    int k = q * 32 + (l >> 4) * 8 + j;
    int n = ntg * 16 + (l & 15);
    float v = 0.f;
    if (mode == 0) { int ky = tp / 3, kx = tp % 3; v = w[(size_t)(n * K + k) * 9 + ky * 3 + kx]; }
    else if (mode == 1) { v = w[(size_t)k * N + n]; }
    else if (mode == 2) { v = w[((size_t)tp * K + k) * N + n]; }
    else { if (k < 27) { int tap = k / 3, c = k % 3; int ky = tap / 3, kx = tap % 3;
                         v = w[((n * 3 + c) * 3 + ky) * 3 + kx]; } }
    dst[idx] = f2bf(v);
}

// ---------------- fused pad-ring zeroing (all buffers, one dispatch) --------
struct ZArgs { int off[10]; int cum[11]; int W2[10]; int H2[10]; int Cs[10]; };
__global__ __launch_bounds__(TPB) void k_zero_all(
    ZArgs za, unsigned short* __restrict__ W, int total)
{
    int idx = blockIdx.x * TPB + threadIdx.x;
    if (idx >= total) return;
    int e = 0;
    #pragma unroll
    for (int i = 1; i < 10; ++i) e += (idx >= za.cum[i]);
    int local = idx - za.cum[e];
    int W2 = za.W2[e], H2 = za.H2[e], Cs = za.Cs[e];
    int topbot = 2 * W2 * Cs;
    int iy, ix, c;
    if (local < topbot) {
        int row = local / (W2 * Cs); int rest = local - row * (W2 * Cs);
        iy = row ? (H2 - 1) : 0; ix = rest / Cs; c = rest - (rest / Cs) * Cs;
    } else {
        int idx2 = local - topbot;
        int per = (H2 - 2) * Cs;
        int side = idx2 / per; int rest = idx2 - side * per;
        iy = 1 + rest / Cs; ix = side ? (W2 - 1) : 0; c = rest - (rest / Cs) * Cs;
    }
    W[(size_t)za.off[e] + ((size_t)iy * W2 + ix) * Cs + c] = 0;
}

// ---------------- conv1 im2col: x fp32 [3][256][256] -> xcol bf16 [65536][32]
__global__ __launch_bounds__(TPB) void k_im2col(
    const float* __restrict__ x, unsigned short* __restrict__ xcol)
{
    int idx = blockIdx.x * TPB + threadIdx.x;
    if (idx >= 65536 * 32) return;
    int k = idx & 31, m = idx >> 5;
    int y = m >> 8, xx = m & 255;
    float v = 0.f;
    if (k < 27) {
        int tap = k / 3, c = k - tap * 3;
        int ty = tap / 3, tx = tap % 3;
        int yy = y + ty - 1, xp = xx + tx - 1;
        if (yy >= 0 && yy < 256 && xp >= 0 && xp < 256)
            v = x[c * 65536 + yy * 256 + xp];
    }
    xcol[idx] = f2bf(v);
}

// ---------------- maxpool 2x2 channels-last (strided in/out) ----------------
__global__ __launch_bounds__(TPB) void k_maxpool(
    const unsigned short* __restrict__ inI, unsigned short* __restrict__ outI,
    int Wo, int C4, int CsIn, int inPitch, int CsOut, int outPitch, int total)
{
    int idx = blockIdx.x * TPB + threadIdx.x;
    if (idx >= total) return;
    int c4 = idx % C4; int p = idx / C4;
    int x = p % Wo, y = p / Wo;
    const unsigned short* ip = inI + (size_t)(2 * y) * inPitch + (size_t)(2 * x) * CsIn + c4 * 4;
    ushort4 a = *(const ushort4*)(ip);
    ushort4 b = *(const ushort4*)(ip + CsIn);
    ushort4 c = *(const ushort4*)(ip + inPitch);
    ushort4 d = *(const ushort4*)(ip + inPitch + CsIn);
    ushort4 o;
    o.x = f2bf(fmaxf(fmaxf(bf2f(a.x), bf2f(b.x)), fmaxf(bf2f(c.x), bf2f(d.x))));
    o.y = f2bf(fmaxf(fmaxf(bf2f(a.y), bf2f(b.y)), fmaxf(bf2f(c.y), bf2f(d.y))));
    o.z = f2bf(fmaxf(fmaxf(bf2f(a.z), bf2f(b.z)), fmaxf(bf2f(c.z), bf2f(d.z))));
    o.w = f2bf(fmaxf(fmaxf(bf2f(a.w), bf2f(b.w)), fmaxf(bf2f(c.w), bf2f(d.w))));
    *(ushort4*)(outI + (size_t)y * outPitch + (size_t)x * CsOut + c4 * 4) = o;
}

// ---------------- graph aggregation on 66x66 grid, node-major bf16 ----------
__global__ __launch_bounds__(TPB) void k_gagg(
    const unsigned short* __restrict__ X, unsigned short* __restrict__ agg,
    int C, int total)
{
    int idx = blockIdx.x * TPB + threadIdx.x;
    if (idx >= total) return;
    int C4 = C >> 2;
    int c4 = idx % C4; int n = idx / C4;
    int i = n / 66, j = n - i * 66;
    size_t base = (size_t)n * C + c4 * 4;
    ushort4 s = *(const ushort4*)(X + base);
    float v0 = bf2f(s.x), v1 = bf2f(s.y), v2 = bf2f(s.z), v3 = bf2f(s.w);
    float cnt = 1.f;
    if (i > 0)  { ushort4 u = *(const ushort4*)(X + base - (size_t)66 * C);
                  v0 += bf2f(u.x); v1 += bf2f(u.y); v2 += bf2f(u.z); v3 += bf2f(u.w); cnt += 1.f; }
    if (i < 65) { ushort4 u = *(const ushort4*)(X + base + (size_t)66 * C);
                  v0 += bf2f(u.x); v1 += bf2f(u.y); v2 += bf2f(u.z); v3 += bf2f(u.w); cnt += 1.f; }
    if (j > 0)  { ushort4 u = *(const ushort4*)(X + base - C);
                  v0 += bf2f(u.x); v1 += bf2f(u.y); v2 += bf2f(u.z); v3 += bf2f(u.w); cnt += 1.f; }
    if (j < 65) { ushort4 u = *(const ushort4*)(X + base + C);
                  v0 += bf2f(u.x); v1 += bf2f(u.y); v2 += bf2f(u.z); v3 += bf2f(u.w); cnt += 1.f; }
    float inv = 1.f / cnt;
    ushort4 o;
    o.x = f2bf(v0 * inv); o.y = f2bf(v1 * inv); o.z = f2bf(v2 * inv); o.w = f2bf(v3 * inv);
    *(ushort4*)(agg + base) = o;
}

// ---------------- final conv 64->1, fp32 out --------------------------------
__global__ __launch_bounds__(TPB) void k_outconv(
    const unsigned short* __restrict__ vI, const float* __restrict__ ow,
    const float* __restrict__ ob, float* __restrict__ out)
{
    __shared__ float wl[576];
    for (int i = threadIdx.x; i < 576; i += TPB) wl[i] = ow[i];
    __syncthreads();
    int p = blockIdx.x * TPB + threadIdx.x;
    int y = p >> 8, x = p & 255;
    float acc = ob[0];
    #pragma unroll
    for (int ky = 0; ky < 3; ++ky)
        #pragma unroll
        for (int kx = 0; kx < 3; ++kx) {
            const unsigned short* ip = vI + (size_t)((y + ky - 1) * 258 + (x + kx - 1)) * 64;
            int wb = ky * 3 + kx;
            for (int c = 0; c < 64; c += 4) {
                ushort4 uv = *(const ushort4*)(ip + c);
                acc += bf2f(uv.x) * wl[c * 9 + wb] + bf2f(uv.y) * wl[(c + 1) * 9 + wb]
                     + bf2f(uv.z) * wl[(c + 2) * 9 + wb] + bf2f(uv.w) * wl[(c + 3) * 9 + wb];
            }
        }
    out[p] = acc;
}

static inline TapOffs zero_toffs() { TapOffs t = {}; return t; }

extern "C" void kernel_launch(void* const* d_in, const int* in_sizes, int n_in,
                              void* d_out, int out_size, void* d_ws, size_t ws_size,
                              hipStream_t stream) {
    const float* x    = (const float*)d_in[0];
    const float* d1w1 = (const float*)d_in[1];  const float* d1b1 = (const float*)d_in[2];
    const float* d1w2 = (const float*)d_in[3];  const float* d1b2 = (const float*)d_in[4];
    const float* d2w1 = (const float*)d_in[5];  const float* d2b1 = (const float*)d_in[6];
    const float* d2w2 = (const float*)d_in[7];  const float* d2b2 = (const float*)d_in[8];
    const float* md1w = (const float*)d_in[9];  const float* md1b = (const float*)d_in[10];
    const float* md2w = (const float*)d_in[11]; const float* md2b = (const float*)d_in[12];
    const float* mbw  = (const float*)d_in[13]; const float* mbb  = (const float*)d_in[14];
    const float* mu1w = (const float*)d_in[15]; const float* mu1b = (const float*)d_in[16];
    const float* mu2w = (const float*)d_in[17]; const float* mu2b = (const float*)d_in[18];
    const float* u3tw = (const float*)d_in[19]; const float* u3tb = (const float*)d_in[20];
    const float* u3w1 = (const float*)d_in[21]; const float* u3b1 = (const float*)d_in[22];
    const float* u3w2 = (const float*)d_in[23]; const float* u3b2 = (const float*)d_in[24];
    const float* u4tw = (const float*)d_in[25]; const float* u4tb = (const float*)d_in[26];
    const float* u4w1 = (const float*)d_in[27]; const float* u4b1 = (const float*)d_in[28];
    const float* u4w2 = (const float*)d_in[29]; const float* u4b2 = (const float*)d_in[30];
    const float* ow   = (const float*)d_in[31]; const float* ob   = (const float*)d_in[32];
    float* out = (float*)d_out;

    unsigned short* W = (unsigned short*)d_ws;

    // ---- flat arena (elem offsets, bf16) ----
    const size_t XCOL = 0;          // 2,097,152
    const size_t A1   = 2097152;    // 258*258*64
    const size_t CAT4 = 6357248;    // 258*258*128
    const size_t P1   = 14877440;   // 130*130*64
    const size_t T2   = 15959040;   // 130*130*128
    const size_t CAT3 = 18122240;   // 130*130*256
    const size_t X0   = 22448640;   // 66*66*128
    const size_t BP1  = 23006208;   // 4608*256
    const size_t BP2  = 24185856;   // 4608*512
    const size_t XB   = 26545152;   // 4608*1024
    const size_t XC   = 31263744;   // 4608*512
    const size_t XD   = 33623040;   // 4608*256
    const size_t V3A  = 34802688;   // 130*130*128
    const size_t V3B  = 36965888;   // 130*130*128
    const size_t V4A  = 39129088;   // 258*258*64
    const size_t V4B  = 43389184;   // 258*258*64
    const size_t AGG  = 47649280;   // 4608*1024
    const size_t WP   = 52367872;   // packed weights 2,320,384

    const size_t a1I   = A1 + 259 * 64;
    const size_t cat4I = CAT4 + 259 * 128;
    const size_t p1I   = P1 + 131 * 64;
    const size_t t2I   = T2 + 131 * 128;
    const size_t cat3I = CAT3 + 131 * 256;
    const size_t X0I   = X0 + 67 * 128;
    const size_t XdI   = XD + 67 * 256;
    const size_t v3aI  = V3A + 131 * 128;
    const size_t v3bI  = V3B + 131 * 128;
    const size_t v4aI  = V4A + 259 * 64;
    const size_t v4bI  = V4B + 259 * 64;

    dim3 blk(TPB);
    const int BIG = 1 << 28;

    // ---- fused pad-ring zeroing ----
    {
        ZArgs za;
        const int off[10] = {(int)A1,(int)CAT4,(int)P1,(int)T2,(int)CAT3,(int)V3A,(int)V3B,(int)V4A,(int)V4B,(int)X0};
        const int w2 [10] = {258,258,130,130,130,130,130,258,258,66};
        const int h2 [10] = {258,258,130,130,130,130,130,258,258,66};
        const int cs [10] = {64,128,64,128,256,128,128,64,64,128};
        int cum = 0;
        for (int i = 0; i < 10; ++i) {
            za.off[i]=off[i]; za.W2[i]=w2[i]; za.H2[i]=h2[i]; za.Cs[i]=cs[i];
            za.cum[i]=cum; cum += (w2[i]*h2[i] - (w2[i]-2)*(h2[i]-2))*cs[i];
        }
        za.cum[10]=cum;
        k_zero_all<<<dim3((cum + TPB - 1) / TPB), blk, 0, stream>>>(za, W, cum);
    }

    // ---- fused weight packing (R8 layout: 16x16 fragments everywhere) ----
    {
        PackArgs pa;
        const float* ws_[15] = {d1w1,d1w2,d2w1,d2w2,md1w,md2w,mbw,mu1w,mu2w,u3tw,u3w1,u3w2,u4tw,u4w1,u4w2};
        const int mode[15] = {3,0,0,0,1,1,1,1,1,2,0,0,2,0,0};
        const int kc [15] = {1,2,2,4,4,8,16,32,16,8,8,4,4,4,2};
        const int nt [15] = {4,4,8,8,16,32,64,32,16,8,8,8,4,4,4};
        const int kk [15] = {32,64,64,128,128,256,512,1024,512,256,256,128,128,128,64};
        const int nn [15] = {64,64,128,128,256,512,1024,512,256,128,128,128,64,64,64};
        const int tt [15] = {1,9,9,9,1,1,1,1,1,4,9,9,4,9,9};
        int cum = 0;
        for (int i = 0; i < 15; ++i) {
            pa.w[i]=ws_[i]; pa.mode[i]=mode[i]; pa.KC[i]=kc[i]; pa.NT[i]=nt[i];
            pa.K[i]=kk[i]; pa.N[i]=nn[i]; pa.cum[i]=cum;
            cum += tt[i]*kc[i]*nt[i]*512;
        }
        pa.cum[15]=cum;
        k_pack_all<<<dim3((cum + TPB - 1) / TPB), blk, 0, stream>>>(pa, W + WP, cum);
    }
    const size_t pw_d1w1=WP+0, pw_d1w2=WP+2048, pw_d2w1=WP+38912, pw_d2w2=WP+112640,
        pw_md1=WP+260096, pw_md2=WP+292864, pw_mb=WP+423936, pw_mu1=WP+948224,
        pw_mu2=WP+1472512, pw_u3t=WP+1603584, pw_u3w1=WP+1734656, pw_u3w2=WP+2029568,
        pw_u4t=WP+2177024, pw_u4w1=WP+2209792, pw_u4w2=WP+2283520;

    // ---- encoder ----
    k_im2col<<<dim3(8192), blk, 0, stream>>>(x, W + XCOL);
    k_gemm<2,1><<<dim3(512,1), blk, 0, stream>>>(W + XCOL, W + pw_d1w1, d1b1,
        W + a1I, 32, 8192, 256, 64, 258*64, 1, zero_toffs(), 4, 1);
    k_conv3n<1><<<dim3(1024,1), blk, 0, stream>>>(W + a1I, W + pw_d1w2, d1b2,
        W + cat4I, 258*64, 4, 128, 258*128, 4);
    k_maxpool<<<dim3(1024), blk, 0, stream>>>(W + cat4I, W + p1I, 128, 16, 128, 258*128, 64, 130*64, 128*128*16);
    k_conv3n<1><<<dim3(256,2), blk, 0, stream>>>(W + p1I, W + pw_d2w1, d2b1,
        W + t2I, 130*64, 2, 128, 130*128, 8);
    k_conv3n<2><<<dim3(256,2), blk, 0, stream>>>(W + t2I, W + pw_d2w2, d2b2,
        W + cat3I, 130*128, 2, 256, 130*256, 8);
    k_maxpool<<<dim3(512), blk, 0, stream>>>(W + cat3I, W + X0I, 64, 32, 256, 130*256, 128, 66*128, 64*64*32);

    // ---- GNN on 66x66 padded grid (separate gagg + K-split GEMMs) ----
    k_gagg<<<dim3(545), blk, 0, stream>>>(W + X0, W + AGG, 128, 4356*32);
    k_gemmS<1><<<dim3(72,4), blk, 0, stream>>>(W + AGG, W + pw_md1, md1b, nullptr,
        W + BP1, 16, 0, BIG, 256, 0, 1, 0, 0, 0);
    k_gagg<<<dim3(1089), blk, 0, stream>>>(W + BP1, W + AGG, 256, 4356*64);
    k_gemmS<2><<<dim3(72,8), blk, 0, stream>>>(W + AGG, W + pw_md2, md2b, nullptr,
        W + BP2, 32, 0, BIG, 512, 0, 1, 0, 0, 0);
    k_gagg<<<dim3(2178), blk, 0, stream>>>(W + BP2, W + AGG, 512, 4356*128);
    k_gemmS<4><<<dim3(72,16), blk, 0, stream>>>(W + AGG, W + pw_mb, mbb, nullptr,
        W + XB, 64, 0, BIG, 1024, 0, 1, 0, 0, 0);
    k_gagg<<<dim3(4356), blk, 0, stream>>>(W + XB, W + AGG, 1024, 4356*256);
    k_gemmS<8><<<dim3(72,8), blk, 0, stream>>>(W + AGG, W + pw_mu1, mu1b, W + BP2,
        W + XC, 32, 0, BIG, 512, 0, 1, 0, 0, 0);
    k_gagg<<<dim3(2178), blk, 0, stream>>>(W + XC, W + AGG, 512, 4356*128);
    k_gemmS<4><<<dim3(72,4), blk, 0, stream>>>(W + AGG, W + pw_mu2, mu2b, W + BP1,
        W + XD, 16, 0, BIG, 256, 0, 1, 0, 0, 0);

    // ---- decoder stage 3: convT (K-split, 4 taps via z) + 2 convs ----
    k_gemmS<2><<<dim3(64,2,4), blk, 0, stream>>>(W + XdI, W + pw_u3t, u3tb, nullptr,
        W + cat3I + 128, 8, 66*256, 64, 512, 2*130*256, 0, 1, 130*256, 256);
    k_conv3n<4><<<dim3(256,2), blk, 0, stream>>>(W + cat3I, W + pw_u3w1, u3b1,
        W + v3aI, 130*256, 2, 128, 130*128, 8);
    k_conv3n<2><<<dim3(256,2), blk, 0, stream>>>(W + v3aI, W + pw_u3w2, u3b2,
        W + v3bI, 130*128, 2, 128, 130*128, 8);

    // ---- decoder stage 4: convT (no-split, 4 taps via z) + 2 convs ----
    k_gemmN<4><<<dim3(256,1,4), blk, 0, stream>>>(W + v3bI, W + pw_u4t, u4tb,
        W + cat4I + 64, 128, 130*128, 128, 256, 2*258*128, 4, 0, 1, 258*128, 128);
    k_conv3n<2><<<dim3(1024,1), blk, 0, stream>>>(W + cat4I, W + pw_u4w1, u4b1,
        W + v4aI, 258*128, 4, 64, 258*64, 4);
    k_conv3n<1><<<dim3(1024,1), blk, 0, stream>>>(W + v4aI, W + pw_u4w2, u4b2,
        W + v4bI, 258*64, 4, 64, 258*64, 4);

    // ---- output conv 64->1, fp32 ----
    k_outconv<<<dim3(256), blk, 0, stream>>>(W + v4bI, ow, ob, out);
}

// Round 12
// 390.272 us; speedup vs baseline: 1.2014x; 1.1030x over previous
//
#include <hip/hip_runtime.h>
#include <cstddef>

#define TPB 256

typedef __attribute__((ext_vector_type(8))) short short8;
typedef __attribute__((ext_vector_type(4))) float f32x4;

__device__ inline unsigned short f2bf(float f) {
    unsigned int u = __builtin_bit_cast(unsigned int, f);
    u += 0x7fffu + ((u >> 16) & 1u);
    return (unsigned short)(u >> 16);
}
__device__ inline float bf2f(unsigned short h) {
    unsigned int u = ((unsigned int)h) << 16;
    return __builtin_bit_cast(float, u);
}

struct TapOffs { int o[9]; };

// ---------------------------------------------------------------------------
// 3x3 conv GEMM (R7 structure, best measured 395us): block = MW*64 px x 64 n,
// 4 waves m-split. A direct from global (channels-last, pad ring valid).
// B staged in LDS (fragment order, lane*16B conflict-free), double-buffered
// by (chunk,ky) 3-tap groups. NEW: staging uses global_load_lds width=16
// (async DMA, no VGPR round-trip; dest = wave-uniform base + lane*16B).
// mfma_f32_16x16x32_bf16: A[m=lane&15][k=(lane>>4)*8+j], B[k][n=lane&15],
// D: col(n)=lane&15, row(m)=(lane>>4)*4+reg.
// ---------------------------------------------------------------------------
template<int CHUNKS, int MW>   // input channels = CHUNKS*64
__global__ __launch_bounds__(TPB) void k_conv3s(
    const unsigned short* __restrict__ A0, const unsigned short* __restrict__ Wf,
    const float* __restrict__ bias, unsigned short* __restrict__ O0,
    int AP, int tilesX, int OMS, int OP, int NTtot)
{
    constexpr int Cs  = CHUNKS * 64;
    constexpr int KC2 = CHUNKS * 2;          // k32-steps per tap (whole K)
    __shared__ unsigned short Bs[2][12288];  // 2 x 24,576 B

    int lane = threadIdx.x & 63, wave = threadIdx.x >> 6;
    int ml = lane & 15, kq = lane >> 4;
    int nb = blockIdx.y;
    int tileX = blockIdx.x % tilesX, gy = blockIdx.x / tilesX;
    int gx0 = tileX * (MW * 64) + wave * (MW * 16);

    const unsigned short* Abase = A0 + (size_t)(gy - 1) * AP
                                     + (size_t)(gx0 + ml - 1) * Cs + kq * 8;

    f32x4 acc[MW][4];
    #pragma unroll
    for (int mf = 0; mf < MW; ++mf)
        #pragma unroll
        for (int nt = 0; nt < 4; ++nt) acc[mf][nt] = (f32x4){0.f, 0.f, 0.f, 0.f};

    const int G = CHUNKS * 3;   // groups: (chunk, ky)

    // async global->LDS staging: dest is wave-uniform base + lane*16B
    auto stageB = [&](int g) {
        int ch = g / 3, ky = g - (g / 3) * 3;
        unsigned short* bd = Bs[g & 1];
        #pragma unroll
        for (int it = 0; it < 6; ++it) {
            int u = threadIdx.x + it * TPB;     // 1536 16B-chunks total
            int e = u * 8;
            int kxq = e >> 11;                  // [kx*2+q] 0..5 (wave-uniform)
            int rem = e & 2047;
            int kx = kxq >> 1, q = kxq & 1;
            const unsigned short* src = Wf
                + ((size_t)((ky * 3 + kx) * KC2 + ch * 2 + q) * NTtot + nb * 4) * 512 + rem;
            unsigned short* dst = &bd[(u & ~63) * 8];   // wave-uniform
            __builtin_amdgcn_global_load_lds(
                (const __attribute__((address_space(1))) unsigned int*)src,
                (__attribute__((address_space(3))) unsigned int*)dst, 16, 0, 0);
        }
    };

    stageB(0);
    __syncthreads();
    for (int g = 0; g < G; ++g) {
        if (g + 1 < G) stageB(g + 1);
        int ch = g / 3, ky = g - (g / 3) * 3;
        const unsigned short* Ar = Abase + (size_t)ky * AP + ch * 64;
        const unsigned short* Bb = &Bs[g & 1][lane * 8];
        #pragma unroll
        for (int kx = 0; kx < 3; ++kx) {
            #pragma unroll
            for (int q = 0; q < 2; ++q) {
                short8 b[4];
                #pragma unroll
                for (int nt = 0; nt < 4; ++nt)
                    b[nt] = *(const short8*)(Bb + (kx * 2 + q) * 2048 + nt * 512);
                short8 a[MW];
                #pragma unroll
                for (int mf = 0; mf < MW; ++mf)
                    a[mf] = *(const short8*)(Ar + (size_t)(kx + mf * 16) * Cs + q * 32);
                #pragma unroll
                for (int mf = 0; mf < MW; ++mf)
                    #pragma unroll
                    for (int nt = 0; nt < 4; ++nt)
                        acc[mf][nt] = __builtin_amdgcn_mfma_f32_16x16x32_bf16(a[mf], b[nt], acc[mf][nt], 0, 0, 0);
            }
        }
        __syncthreads();
    }

    unsigned short* Orow = O0 + (size_t)gy * OP + (size_t)nb * 64;
    #pragma unroll
    for (int mf = 0; mf < MW; ++mf) {
        int gx = gx0 + mf * 16 + kq * 4;
        #pragma unroll
        for (int nt = 0; nt < 4; ++nt) {
            float bv = bias[nb * 64 + nt * 16 + ml];
            #pragma unroll
            for (int r = 0; r < 4; ++r) {
                float v = fmaxf(acc[mf][nt][r] + bv, 0.f);
                Orow[(size_t)(gx + r) * OMS + nt * 16 + ml] = f2bf(v);
            }
        }
    }
}

// ---------------------------------------------------------------------------
// K-split GEMM (GNN + convT u3t): block = 64m x 64n, 4 waves each K/4, LDS
// cross-wave reduce (rotated slice order so own slice is acc[0]). R8-proven.
// ---------------------------------------------------------------------------
template<int KCW>   // k32-steps per wave; K = KCW*128
__global__ __launch_bounds__(TPB) void k_gemmS(
    const unsigned short* __restrict__ A0, const unsigned short* __restrict__ Wf,
    const float* __restrict__ bias, const unsigned short* __restrict__ resid,
    unsigned short* __restrict__ O0, int NTtot,
    int AP, int Wimg, int OMS, int OP, int relu, int ct, int ctDy, int ctDx)
{
    constexpr int K = KCW * 128;
    __shared__ float red[12 * 4 * 64 * 4];   // 49,152 B
    int lane = threadIdx.x & 63, wave = threadIdx.x >> 6;
    int ml = lane & 15, kq = lane >> 4;
    int m0 = blockIdx.x * 64, nb = blockIdx.y;

    const unsigned short* Wb = Wf;
    unsigned short* Ob = O0;
    if (ct) {
        int tp = blockIdx.z;
        Wb += (size_t)(tp * KCW * 4) * NTtot * 512;
        int dy = 1 - (tp >> 1), dx = 1 - (tp & 1);   // jax conv_transpose tap flip
        Ob += (size_t)dy * ctDy + (size_t)dx * ctDx;
    }

    const unsigned short* Ap[4];
    #pragma unroll
    for (int i = 0; i < 4; ++i) {
        int mf = (wave + i) & 3;
        int m = m0 + mf * 16;
        int y = m / Wimg, x = m - y * Wimg;
        Ap[i] = A0 + (size_t)y * AP + (size_t)(x + ml) * K + wave * (KCW * 32) + kq * 8;
    }
    const unsigned short* Bp = Wb + ((size_t)(wave * KCW) * NTtot + nb * 4) * 512 + lane * 8;

    f32x4 acc[4][4];
    #pragma unroll
    for (int i = 0; i < 4; ++i)
        #pragma unroll
        for (int nt = 0; nt < 4; ++nt) acc[i][nt] = (f32x4){0.f, 0.f, 0.f, 0.f};

    #pragma unroll
    for (int q = 0; q < KCW; ++q) {
        short8 b[4];
        #pragma unroll
        for (int nt = 0; nt < 4; ++nt)
            b[nt] = *(const short8*)(Bp + ((size_t)q * NTtot + nt) * 512);
        short8 a[4];
        #pragma unroll
        for (int i = 0; i < 4; ++i)
            a[i] = *(const short8*)(Ap[i] + q * 32);
        #pragma unroll
        for (int i = 0; i < 4; ++i)
            #pragma unroll
            for (int nt = 0; nt < 4; ++nt)
                acc[i][nt] = __builtin_amdgcn_mfma_f32_16x16x32_bf16(a[i], b[nt], acc[i][nt], 0, 0, 0);
    }

    #pragma unroll
    for (int i = 1; i < 4; ++i) {
        int s = wave * 3 + (i - 1);
        #pragma unroll
        for (int nt = 0; nt < 4; ++nt)
            *(f32x4*)&red[(((s * 4 + nt) * 64) + lane) * 4] = acc[i][nt];
    }
    __syncthreads();
    #pragma unroll
    for (int w2 = 0; w2 < 4; ++w2) {
        if (w2 == wave) continue;
        int i = (wave - w2) & 3;
        int s = w2 * 3 + (i - 1);
        #pragma unroll
        for (int nt = 0; nt < 4; ++nt) {
            f32x4 v = *(const f32x4*)&red[(((s * 4 + nt) * 64) + lane) * 4];
            acc[0][nt] += v;
        }
    }

    int mrow = m0 + wave * 16 + kq * 4;
    int y = mrow / Wimg, x = mrow - y * Wimg;
    unsigned short* Ot = Ob + (size_t)y * OP + (size_t)x * OMS + nb * 64;
    const unsigned short* Rt = resid ? resid + (size_t)mrow * OMS + nb * 64 : nullptr;
    #pragma unroll
    for (int nt = 0; nt < 4; ++nt) {
        float bv = bias[nb * 64 + nt * 16 + ml];
        #pragma unroll
        for (int r = 0; r < 4; ++r) {
            float v = acc[0][nt][r] + bv;
            if (relu) v = fmaxf(v, 0.f);
            if (Rt) v += bf2f(Rt[(size_t)r * OMS + nt * 16 + ml]);
            Ot[(size_t)r * OMS + nt * 16 + ml] = f2bf(v);
        }
    }
}

// ---------------------------------------------------------------------------
// No-split GEMM (convT u4t): 4 waves m-split, whole K, B from global (L1).
// ---------------------------------------------------------------------------
template<int KC>   // q-steps; K = KC*32
__global__ __launch_bounds__(TPB) void k_gemmN(
    const unsigned short* __restrict__ A0, const unsigned short* __restrict__ Wf,
    const float* __restrict__ bias, unsigned short* __restrict__ O0,
    int Cs, int AP, int Wimg, int OMS, int OP, int NTtot, int relu,
    int ct, int ctDy, int ctDx)
{
    int lane = threadIdx.x & 63, wave = threadIdx.x >> 6;
    int ml = lane & 15, kq = lane >> 4;
    int nb = blockIdx.y;

    const unsigned short* Wb = Wf;
    unsigned short* Ob = O0;
    if (ct) {
        int tp = blockIdx.z;
        Wb += (size_t)(tp * KC) * NTtot * 512;
        int dy = 1 - (tp >> 1), dx = 1 - (tp & 1);
        Ob += (size_t)dy * ctDy + (size_t)dx * ctDx;
    }
    int m0 = blockIdx.x * 64 + wave * 16;
    int y = m0 / Wimg, x = m0 - y * Wimg;
    const unsigned short* Arow = A0 + (size_t)y * AP + (size_t)(x + ml) * Cs + kq * 8;
    const unsigned short* Bp = Wb + (size_t)(nb * 4) * 512 + lane * 8;

    f32x4 acc[4];
    #pragma unroll
    for (int nt = 0; nt < 4; ++nt) acc[nt] = (f32x4){0.f, 0.f, 0.f, 0.f};

    #pragma unroll
    for (int q = 0; q < KC; ++q) {
        short8 b[4];
        #pragma unroll
        for (int nt = 0; nt < 4; ++nt)
            b[nt] = *(const short8*)(Bp + ((size_t)q * NTtot + nt) * 512);
        short8 a = *(const short8*)(Arow + q * 32);
        #pragma unroll
        for (int nt = 0; nt < 4; ++nt)
            acc[nt] = __builtin_amdgcn_mfma_f32_16x16x32_bf16(a, b[nt], acc[nt], 0, 0, 0);
    }

    unsigned short* Ot = Ob + (size_t)y * OP + (size_t)(x + kq * 4) * OMS + (size_t)nb * 64;
    #pragma unroll
    for (int nt = 0; nt < 4; ++nt) {
        float bv = bias[nb * 64 + nt * 16 + ml];
        #pragma unroll
        for (int r = 0; r < 4; ++r) {
            float v = acc[nt][r] + bv;
            if (relu) v = fmaxf(v, 0.f);
            Ot[(size_t)r * OMS + nt * 16 + ml] = f2bf(v);
        }
    }
}

// ---------------------------------------------------------------------------
// Generic MFMA GEMM (global-direct) — used only for conv1 (K=32 im2col).
// ---------------------------------------------------------------------------
template<int MW, int KC>
__global__ __launch_bounds__(TPB) void k_gemm(
    const unsigned short* __restrict__ A0, const unsigned short* __restrict__ Wf,
    const float* __restrict__ bias, unsigned short* __restrict__ O0,
    int Cs, int AP, int Wimg, int OMS, int OP,
    int T, TapOffs toffs, int NTtot, int relu)
{
    int lane = threadIdx.x & 63, wave = threadIdx.x >> 6;
    int ml = lane & 15, kq = lane >> 4;
    int nb = blockIdx.y;
    const unsigned short* WbB = Wf + (size_t)(nb * 4) * 512 + lane * 8;

    int fy[MW], fx[MW];
    const unsigned short* Af[MW];
    #pragma unroll
    for (int f = 0; f < MW; ++f) {
        int mf = (blockIdx.x * 4 + wave) * (16 * MW) + f * 16;
        int y = mf / Wimg, x = mf - y * Wimg;
        fy[f] = y; fx[f] = x;
        Af[f] = A0 + (size_t)y * AP + (size_t)(x + ml) * Cs + kq * 8;
    }

    f32x4 acc[MW][4];
    #pragma unroll
    for (int f = 0; f < MW; ++f)
        #pragma unroll
        for (int nt = 0; nt < 4; ++nt) acc[f][nt] = (f32x4){0.f, 0.f, 0.f, 0.f};

    for (int tp = 0; tp < T; ++tp) {
        int toff = toffs.o[tp];
        const unsigned short* Wt = WbB + (size_t)(tp * KC) * NTtot * 512;
        #pragma unroll
        for (int q = 0; q < KC; ++q) {
            short8 b[4];
            #pragma unroll
            for (int nt = 0; nt < 4; ++nt)
                b[nt] = *(const short8*)(Wt + (size_t)q * NTtot * 512 + nt * 512);
            short8 a[MW];
            #pragma unroll
            for (int f = 0; f < MW; ++f)
                a[f] = *(const short8*)(Af[f] + toff + q * 32);
            #pragma unroll
            for (int f = 0; f < MW; ++f)
                #pragma unroll
                for (int nt = 0; nt < 4; ++nt)
                    acc[f][nt] = __builtin_amdgcn_mfma_f32_16x16x32_bf16(a[f], b[nt], acc[f][nt], 0, 0, 0);
        }
    }

    #pragma unroll
    for (int f = 0; f < MW; ++f) {
        unsigned short* Ot = O0 + (size_t)fy[f] * OP + (size_t)(fx[f] + kq * 4) * OMS + (size_t)nb * 64;
        #pragma unroll
        for (int nt = 0; nt < 4; ++nt) {
            float bv = bias[nb * 64 + nt * 16 + ml];
            #pragma unroll
            for (int r = 0; r < 4; ++r) {
                float v = acc[f][nt][r] + bv;
                if (relu) v = fmaxf(v, 0.f);
                Ot[(size_t)r * OMS + nt * 16 + ml] = f2bf(v);
            }
        }
    }
}

// ---------------- fused weight packing (all 15 tensors, one dispatch) -------
struct PackArgs {
    const float* w[15];
    int cum[16];
    int mode[15], KC[15], NT[15], K[15], N[15];
};
__global__ __launch_bounds__(TPB) void k_pack_all(
    PackArgs pa, unsigned short* __restrict__ dst, int total)
{
    int idx = blockIdx.x * TPB + threadIdx.x;
    if (idx >= total) return;
    int e = 0;
    #pragma unroll
    for (int i = 1; i < 15; ++i) e += (idx >= pa.cum[i]);
    int local = idx - pa.cum[e];
    const float* w = pa.w[e];
    int KC = pa.KC[e], NT = pa.NT[e], K = pa.K[e], N = pa.N[e], mode = pa.mode[e];

    int j = local & 7, l = (local >> 3) & 63;
    int r = local >> 9;
    int ntg = r % NT; int r2 = r / NT;
    int q = r2 % KC; int tp = r2 / KC;
    int k = q * 32 + (l >> 4) * 8 + j;
    int n = ntg * 16 + (l & 15);
    float v = 0.f;
    if (mode == 0) { int ky = tp / 3, kx = tp % 3; v = w[(size_t)(n * K + k) * 9 + ky * 3 + kx]; }
    else if (mode == 1) { v = w[(size_t)k * N + n]; }
    else if (mode == 2) { v = w[((size_t)tp * K + k) * N + n]; }
    else { if (k < 27) { int tap = k / 3, c = k % 3; int ky = tap / 3, kx = tap % 3;
                         v = w[((n * 3 + c) * 3 + ky) * 3 + kx]; } }
    dst[idx] = f2bf(v);
}

// ---------------- fused pad-ring zeroing (all buffers, one dispatch) --------
struct ZArgs { int off[10]; int cum[11]; int W2[10]; int H2[10]; int Cs[10]; };
__global__ __launch_bounds__(TPB) void k_zero_all(
    ZArgs za, unsigned short* __restrict__ W, int total)
{
    int idx = blockIdx.x * TPB + threadIdx.x;
    if (idx >= total) return;
    int e = 0;
    #pragma unroll
    for (int i = 1; i < 10; ++i) e += (idx >= za.cum[i]);
    int local = idx - za.cum[e];
    int W2 = za.W2[e], H2 = za.H2[e], Cs = za.Cs[e];
    int topbot = 2 * W2 * Cs;
    int iy, ix, c;
    if (local < topbot) {
        int row = local / (W2 * Cs); int rest = local - row * (W2 * Cs);
        iy = row ? (H2 - 1) : 0; ix = rest / Cs; c = rest - (rest / Cs) * Cs;
    } else {
        int idx2 = local - topbot;
        int per = (H2 - 2) * Cs;
        int side = idx2 / per; int rest = idx2 - side * per;
        iy = 1 + rest / Cs; ix = side ? (W2 - 1) : 0; c = rest - (rest / Cs) * Cs;
    }
    W[(size_t)za.off[e] + ((size_t)iy * W2 + ix) * Cs + c] = 0;
}

// ---------------- conv1 im2col: x fp32 [3][256][256] -> xcol bf16 [65536][32]
__global__ __launch_bounds__(TPB) void k_im2col(
    const float* __restrict__ x, unsigned short* __restrict__ xcol)
{
    int idx = blockIdx.x * TPB + threadIdx.x;
    if (idx >= 65536 * 32) return;
    int k = idx & 31, m = idx >> 5;
    int y = m >> 8, xx = m & 255;
    float v = 0.f;
    if (k < 27) {
        int tap = k / 3, c = k - tap * 3;
        int ty = tap / 3, tx = tap % 3;
        int yy = y + ty - 1, xp = xx + tx - 1;
        if (yy >= 0 && yy < 256 && xp >= 0 && xp < 256)
            v = x[c * 65536 + yy * 256 + xp];
    }
    xcol[idx] = f2bf(v);
}

// ---------------- maxpool 2x2 channels-last (strided in/out) ----------------
__global__ __launch_bounds__(TPB) void k_maxpool(
    const unsigned short* __restrict__ inI, unsigned short* __restrict__ outI,
    int Wo, int C4, int CsIn, int inPitch, int CsOut, int outPitch, int total)
{
    int idx = blockIdx.x * TPB + threadIdx.x;
    if (idx >= total) return;
    int c4 = idx % C4; int p = idx / C4;
    int x = p % Wo, y = p / Wo;
    const unsigned short* ip = inI + (size_t)(2 * y) * inPitch + (size_t)(2 * x) * CsIn + c4 * 4;
    ushort4 a = *(const ushort4*)(ip);
    ushort4 b = *(const ushort4*)(ip + CsIn);
    ushort4 c = *(const ushort4*)(ip + inPitch);
    ushort4 d = *(const ushort4*)(ip + inPitch + CsIn);
    ushort4 o;
    o.x = f2bf(fmaxf(fmaxf(bf2f(a.x), bf2f(b.x)), fmaxf(bf2f(c.x), bf2f(d.x))));
    o.y = f2bf(fmaxf(fmaxf(bf2f(a.y), bf2f(b.y)), fmaxf(bf2f(c.y), bf2f(d.y))));
    o.z = f2bf(fmaxf(fmaxf(bf2f(a.z), bf2f(b.z)), fmaxf(bf2f(c.z), bf2f(d.z))));
    o.w = f2bf(fmaxf(fmaxf(bf2f(a.w), bf2f(b.w)), fmaxf(bf2f(c.w), bf2f(d.w))));
    *(ushort4*)(outI + (size_t)y * outPitch + (size_t)x * CsOut + c4 * 4) = o;
}

// ---------------- graph aggregation on 66x66 grid, node-major bf16 ----------
__global__ __launch_bounds__(TPB) void k_gagg(
    const unsigned short* __restrict__ X, unsigned short* __restrict__ agg,
    int C, int total)
{
    int idx = blockIdx.x * TPB + threadIdx.x;
    if (idx >= total) return;
    int C4 = C >> 2;
    int c4 = idx % C4; int n = idx / C4;
    int i = n / 66, j = n - i * 66;
    size_t base = (size_t)n * C + c4 * 4;
    ushort4 s = *(const ushort4*)(X + base);
    float v0 = bf2f(s.x), v1 = bf2f(s.y), v2 = bf2f(s.z), v3 = bf2f(s.w);
    float cnt = 1.f;
    if (i > 0)  { ushort4 u = *(const ushort4*)(X + base - (size_t)66 * C);
                  v0 += bf2f(u.x); v1 += bf2f(u.y); v2 += bf2f(u.z); v3 += bf2f(u.w); cnt += 1.f; }
    if (i < 65) { ushort4 u = *(const ushort4*)(X + base + (size_t)66 * C);
                  v0 += bf2f(u.x); v1 += bf2f(u.y); v2 += bf2f(u.z); v3 += bf2f(u.w); cnt += 1.f; }
    if (j > 0)  { ushort4 u = *(const ushort4*)(X + base - C);
                  v0 += bf2f(u.x); v1 += bf2f(u.y); v2 += bf2f(u.z); v3 += bf2f(u.w); cnt += 1.f; }
    if (j < 65) { ushort4 u = *(const ushort4*)(X + base + C);
                  v0 += bf2f(u.x); v1 += bf2f(u.y); v2 += bf2f(u.z); v3 += bf2f(u.w); cnt += 1.f; }
    float inv = 1.f / cnt;
    ushort4 o;
    o.x = f2bf(v0 * inv); o.y = f2bf(v1 * inv); o.z = f2bf(v2 * inv); o.w = f2bf(v3 * inv);
    *(ushort4*)(agg + base) = o;
}

// ---------------- final conv 64->1, fp32 out --------------------------------
__global__ __launch_bounds__(TPB) void k_outconv(
    const unsigned short* __restrict__ vI, const float* __restrict__ ow,
    const float* __restrict__ ob, float* __restrict__ out)
{
    __shared__ float wl[576];
    for (int i = threadIdx.x; i < 576; i += TPB) wl[i] = ow[i];
    __syncthreads();
    int p = blockIdx.x * TPB + threadIdx.x;
    int y = p >> 8, x = p & 255;
    float acc = ob[0];
    #pragma unroll
    for (int ky = 0; ky < 3; ++ky)
        #pragma unroll
        for (int kx = 0; kx < 3; ++kx) {
            const unsigned short* ip = vI + (size_t)((y + ky - 1) * 258 + (x + kx - 1)) * 64;
            int wb = ky * 3 + kx;
            for (int c = 0; c < 64; c += 4) {
                ushort4 uv = *(const ushort4*)(ip + c);
                acc += bf2f(uv.x) * wl[c * 9 + wb] + bf2f(uv.y) * wl[(c + 1) * 9 + wb]
                     + bf2f(uv.z) * wl[(c + 2) * 9 + wb] + bf2f(uv.w) * wl[(c + 3) * 9 + wb];
            }
        }
    out[p] = acc;
}

static inline TapOffs zero_toffs() { TapOffs t = {}; return t; }

extern "C" void kernel_launch(void* const* d_in, const int* in_sizes, int n_in,
                              void* d_out, int out_size, void* d_ws, size_t ws_size,
                              hipStream_t stream) {
    const float* x    = (const float*)d_in[0];
    const float* d1w1 = (const float*)d_in[1];  const float* d1b1 = (const float*)d_in[2];
    const float* d1w2 = (const float*)d_in[3];  const float* d1b2 = (const float*)d_in[4];
    const float* d2w1 = (const float*)d_in[5];  const float* d2b1 = (const float*)d_in[6];
    const float* d2w2 = (const float*)d_in[7];  const float* d2b2 = (const float*)d_in[8];
    const float* md1w = (const float*)d_in[9];  const float* md1b = (const float*)d_in[10];
    const float* md2w = (const float*)d_in[11]; const float* md2b = (const float*)d_in[12];
    const float* mbw  = (const float*)d_in[13]; const float* mbb  = (const float*)d_in[14];
    const float* mu1w = (const float*)d_in[15]; const float* mu1b = (const float*)d_in[16];
    const float* mu2w = (const float*)d_in[17]; const float* mu2b = (const float*)d_in[18];
    const float* u3tw = (const float*)d_in[19]; const float* u3tb = (const float*)d_in[20];
    const float* u3w1 = (const float*)d_in[21]; const float* u3b1 = (const float*)d_in[22];
    const float* u3w2 = (const float*)d_in[23]; const float* u3b2 = (const float*)d_in[24];
    const float* u4tw = (const float*)d_in[25]; const float* u4tb = (const float*)d_in[26];
    const float* u4w1 = (const float*)d_in[27]; const float* u4b1 = (const float*)d_in[28];
    const float* u4w2 = (const float*)d_in[29]; const float* u4b2 = (const float*)d_in[30];
    const float* ow   = (const float*)d_in[31]; const float* ob   = (const float*)d_in[32];
    float* out = (float*)d_out;

    unsigned short* W = (unsigned short*)d_ws;

    // ---- flat arena (elem offsets, bf16) ----
    const size_t XCOL = 0;          // 2,097,152
    const size_t A1   = 2097152;    // 258*258*64
    const size_t CAT4 = 6357248;    // 258*258*128
    const size_t P1   = 14877440;   // 130*130*64
    const size_t T2   = 15959040;   // 130*130*128
    const size_t CAT3 = 18122240;   // 130*130*256
    const size_t X0   = 22448640;   // 66*66*128
    const size_t BP1  = 23006208;   // 4608*256
    const size_t BP2  = 24185856;   // 4608*512
    const size_t XB   = 26545152;   // 4608*1024
    const size_t XC   = 31263744;   // 4608*512
    const size_t XD   = 33623040;   // 4608*256
    const size_t V3A  = 34802688;   // 130*130*128
    const size_t V3B  = 36965888;   // 130*130*128
    const size_t V4A  = 39129088;   // 258*258*64
    const size_t V4B  = 43389184;   // 258*258*64
    const size_t AGG  = 47649280;   // 4608*1024
    const size_t WP   = 52367872;   // packed weights 2,320,384

    const size_t a1I   = A1 + 259 * 64;
    const size_t cat4I = CAT4 + 259 * 128;
    const size_t p1I   = P1 + 131 * 64;
    const size_t t2I   = T2 + 131 * 128;
    const size_t cat3I = CAT3 + 131 * 256;
    const size_t X0I   = X0 + 67 * 128;
    const size_t XdI   = XD + 67 * 256;
    const size_t v3aI  = V3A + 131 * 128;
    const size_t v3bI  = V3B + 131 * 128;
    const size_t v4aI  = V4A + 259 * 64;
    const size_t v4bI  = V4B + 259 * 64;

    dim3 blk(TPB);
    const int BIG = 1 << 28;

    // ---- fused pad-ring zeroing ----
    {
        ZArgs za;
        const int off[10] = {(int)A1,(int)CAT4,(int)P1,(int)T2,(int)CAT3,(int)V3A,(int)V3B,(int)V4A,(int)V4B,(int)X0};
        const int w2 [10] = {258,258,130,130,130,130,130,258,258,66};
        const int h2 [10] = {258,258,130,130,130,130,130,258,258,66};
        const int cs [10] = {64,128,64,128,256,128,128,64,64,128};
        int cum = 0;
        for (int i = 0; i < 10; ++i) {
            za.off[i]=off[i]; za.W2[i]=w2[i]; za.H2[i]=h2[i]; za.Cs[i]=cs[i];
            za.cum[i]=cum; cum += (w2[i]*h2[i] - (w2[i]-2)*(h2[i]-2))*cs[i];
        }
        za.cum[10]=cum;
        k_zero_all<<<dim3((cum + TPB - 1) / TPB), blk, 0, stream>>>(za, W, cum);
    }

    // ---- fused weight packing (16x16 fragment layout) ----
    {
        PackArgs pa;
        const float* ws_[15] = {d1w1,d1w2,d2w1,d2w2,md1w,md2w,mbw,mu1w,mu2w,u3tw,u3w1,u3w2,u4tw,u4w1,u4w2};
        const int mode[15] = {3,0,0,0,1,1,1,1,1,2,0,0,2,0,0};
        const int kc [15] = {1,2,2,4,4,8,16,32,16,8,8,4,4,4,2};
        const int nt [15] = {4,4,8,8,16,32,64,32,16,8,8,8,4,4,4};
        const int kk [15] = {32,64,64,128,128,256,512,1024,512,256,256,128,128,128,64};
        const int nn [15] = {64,64,128,128,256,512,1024,512,256,128,128,128,64,64,64};
        const int tt [15] = {1,9,9,9,1,1,1,1,1,4,9,9,4,9,9};
        int cum = 0;
        for (int i = 0; i < 15; ++i) {
            pa.w[i]=ws_[i]; pa.mode[i]=mode[i]; pa.KC[i]=kc[i]; pa.NT[i]=nt[i];
            pa.K[i]=kk[i]; pa.N[i]=nn[i]; pa.cum[i]=cum;
            cum += tt[i]*kc[i]*nt[i]*512;
        }
        pa.cum[15]=cum;
        k_pack_all<<<dim3((cum + TPB - 1) / TPB), blk, 0, stream>>>(pa, W + WP, cum);
    }
    const size_t pw_d1w1=WP+0, pw_d1w2=WP+2048, pw_d2w1=WP+38912, pw_d2w2=WP+112640,
        pw_md1=WP+260096, pw_md2=WP+292864, pw_mb=WP+423936, pw_mu1=WP+948224,
        pw_mu2=WP+1472512, pw_u3t=WP+1603584, pw_u3w1=WP+1734656, pw_u3w2=WP+2029568,
        pw_u4t=WP+2177024, pw_u4w1=WP+2209792, pw_u4w2=WP+2283520;

    // ---- encoder ----
    k_im2col<<<dim3(8192), blk, 0, stream>>>(x, W + XCOL);
    k_gemm<2,1><<<dim3(512,1), blk, 0, stream>>>(W + XCOL, W + pw_d1w1, d1b1,
        W + a1I, 32, 8192, 256, 64, 258*64, 1, zero_toffs(), 4, 1);
    k_conv3s<1,2><<<dim3(512,1), blk, 0, stream>>>(W + a1I, W + pw_d1w2, d1b2,
        W + cat4I, 258*64, 2, 128, 258*128, 4);
    k_maxpool<<<dim3(1024), blk, 0, stream>>>(W + cat4I, W + p1I, 128, 16, 128, 258*128, 64, 130*64, 128*128*16);
    k_conv3s<1,1><<<dim3(256,2), blk, 0, stream>>>(W + p1I, W + pw_d2w1, d2b1,
        W + t2I, 130*64, 2, 128, 130*128, 8);
    k_conv3s<2,1><<<dim3(256,2), blk, 0, stream>>>(W + t2I, W + pw_d2w2, d2b2,
        W + cat3I, 130*128, 2, 256, 130*256, 8);
    k_maxpool<<<dim3(512), blk, 0, stream>>>(W + cat3I, W + X0I, 64, 32, 256, 130*256, 128, 66*128, 64*64*32);

    // ---- GNN on 66x66 padded grid (separate gagg + K-split GEMMs) ----
    k_gagg<<<dim3(545), blk, 0, stream>>>(W + X0, W + AGG, 128, 4356*32);
    k_gemmS<1><<<dim3(72,4), blk, 0, stream>>>(W + AGG, W + pw_md1, md1b, nullptr,
        W + BP1, 16, 0, BIG, 256, 0, 1, 0, 0, 0);
    k_gagg<<<dim3(1089), blk, 0, stream>>>(W + BP1, W + AGG, 256, 4356*64);
    k_gemmS<2><<<dim3(72,8), blk, 0, stream>>>(W + AGG, W + pw_md2, md2b, nullptr,
        W + BP2, 32, 0, BIG, 512, 0, 1, 0, 0, 0);
    k_gagg<<<dim3(2178), blk, 0, stream>>>(W + BP2, W + AGG, 512, 4356*128);
    k_gemmS<4><<<dim3(72,16), blk, 0, stream>>>(W + AGG, W + pw_mb, mbb, nullptr,
        W + XB, 64, 0, BIG, 1024, 0, 1, 0, 0, 0);
    k_gagg<<<dim3(4356), blk, 0, stream>>>(W + XB, W + AGG, 1024, 4356*256);
    k_gemmS<8><<<dim3(72,8), blk, 0, stream>>>(W + AGG, W + pw_mu1, mu1b, W + BP2,
        W + XC, 32, 0, BIG, 512, 0, 1, 0, 0, 0);
    k_gagg<<<dim3(2178), blk, 0, stream>>>(W + XC, W + AGG, 512, 4356*128);
    k_gemmS<4><<<dim3(72,4), blk, 0, stream>>>(W + AGG, W + pw_mu2, mu2b, W + BP1,
        W + XD, 16, 0, BIG, 256, 0, 1, 0, 0, 0);

    // ---- decoder stage 3: convT (K-split, 4 taps via z) + 2 convs ----
    k_gemmS<2><<<dim3(64,2,4), blk, 0, stream>>>(W + XdI, W + pw_u3t, u3tb, nullptr,
        W + cat3I + 128, 8, 66*256, 64, 512, 2*130*256, 0, 1, 130*256, 256);
    k_conv3s<4,1><<<dim3(256,2), blk, 0, stream>>>(W + cat3I, W + pw_u3w1, u3b1,
        W + v3aI, 130*256, 2, 128, 130*128, 8);
    k_conv3s<2,1><<<dim3(256,2), blk, 0, stream>>>(W + v3aI, W + pw_u3w2, u3b2,
        W + v3bI, 130*128, 2, 128, 130*128, 8);

    // ---- decoder stage 4: convT (no-split, 4 taps via z) + 2 convs ----
    k_gemmN<4><<<dim3(256,1,4), blk, 0, stream>>>(W + v3bI, W + pw_u4t, u4tb,
        W + cat4I + 64, 128, 130*128, 128, 256, 2*258*128, 4, 0, 1, 258*128, 128);
    k_conv3s<2,2><<<dim3(512,1), blk, 0, stream>>>(W + cat4I, W + pw_u4w1, u4b1,
        W + v4aI, 258*128, 2, 64, 258*64, 4);
    k_conv3s<1,2><<<dim3(512,1), blk, 0, stream>>>(W + v4aI, W + pw_u4w2, u4b2,
        W + v4bI, 258*64, 2, 64, 258*64, 4);

    // ---- output conv 64->1, fp32 ----
    k_outconv<<<dim3(256), blk, 0, stream>>>(W + v4bI, ow, ob, out);
}

// Round 13
// 389.262 us; speedup vs baseline: 1.2046x; 1.0026x over previous
//
#include <hip/hip_runtime.h>
#include <cstddef>

#define TPB 256

typedef __attribute__((ext_vector_type(8))) short short8;
typedef __attribute__((ext_vector_type(4))) float f32x4;

__device__ inline unsigned short f2bf(float f) {
    unsigned int u = __builtin_bit_cast(unsigned int, f);
    u += 0x7fffu + ((u >> 16) & 1u);
    return (unsigned short)(u >> 16);
}
__device__ inline float bf2f(unsigned short h) {
    unsigned int u = ((unsigned int)h) << 16;
    return __builtin_bit_cast(float, u);
}

struct TapOffs { int o[9]; };

// ---------------------------------------------------------------------------
// Whole-B-in-LDS 3x3 conv (CHUNKS=1 layers): block = MW*64 px x 64 n, 4 waves
// m-split. Per-block B slice (this nb's 64 cols, all 9 taps) = 72 KB -> fits
// LDS at 2 blocks/CU, and these layers' grids are already 2 blocks/CU, so no
// occupancy cost. ONE __syncthreads total (vs 4-10 in conv3s): after async
// global_load_lds staging, 108*MW MFMAs run straight-line with A-loads
// free-flowing (no vmcnt(0) barrier drains).
// mfma_f32_16x16x32_bf16: A[m=lane&15][k=(lane>>4)*8+j], B[k][n=lane&15],
// D: col(n)=lane&15, row(m)=(lane>>4)*4+reg.
// ---------------------------------------------------------------------------
template<int CHUNKS, int MW>   // CHUNKS must be 1 here (72 KB LDS)
__global__ __launch_bounds__(TPB) void k_conv3w(
    const unsigned short* __restrict__ A0, const unsigned short* __restrict__ Wf,
    const float* __restrict__ bias, unsigned short* __restrict__ O0,
    int AP, int tilesX, int OMS, int OP, int NTtot)
{
    constexpr int Cs  = CHUNKS * 64;
    constexpr int KC2 = CHUNKS * 2;              // k32-steps per tap
    constexpr int TOT = 9 * KC2 * 4 * 512;       // elems (CHUNKS=1: 36,864 = 72 KB)
    __shared__ unsigned short Bs[TOT];

    int lane = threadIdx.x & 63, wave = threadIdx.x >> 6;
    int ml = lane & 15, kq = lane >> 4;
    int nb = blockIdx.y;
    int tileX = blockIdx.x % tilesX, gy = blockIdx.x / tilesX;
    int gx0 = tileX * (MW * 64) + wave * (MW * 16);

    const unsigned short* Abase = A0 + (size_t)(gy - 1) * AP
                                     + (size_t)(gx0 + ml - 1) * Cs + kq * 8;

    // ---- stage ALL taps' B via async DMA (wave-uniform dest + lane*16B) ----
    #pragma unroll
    for (int it = 0; it < TOT / (TPB * 8); ++it) {
        int u = threadIdx.x + it * TPB;
        int e = u * 8;
        int tq = e >> 11;                 // (tap*KC2+q), wave-uniform
        int rem = e & 2047;               // nt*512 + r, lane-linear
        const unsigned short* src = Wf + ((size_t)tq * NTtot + nb * 4) * 512 + rem;
        unsigned short* dst = &Bs[(u & ~63) * 8];
        __builtin_amdgcn_global_load_lds(
            (const __attribute__((address_space(1))) unsigned int*)src,
            (__attribute__((address_space(3))) unsigned int*)dst, 16, 0, 0);
    }

    f32x4 acc[MW][4];
    #pragma unroll
    for (int mf = 0; mf < MW; ++mf)
        #pragma unroll
        for (int nt = 0; nt < 4; ++nt) acc[mf][nt] = (f32x4){0.f, 0.f, 0.f, 0.f};

    __syncthreads();   // the ONLY barrier

    #pragma unroll
    for (int tap = 0; tap < 9; ++tap) {
        int ky = tap / 3, kx = tap - (tap / 3) * 3;
        const unsigned short* Ar = Abase + (size_t)ky * AP + kx * Cs;
        const unsigned short* Bb = &Bs[(size_t)(tap * KC2) * 2048 + lane * 8];
        #pragma unroll
        for (int q = 0; q < KC2; ++q) {
            short8 b[4];
            #pragma unroll
            for (int nt = 0; nt < 4; ++nt)
                b[nt] = *(const short8*)(Bb + q * 2048 + nt * 512);
            short8 a[MW];
            #pragma unroll
            for (int mf = 0; mf < MW; ++mf)
                a[mf] = *(const short8*)(Ar + (size_t)(q * 32) + (size_t)(mf * 16) * Cs);
            #pragma unroll
            for (int mf = 0; mf < MW; ++mf)
                #pragma unroll
                for (int nt = 0; nt < 4; ++nt)
                    acc[mf][nt] = __builtin_amdgcn_mfma_f32_16x16x32_bf16(a[mf], b[nt], acc[mf][nt], 0, 0, 0);
        }
    }

    unsigned short* Orow = O0 + (size_t)gy * OP + (size_t)nb * 64;
    #pragma unroll
    for (int mf = 0; mf < MW; ++mf) {
        int gx = gx0 + mf * 16 + kq * 4;
        #pragma unroll
        for (int nt = 0; nt < 4; ++nt) {
            float bv = bias[nb * 64 + nt * 16 + ml];
            #pragma unroll
            for (int r = 0; r < 4; ++r) {
                float v = fmaxf(acc[mf][nt][r] + bv, 0.f);
                Orow[(size_t)(gx + r) * OMS + nt * 16 + ml] = f2bf(v);
            }
        }
    }
}

// ---------------------------------------------------------------------------
// 3x3 conv GEMM (R12, for CHUNKS>=2): B in LDS by (chunk,ky) 3-tap groups,
// double-buffered, async global_load_lds staging.
// ---------------------------------------------------------------------------
template<int CHUNKS, int MW>
__global__ __launch_bounds__(TPB) void k_conv3s(
    const unsigned short* __restrict__ A0, const unsigned short* __restrict__ Wf,
    const float* __restrict__ bias, unsigned short* __restrict__ O0,
    int AP, int tilesX, int OMS, int OP, int NTtot)
{
    constexpr int Cs  = CHUNKS * 64;
    constexpr int KC2 = CHUNKS * 2;
    __shared__ unsigned short Bs[2][12288];  // 2 x 24,576 B

    int lane = threadIdx.x & 63, wave = threadIdx.x >> 6;
    int ml = lane & 15, kq = lane >> 4;
    int nb = blockIdx.y;
    int tileX = blockIdx.x % tilesX, gy = blockIdx.x / tilesX;
    int gx0 = tileX * (MW * 64) + wave * (MW * 16);

    const unsigned short* Abase = A0 + (size_t)(gy - 1) * AP
                                     + (size_t)(gx0 + ml - 1) * Cs + kq * 8;

    f32x4 acc[MW][4];
    #pragma unroll
    for (int mf = 0; mf < MW; ++mf)
        #pragma unroll
        for (int nt = 0; nt < 4; ++nt) acc[mf][nt] = (f32x4){0.f, 0.f, 0.f, 0.f};

    const int G = CHUNKS * 3;

    auto stageB = [&](int g) {
        int ch = g / 3, ky = g - (g / 3) * 3;
        unsigned short* bd = Bs[g & 1];
        #pragma unroll
        for (int it = 0; it < 6; ++it) {
            int u = threadIdx.x + it * TPB;
            int e = u * 8;
            int kxq = e >> 11;
            int rem = e & 2047;
            int kx = kxq >> 1, q = kxq & 1;
            const unsigned short* src = Wf
                + ((size_t)((ky * 3 + kx) * KC2 + ch * 2 + q) * NTtot + nb * 4) * 512 + rem;
            unsigned short* dst = &bd[(u & ~63) * 8];
            __builtin_amdgcn_global_load_lds(
                (const __attribute__((address_space(1))) unsigned int*)src,
                (__attribute__((address_space(3))) unsigned int*)dst, 16, 0, 0);
        }
    };

    stageB(0);
    __syncthreads();
    for (int g = 0; g < G; ++g) {
        if (g + 1 < G) stageB(g + 1);
        int ch = g / 3, ky = g - (g / 3) * 3;
        const unsigned short* Ar = Abase + (size_t)ky * AP + ch * 64;
        const unsigned short* Bb = &Bs[g & 1][lane * 8];
        #pragma unroll
        for (int kx = 0; kx < 3; ++kx) {
            #pragma unroll
            for (int q = 0; q < 2; ++q) {
                short8 b[4];
                #pragma unroll
                for (int nt = 0; nt < 4; ++nt)
                    b[nt] = *(const short8*)(Bb + (kx * 2 + q) * 2048 + nt * 512);
                short8 a[MW];
                #pragma unroll
                for (int mf = 0; mf < MW; ++mf)
                    a[mf] = *(const short8*)(Ar + (size_t)(kx + mf * 16) * Cs + q * 32);
                #pragma unroll
                for (int mf = 0; mf < MW; ++mf)
                    #pragma unroll
                    for (int nt = 0; nt < 4; ++nt)
                        acc[mf][nt] = __builtin_amdgcn_mfma_f32_16x16x32_bf16(a[mf], b[nt], acc[mf][nt], 0, 0, 0);
            }
        }
        __syncthreads();
    }

    unsigned short* Orow = O0 + (size_t)gy * OP + (size_t)nb * 64;
    #pragma unroll
    for (int mf = 0; mf < MW; ++mf) {
        int gx = gx0 + mf * 16 + kq * 4;
        #pragma unroll
        for (int nt = 0; nt < 4; ++nt) {
            float bv = bias[nb * 64 + nt * 16 + ml];
            #pragma unroll
            for (int r = 0; r < 4; ++r) {
                float v = fmaxf(acc[mf][nt][r] + bv, 0.f);
                Orow[(size_t)(gx + r) * OMS + nt * 16 + ml] = f2bf(v);
            }
        }
    }
}

// ---------------------------------------------------------------------------
// K-split GEMM (GNN + convT u3t): block = 64m x 64n, 4 waves each K/4, LDS
// cross-wave reduce (rotated slice order so own slice is acc[0]). R8-proven.
// ---------------------------------------------------------------------------
template<int KCW>   // k32-steps per wave; K = KCW*128
__global__ __launch_bounds__(TPB) void k_gemmS(
    const unsigned short* __restrict__ A0, const unsigned short* __restrict__ Wf,
    const float* __restrict__ bias, const unsigned short* __restrict__ resid,
    unsigned short* __restrict__ O0, int NTtot,
    int AP, int Wimg, int OMS, int OP, int relu, int ct, int ctDy, int ctDx)
{
    constexpr int K = KCW * 128;
    __shared__ float red[12 * 4 * 64 * 4];   // 49,152 B
    int lane = threadIdx.x & 63, wave = threadIdx.x >> 6;
    int ml = lane & 15, kq = lane >> 4;
    int m0 = blockIdx.x * 64, nb = blockIdx.y;

    const unsigned short* Wb = Wf;
    unsigned short* Ob = O0;
    if (ct) {
        int tp = blockIdx.z;
        Wb += (size_t)(tp * KCW * 4) * NTtot * 512;
        int dy = 1 - (tp >> 1), dx = 1 - (tp & 1);   // jax conv_transpose tap flip
        Ob += (size_t)dy * ctDy + (size_t)dx * ctDx;
    }

    const unsigned short* Ap[4];
    #pragma unroll
    for (int i = 0; i < 4; ++i) {
        int mf = (wave + i) & 3;
        int m = m0 + mf * 16;
        int y = m / Wimg, x = m - y * Wimg;
        Ap[i] = A0 + (size_t)y * AP + (size_t)(x + ml) * K + wave * (KCW * 32) + kq * 8;
    }
    const unsigned short* Bp = Wb + ((size_t)(wave * KCW) * NTtot + nb * 4) * 512 + lane * 8;

    f32x4 acc[4][4];
    #pragma unroll
    for (int i = 0; i < 4; ++i)
        #pragma unroll
        for (int nt = 0; nt < 4; ++nt) acc[i][nt] = (f32x4){0.f, 0.f, 0.f, 0.f};

    #pragma unroll
    for (int q = 0; q < KCW; ++q) {
        short8 b[4];
        #pragma unroll
        for (int nt = 0; nt < 4; ++nt)
            b[nt] = *(const short8*)(Bp + ((size_t)q * NTtot + nt) * 512);
        short8 a[4];
        #pragma unroll
        for (int i = 0; i < 4; ++i)
            a[i] = *(const short8*)(Ap[i] + q * 32);
        #pragma unroll
        for (int i = 0; i < 4; ++i)
            #pragma unroll
            for (int nt = 0; nt < 4; ++nt)
                acc[i][nt] = __builtin_amdgcn_mfma_f32_16x16x32_bf16(a[i], b[nt], acc[i][nt], 0, 0, 0);
    }

    #pragma unroll
    for (int i = 1; i < 4; ++i) {
        int s = wave * 3 + (i - 1);
        #pragma unroll
        for (int nt = 0; nt < 4; ++nt)
            *(f32x4*)&red[(((s * 4 + nt) * 64) + lane) * 4] = acc[i][nt];
    }
    __syncthreads();
    #pragma unroll
    for (int w2 = 0; w2 < 4; ++w2) {
        if (w2 == wave) continue;
        int i = (wave - w2) & 3;
        int s = w2 * 3 + (i - 1);
        #pragma unroll
        for (int nt = 0; nt < 4; ++nt) {
            f32x4 v = *(const f32x4*)&red[(((s * 4 + nt) * 64) + lane) * 4];
            acc[0][nt] += v;
        }
    }

    int mrow = m0 + wave * 16 + kq * 4;
    int y = mrow / Wimg, x = mrow - y * Wimg;
    unsigned short* Ot = Ob + (size_t)y * OP + (size_t)x * OMS + nb * 64;
    const unsigned short* Rt = resid ? resid + (size_t)mrow * OMS + nb * 64 : nullptr;
    #pragma unroll
    for (int nt = 0; nt < 4; ++nt) {
        float bv = bias[nb * 64 + nt * 16 + ml];
        #pragma unroll
        for (int r = 0; r < 4; ++r) {
            float v = acc[0][nt][r] + bv;
            if (relu) v = fmaxf(v, 0.f);
            if (Rt) v += bf2f(Rt[(size_t)r * OMS + nt * 16 + ml]);
            Ot[(size_t)r * OMS + nt * 16 + ml] = f2bf(v);
        }
    }
}

// ---------------------------------------------------------------------------
// No-split GEMM (convT u4t): 4 waves m-split, whole K, B from global (L1).
// ---------------------------------------------------------------------------
template<int KC>   // q-steps; K = KC*32
__global__ __launch_bounds__(TPB) void k_gemmN(
    const unsigned short* __restrict__ A0, const unsigned short* __restrict__ Wf,
    const float* __restrict__ bias, unsigned short* __restrict__ O0,
    int Cs, int AP, int Wimg, int OMS, int OP, int NTtot, int relu,
    int ct, int ctDy, int ctDx)
{
    int lane = threadIdx.x & 63, wave = threadIdx.x >> 6;
    int ml = lane & 15, kq = lane >> 4;
    int nb = blockIdx.y;

    const unsigned short* Wb = Wf;
    unsigned short* Ob = O0;
    if (ct) {
        int tp = blockIdx.z;
        Wb += (size_t)(tp * KC) * NTtot * 512;
        int dy = 1 - (tp >> 1), dx = 1 - (tp & 1);
        Ob += (size_t)dy * ctDy + (size_t)dx * ctDx;
    }
    int m0 = blockIdx.x * 64 + wave * 16;
    int y = m0 / Wimg, x = m0 - y * Wimg;
    const unsigned short* Arow = A0 + (size_t)y * AP + (size_t)(x + ml) * Cs + kq * 8;
    const unsigned short* Bp = Wb + (size_t)(nb * 4) * 512 + lane * 8;

    f32x4 acc[4];
    #pragma unroll
    for (int nt = 0; nt < 4; ++nt) acc[nt] = (f32x4){0.f, 0.f, 0.f, 0.f};

    #pragma unroll
    for (int q = 0; q < KC; ++q) {
        short8 b[4];
        #pragma unroll
        for (int nt = 0; nt < 4; ++nt)
            b[nt] = *(const short8*)(Bp + ((size_t)q * NTtot + nt) * 512);
        short8 a = *(const short8*)(Arow + q * 32);
        #pragma unroll
        for (int nt = 0; nt < 4; ++nt)
            acc[nt] = __builtin_amdgcn_mfma_f32_16x16x32_bf16(a, b[nt], acc[nt], 0, 0, 0);
    }

    unsigned short* Ot = Ob + (size_t)y * OP + (size_t)(x + kq * 4) * OMS + (size_t)nb * 64;
    #pragma unroll
    for (int nt = 0; nt < 4; ++nt) {
        float bv = bias[nb * 64 + nt * 16 + ml];
        #pragma unroll
        for (int r = 0; r < 4; ++r) {
            float v = acc[nt][r] + bv;
            if (relu) v = fmaxf(v, 0.f);
            Ot[(size_t)r * OMS + nt * 16 + ml] = f2bf(v);
        }
    }
}

// ---------------------------------------------------------------------------
// Generic MFMA GEMM (global-direct) — used only for conv1 (K=32 im2col).
// ---------------------------------------------------------------------------
template<int MW, int KC>
__global__ __launch_bounds__(TPB) void k_gemm(
    const unsigned short* __restrict__ A0, const unsigned short* __restrict__ Wf,
    const float* __restrict__ bias, unsigned short* __restrict__ O0,
    int Cs, int AP, int Wimg, int OMS, int OP,
    int T, TapOffs toffs, int NTtot, int relu)
{
    int lane = threadIdx.x & 63, wave = threadIdx.x >> 6;
    int ml = lane & 15, kq = lane >> 4;
    int nb = blockIdx.y;
    const unsigned short* WbB = Wf + (size_t)(nb * 4) * 512 + lane * 8;

    int fy[MW], fx[MW];
    const unsigned short* Af[MW];
    #pragma unroll
    for (int f = 0; f < MW; ++f) {
        int mf = (blockIdx.x * 4 + wave) * (16 * MW) + f * 16;
        int y = mf / Wimg, x = mf - y * Wimg;
        fy[f] = y; fx[f] = x;
        Af[f] = A0 + (size_t)y * AP + (size_t)(x + ml) * Cs + kq * 8;
    }

    f32x4 acc[MW][4];
    #pragma unroll
    for (int f = 0; f < MW; ++f)
        #pragma unroll
        for (int nt = 0; nt < 4; ++nt) acc[f][nt] = (f32x4){0.f, 0.f, 0.f, 0.f};

    for (int tp = 0; tp < T; ++tp) {
        int toff = toffs.o[tp];
        const unsigned short* Wt = WbB + (size_t)(tp * KC) * NTtot * 512;
        #pragma unroll
        for (int q = 0; q < KC; ++q) {
            short8 b[4];
            #pragma unroll
            for (int nt = 0; nt < 4; ++nt)
                b[nt] = *(const short8*)(Wt + (size_t)q * NTtot * 512 + nt * 512);
            short8 a[MW];
            #pragma unroll
            for (int f = 0; f < MW; ++f)
                a[f] = *(const short8*)(Af[f] + toff + q * 32);
            #pragma unroll
            for (int f = 0; f < MW; ++f)
                #pragma unroll
                for (int nt = 0; nt < 4; ++nt)
                    acc[f][nt] = __builtin_amdgcn_mfma_f32_16x16x32_bf16(a[f], b[nt], acc[f][nt], 0, 0, 0);
        }
    }

    #pragma unroll
    for (int f = 0; f < MW; ++f) {
        unsigned short* Ot = O0 + (size_t)fy[f] * OP + (size_t)(fx[f] + kq * 4) * OMS + (size_t)nb * 64;
        #pragma unroll
        for (int nt = 0; nt < 4; ++nt) {
            float bv = bias[nb * 64 + nt * 16 + ml];
            #pragma unroll
            for (int r = 0; r < 4; ++r) {
                float v = acc[f][nt][r] + bv;
                if (relu) v = fmaxf(v, 0.f);
                Ot[(size_t)r * OMS + nt * 16 + ml] = f2bf(v);
            }
        }
    }
}

// ---------------- fused weight packing (all 15 tensors, one dispatch) -------
struct PackArgs {
    const float* w[15];
    int cum[16];
    int mode[15], KC[15], NT[15], K[15], N[15];
};
__global__ __launch_bounds__(TPB) void k_pack_all(
    PackArgs pa, unsigned short* __restrict__ dst, int total)
{
    int idx = blockIdx.x * TPB + threadIdx.x;
    if (idx >= total) return;
    int e = 0;
    #pragma unroll
    for (int i = 1; i < 15; ++i) e += (idx >= pa.cum[i]);
    int local = idx - pa.cum[e];
    const float* w = pa.w[e];
    int KC = pa.KC[e], NT = pa.NT[e], K = pa.K[e], N = pa.N[e], mode = pa.mode[e];

    int j = local & 7, l = (local >> 3) & 63;
    int r = local >> 9;
    int ntg = r % NT; int r2 = r / NT;
    int q = r2 % KC; int tp = r2 / KC;
    int k = q * 32 + (l >> 4) * 8 + j;
    int n = ntg * 16 + (l & 15);
    float v = 0.f;
    if (mode == 0) { int ky = tp / 3, kx = tp % 3; v = w[(size_t)(n * K + k) * 9 + ky * 3 + kx]; }
    else if (mode == 1) { v = w[(size_t)k * N + n]; }
    else if (mode == 2) { v = w[((size_t)tp * K + k) * N + n]; }
    else { if (k < 27) { int tap = k / 3, c = k % 3; int ky = tap / 3, kx = tap % 3;
                         v = w[((n * 3 + c) * 3 + ky) * 3 + kx]; } }
    dst[idx] = f2bf(v);
}

// ---------------- fused pad-ring zeroing (all buffers, one dispatch) --------
struct ZArgs { int off[10]; int cum[11]; int W2[10]; int H2[10]; int Cs[10]; };
__global__ __launch_bounds__(TPB) void k_zero_all(
    ZArgs za, unsigned short* __restrict__ W, int total)
{
    int idx = blockIdx.x * TPB + threadIdx.x;
    if (idx >= total) return;
    int e = 0;
    #pragma unroll
    for (int i = 1; i < 10; ++i) e += (idx >= za.cum[i]);
    int local = idx - za.cum[e];
    int W2 = za.W2[e], H2 = za.H2[e], Cs = za.Cs[e];
    int topbot = 2 * W2 * Cs;
    int iy, ix, c;
    if (local < topbot) {
        int row = local / (W2 * Cs); int rest = local - row * (W2 * Cs);
        iy = row ? (H2 - 1) : 0; ix = rest / Cs; c = rest - (rest / Cs) * Cs;
    } else {
        int idx2 = local - topbot;
        int per = (H2 - 2) * Cs;
        int side = idx2 / per; int rest = idx2 - side * per;
        iy = 1 + rest / Cs; ix = side ? (W2 - 1) : 0; c = rest - (rest / Cs) * Cs;
    }
    W[(size_t)za.off[e] + ((size_t)iy * W2 + ix) * Cs + c] = 0;
}

// ---------------- conv1 im2col: x fp32 [3][256][256] -> xcol bf16 [65536][32]
__global__ __launch_bounds__(TPB) void k_im2col(
    const float* __restrict__ x, unsigned short* __restrict__ xcol)
{
    int idx = blockIdx.x * TPB + threadIdx.x;
    if (idx >= 65536 * 32) return;
    int k = idx & 31, m = idx >> 5;
    int y = m >> 8, xx = m & 255;
    float v = 0.f;
    if (k < 27) {
        int tap = k / 3, c = k - tap * 3;
        int ty = tap / 3, tx = tap % 3;
        int yy = y + ty - 1, xp = xx + tx - 1;
        if (yy >= 0 && yy < 256 && xp >= 0 && xp < 256)
            v = x[c * 65536 + yy * 256 + xp];
    }
    xcol[idx] = f2bf(v);
}

// ---------------- maxpool 2x2 channels-last (strided in/out) ----------------
__global__ __launch_bounds__(TPB) void k_maxpool(
    const unsigned short* __restrict__ inI, unsigned short* __restrict__ outI,
    int Wo, int C4, int CsIn, int inPitch, int CsOut, int outPitch, int total)
{
    int idx = blockIdx.x * TPB + threadIdx.x;
    if (idx >= total) return;
    int c4 = idx % C4; int p = idx / C4;
    int x = p % Wo, y = p / Wo;
    const unsigned short* ip = inI + (size_t)(2 * y) * inPitch + (size_t)(2 * x) * CsIn + c4 * 4;
    ushort4 a = *(const ushort4*)(ip);
    ushort4 b = *(const ushort4*)(ip + CsIn);
    ushort4 c = *(const ushort4*)(ip + inPitch);
    ushort4 d = *(const ushort4*)(ip + inPitch + CsIn);
    ushort4 o;
    o.x = f2bf(fmaxf(fmaxf(bf2f(a.x), bf2f(b.x)), fmaxf(bf2f(c.x), bf2f(d.x))));
    o.y = f2bf(fmaxf(fmaxf(bf2f(a.y), bf2f(b.y)), fmaxf(bf2f(c.y), bf2f(d.y))));
    o.z = f2bf(fmaxf(fmaxf(bf2f(a.z), bf2f(b.z)), fmaxf(bf2f(c.z), bf2f(d.z))));
    o.w = f2bf(fmaxf(fmaxf(bf2f(a.w), bf2f(b.w)), fmaxf(bf2f(c.w), bf2f(d.w))));
    *(ushort4*)(outI + (size_t)y * outPitch + (size_t)x * CsOut + c4 * 4) = o;
}

// ---------------- graph aggregation on 66x66 grid, node-major bf16 ----------
__global__ __launch_bounds__(TPB) void k_gagg(
    const unsigned short* __restrict__ X, unsigned short* __restrict__ agg,
    int C, int total)
{
    int idx = blockIdx.x * TPB + threadIdx.x;
    if (idx >= total) return;
    int C4 = C >> 2;
    int c4 = idx % C4; int n = idx / C4;
    int i = n / 66, j = n - i * 66;
    size_t base = (size_t)n * C + c4 * 4;
    ushort4 s = *(const ushort4*)(X + base);
    float v0 = bf2f(s.x), v1 = bf2f(s.y), v2 = bf2f(s.z), v3 = bf2f(s.w);
    float cnt = 1.f;
    if (i > 0)  { ushort4 u = *(const ushort4*)(X + base - (size_t)66 * C);
                  v0 += bf2f(u.x); v1 += bf2f(u.y); v2 += bf2f(u.z); v3 += bf2f(u.w); cnt += 1.f; }
    if (i < 65) { ushort4 u = *(const ushort4*)(X + base + (size_t)66 * C);
                  v0 += bf2f(u.x); v1 += bf2f(u.y); v2 += bf2f(u.z); v3 += bf2f(u.w); cnt += 1.f; }
    if (j > 0)  { ushort4 u = *(const ushort4*)(X + base - C);
                  v0 += bf2f(u.x); v1 += bf2f(u.y); v2 += bf2f(u.z); v3 += bf2f(u.w); cnt += 1.f; }
    if (j < 65) { ushort4 u = *(const ushort4*)(X + base + C);
                  v0 += bf2f(u.x); v1 += bf2f(u.y); v2 += bf2f(u.z); v3 += bf2f(u.w); cnt += 1.f; }
    float inv = 1.f / cnt;
    ushort4 o;
    o.x = f2bf(v0 * inv); o.y = f2bf(v1 * inv); o.z = f2bf(v2 * inv); o.w = f2bf(v3 * inv);
    *(ushort4*)(agg + base) = o;
}

// ---------------- final conv 64->1, fp32 out --------------------------------
__global__ __launch_bounds__(TPB) void k_outconv(
    const unsigned short* __restrict__ vI, const float* __restrict__ ow,
    const float* __restrict__ ob, float* __restrict__ out)
{
    __shared__ float wl[576];
    for (int i = threadIdx.x; i < 576; i += TPB) wl[i] = ow[i];
    __syncthreads();
    int p = blockIdx.x * TPB + threadIdx.x;
    int y = p >> 8, x = p & 255;
    float acc = ob[0];
    #pragma unroll
    for (int ky = 0; ky < 3; ++ky)
        #pragma unroll
        for (int kx = 0; kx < 3; ++kx) {
            const unsigned short* ip = vI + (size_t)((y + ky - 1) * 258 + (x + kx - 1)) * 64;
            int wb = ky * 3 + kx;
            for (int c = 0; c < 64; c += 4) {
                ushort4 uv = *(const ushort4*)(ip + c);
                acc += bf2f(uv.x) * wl[c * 9 + wb] + bf2f(uv.y) * wl[(c + 1) * 9 + wb]
                     + bf2f(uv.z) * wl[(c + 2) * 9 + wb] + bf2f(uv.w) * wl[(c + 3) * 9 + wb];
            }
        }
    out[p] = acc;
}

static inline TapOffs zero_toffs() { TapOffs t = {}; return t; }

extern "C" void kernel_launch(void* const* d_in, const int* in_sizes, int n_in,
                              void* d_out, int out_size, void* d_ws, size_t ws_size,
                              hipStream_t stream) {
    const float* x    = (const float*)d_in[0];
    const float* d1w1 = (const float*)d_in[1];  const float* d1b1 = (const float*)d_in[2];
    const float* d1w2 = (const float*)d_in[3];  const float* d1b2 = (const float*)d_in[4];
    const float* d2w1 = (const float*)d_in[5];  const float* d2b1 = (const float*)d_in[6];
    const float* d2w2 = (const float*)d_in[7];  const float* d2b2 = (const float*)d_in[8];
    const float* md1w = (const float*)d_in[9];  const float* md1b = (const float*)d_in[10];
    const float* md2w = (const float*)d_in[11]; const float* md2b = (const float*)d_in[12];
    const float* mbw  = (const float*)d_in[13]; const float* mbb  = (const float*)d_in[14];
    const float* mu1w = (const float*)d_in[15]; const float* mu1b = (const float*)d_in[16];
    const float* mu2w = (const float*)d_in[17]; const float* mu2b = (const float*)d_in[18];
    const float* u3tw = (const float*)d_in[19]; const float* u3tb = (const float*)d_in[20];
    const float* u3w1 = (const float*)d_in[21]; const float* u3b1 = (const float*)d_in[22];
    const float* u3w2 = (const float*)d_in[23]; const float* u3b2 = (const float*)d_in[24];
    const float* u4tw = (const float*)d_in[25]; const float* u4tb = (const float*)d_in[26];
    const float* u4w1 = (const float*)d_in[27]; const float* u4b1 = (const float*)d_in[28];
    const float* u4w2 = (const float*)d_in[29]; const float* u4b2 = (const float*)d_in[30];
    const float* ow   = (const float*)d_in[31]; const float* ob   = (const float*)d_in[32];
    float* out = (float*)d_out;

    unsigned short* W = (unsigned short*)d_ws;

    // ---- flat arena (elem offsets, bf16) ----
    const size_t XCOL = 0;          // 2,097,152
    const size_t A1   = 2097152;    // 258*258*64
    const size_t CAT4 = 6357248;    // 258*258*128
    const size_t P1   = 14877440;   // 130*130*64
    const size_t T2   = 15959040;   // 130*130*128
    const size_t CAT3 = 18122240;   // 130*130*256
    const size_t X0   = 22448640;   // 66*66*128
    const size_t BP1  = 23006208;   // 4608*256
    const size_t BP2  = 24185856;   // 4608*512
    const size_t XB   = 26545152;   // 4608*1024
    const size_t XC   = 31263744;   // 4608*512
    const size_t XD   = 33623040;   // 4608*256
    const size_t V3A  = 34802688;   // 130*130*128
    const size_t V3B  = 36965888;   // 130*130*128
    const size_t V4A  = 39129088;   // 258*258*64
    const size_t V4B  = 43389184;   // 258*258*64
    const size_t AGG  = 47649280;   // 4608*1024
    const size_t WP   = 52367872;   // packed weights 2,320,384

    const size_t a1I   = A1 + 259 * 64;
    const size_t cat4I = CAT4 + 259 * 128;
    const size_t p1I   = P1 + 131 * 64;
    const size_t t2I   = T2 + 131 * 128;
    const size_t cat3I = CAT3 + 131 * 256;
    const size_t X0I   = X0 + 67 * 128;
    const size_t XdI   = XD + 67 * 256;
    const size_t v3aI  = V3A + 131 * 128;
    const size_t v3bI  = V3B + 131 * 128;
    const size_t v4aI  = V4A + 259 * 64;
    const size_t v4bI  = V4B + 259 * 64;

    dim3 blk(TPB);
    const int BIG = 1 << 28;

    // ---- fused pad-ring zeroing ----
    {
        ZArgs za;
        const int off[10] = {(int)A1,(int)CAT4,(int)P1,(int)T2,(int)CAT3,(int)V3A,(int)V3B,(int)V4A,(int)V4B,(int)X0};
        const int w2 [10] = {258,258,130,130,130,130,130,258,258,66};
        const int h2 [10] = {258,258,130,130,130,130,130,258,258,66};
        const int cs [10] = {64,128,64,128,256,128,128,64,64,128};
        int cum = 0;
        for (int i = 0; i < 10; ++i) {
            za.off[i]=off[i]; za.W2[i]=w2[i]; za.H2[i]=h2[i]; za.Cs[i]=cs[i];
            za.cum[i]=cum; cum += (w2[i]*h2[i] - (w2[i]-2)*(h2[i]-2))*cs[i];
        }
        za.cum[10]=cum;
        k_zero_all<<<dim3((cum + TPB - 1) / TPB), blk, 0, stream>>>(za, W, cum);
    }

    // ---- fused weight packing (16x16 fragment layout) ----
    {
        PackArgs pa;
        const float* ws_[15] = {d1w1,d1w2,d2w1,d2w2,md1w,md2w,mbw,mu1w,mu2w,u3tw,u3w1,u3w2,u4tw,u4w1,u4w2};
        const int mode[15] = {3,0,0,0,1,1,1,1,1,2,0,0,2,0,0};
        const int kc [15] = {1,2,2,4,4,8,16,32,16,8,8,4,4,4,2};
        const int nt [15] = {4,4,8,8,16,32,64,32,16,8,8,8,4,4,4};
        const int kk [15] = {32,64,64,128,128,256,512,1024,512,256,256,128,128,128,64};
        const int nn [15] = {64,64,128,128,256,512,1024,512,256,128,128,128,64,64,64};
        const int tt [15] = {1,9,9,9,1,1,1,1,1,4,9,9,4,9,9};
        int cum = 0;
        for (int i = 0; i < 15; ++i) {
            pa.w[i]=ws_[i]; pa.mode[i]=mode[i]; pa.KC[i]=kc[i]; pa.NT[i]=nt[i];
            pa.K[i]=kk[i]; pa.N[i]=nn[i]; pa.cum[i]=cum;
            cum += tt[i]*kc[i]*nt[i]*512;
        }
        pa.cum[15]=cum;
        k_pack_all<<<dim3((cum + TPB - 1) / TPB), blk, 0, stream>>>(pa, W + WP, cum);
    }
    const size_t pw_d1w1=WP+0, pw_d1w2=WP+2048, pw_d2w1=WP+38912, pw_d2w2=WP+112640,
        pw_md1=WP+260096, pw_md2=WP+292864, pw_mb=WP+423936, pw_mu1=WP+948224,
        pw_mu2=WP+1472512, pw_u3t=WP+1603584, pw_u3w1=WP+1734656, pw_u3w2=WP+2029568,
        pw_u4t=WP+2177024, pw_u4w1=WP+2209792, pw_u4w2=WP+2283520;

    // ---- encoder ----
    k_im2col<<<dim3(8192), blk, 0, stream>>>(x, W + XCOL);
    k_gemm<2,1><<<dim3(512,1), blk, 0, stream>>>(W + XCOL, W + pw_d1w1, d1b1,
        W + a1I, 32, 8192, 256, 64, 258*64, 1, zero_toffs(), 4, 1);
    k_conv3w<1,2><<<dim3(512,1), blk, 0, stream>>>(W + a1I, W + pw_d1w2, d1b2,
        W + cat4I, 258*64, 2, 128, 258*128, 4);
    k_maxpool<<<dim3(1024), blk, 0, stream>>>(W + cat4I, W + p1I, 128, 16, 128, 258*128, 64, 130*64, 128*128*16);
    k_conv3w<1,1><<<dim3(256,2), blk, 0, stream>>>(W + p1I, W + pw_d2w1, d2b1,
        W + t2I, 130*64, 2, 128, 130*128, 8);
    k_conv3s<2,1><<<dim3(256,2), blk, 0, stream>>>(W + t2I, W + pw_d2w2, d2b2,
        W + cat3I, 130*128, 2, 256, 130*256, 8);
    k_maxpool<<<dim3(512), blk, 0, stream>>>(W + cat3I, W + X0I, 64, 32, 256, 130*256, 128, 66*128, 64*64*32);

    // ---- GNN on 66x66 padded grid (separate gagg + K-split GEMMs) ----
    k_gagg<<<dim3(545), blk, 0, stream>>>(W + X0, W + AGG, 128, 4356*32);
    k_gemmS<1><<<dim3(72,4), blk, 0, stream>>>(W + AGG, W + pw_md1, md1b, nullptr,
        W + BP1, 16, 0, BIG, 256, 0, 1, 0, 0, 0);
    k_gagg<<<dim3(1089), blk, 0, stream>>>(W + BP1, W + AGG, 256, 4356*64);
    k_gemmS<2><<<dim3(72,8), blk, 0, stream>>>(W + AGG, W + pw_md2, md2b, nullptr,
        W + BP2, 32, 0, BIG, 512, 0, 1, 0, 0, 0);
    k_gagg<<<dim3(2178), blk, 0, stream>>>(W + BP2, W + AGG, 512, 4356*128);
    k_gemmS<4><<<dim3(72,16), blk, 0, stream>>>(W + AGG, W + pw_mb, mbb, nullptr,
        W + XB, 64, 0, BIG, 1024, 0, 1, 0, 0, 0);
    k_gagg<<<dim3(4356), blk, 0, stream>>>(W + XB, W + AGG, 1024, 4356*256);
    k_gemmS<8><<<dim3(72,8), blk, 0, stream>>>(W + AGG, W + pw_mu1, mu1b, W + BP2,
        W + XC, 32, 0, BIG, 512, 0, 1, 0, 0, 0);
    k_gagg<<<dim3(2178), blk, 0, stream>>>(W + XC, W + AGG, 512, 4356*128);
    k_gemmS<4><<<dim3(72,4), blk, 0, stream>>>(W + AGG, W + pw_mu2, mu2b, W + BP1,
        W + XD, 16, 0, BIG, 256, 0, 1, 0, 0, 0);

    // ---- decoder stage 3: convT (K-split, 4 taps via z) + 2 convs ----
    k_gemmS<2><<<dim3(64,2,4), blk, 0, stream>>>(W + XdI, W + pw_u3t, u3tb, nullptr,
        W + cat3I + 128, 8, 66*256, 64, 512, 2*130*256, 0, 1, 130*256, 256);
    k_conv3s<4,1><<<dim3(256,2), blk, 0, stream>>>(W + cat3I, W + pw_u3w1, u3b1,
        W + v3aI, 130*256, 2, 128, 130*128, 8);
    k_conv3s<2,1><<<dim3(256,2), blk, 0, stream>>>(W + v3aI, W + pw_u3w2, u3b2,
        W + v3bI, 130*128, 2, 128, 130*128, 8);

    // ---- decoder stage 4: convT (no-split, 4 taps via z) + 2 convs ----
    k_gemmN<4><<<dim3(256,1,4), blk, 0, stream>>>(W + v3bI, W + pw_u4t, u4tb,
        W + cat4I + 64, 128, 130*128, 128, 256, 2*258*128, 4, 0, 1, 258*128, 128);
    k_conv3s<2,2><<<dim3(512,1), blk, 0, stream>>>(W + cat4I, W + pw_u4w1, u4b1,
        W + v4aI, 258*128, 2, 64, 258*64, 4);
    k_conv3w<1,2><<<dim3(512,1), blk, 0, stream>>>(W + v4aI, W + pw_u4w2, u4b2,
        W + v4bI, 258*64, 2, 64, 258*64, 4);

    // ---- output conv 64->1, fp32 ----
    k_outconv<<<dim3(256), blk, 0, stream>>>(W + v4bI, ow, ob, out);
}

// Round 14
// 384.187 us; speedup vs baseline: 1.2205x; 1.0132x over previous
//
#include <hip/hip_runtime.h>
#include <cstddef>

#define TPB 256

typedef __attribute__((ext_vector_type(8))) short short8;
typedef __attribute__((ext_vector_type(4))) float f32x4;

__device__ inline unsigned short f2bf(float f) {
    unsigned int u = __builtin_bit_cast(unsigned int, f);
    u += 0x7fffu + ((u >> 16) & 1u);
    return (unsigned short)(u >> 16);
}
__device__ inline float bf2f(unsigned short h) {
    unsigned int u = ((unsigned int)h) << 16;
    return __builtin_bit_cast(float, u);
}

struct TapOffs { int o[9]; };

// ---------------------------------------------------------------------------
// Whole-B-in-LDS 3x3 conv (CHUNKS=1 layers): one barrier total. (R13)
// ---------------------------------------------------------------------------
template<int CHUNKS, int MW>
__global__ __launch_bounds__(TPB) void k_conv3w(
    const unsigned short* __restrict__ A0, const unsigned short* __restrict__ Wf,
    const float* __restrict__ bias, unsigned short* __restrict__ O0,
    int AP, int tilesX, int OMS, int OP, int NTtot)
{
    constexpr int Cs  = CHUNKS * 64;
    constexpr int KC2 = CHUNKS * 2;
    constexpr int TOT = 9 * KC2 * 4 * 512;
    __shared__ unsigned short Bs[TOT];

    int lane = threadIdx.x & 63, wave = threadIdx.x >> 6;
    int ml = lane & 15, kq = lane >> 4;
    int nb = blockIdx.y;
    int tileX = blockIdx.x % tilesX, gy = blockIdx.x / tilesX;
    int gx0 = tileX * (MW * 64) + wave * (MW * 16);

    const unsigned short* Abase = A0 + (size_t)(gy - 1) * AP
                                     + (size_t)(gx0 + ml - 1) * Cs + kq * 8;

    #pragma unroll
    for (int it = 0; it < TOT / (TPB * 8); ++it) {
        int u = threadIdx.x + it * TPB;
        int e = u * 8;
        int tq = e >> 11;
        int rem = e & 2047;
        const unsigned short* src = Wf + ((size_t)tq * NTtot + nb * 4) * 512 + rem;
        unsigned short* dst = &Bs[(u & ~63) * 8];
        __builtin_amdgcn_global_load_lds(
            (const __attribute__((address_space(1))) unsigned int*)src,
            (__attribute__((address_space(3))) unsigned int*)dst, 16, 0, 0);
    }

    f32x4 acc[MW][4];
    #pragma unroll
    for (int mf = 0; mf < MW; ++mf)
        #pragma unroll
        for (int nt = 0; nt < 4; ++nt) acc[mf][nt] = (f32x4){0.f, 0.f, 0.f, 0.f};

    __syncthreads();

    #pragma unroll
    for (int tap = 0; tap < 9; ++tap) {
        int ky = tap / 3, kx = tap - (tap / 3) * 3;
        const unsigned short* Ar = Abase + (size_t)ky * AP + kx * Cs;
        const unsigned short* Bb = &Bs[(size_t)(tap * KC2) * 2048 + lane * 8];
        #pragma unroll
        for (int q = 0; q < KC2; ++q) {
            short8 b[4];
            #pragma unroll
            for (int nt = 0; nt < 4; ++nt)
                b[nt] = *(const short8*)(Bb + q * 2048 + nt * 512);
            short8 a[MW];
            #pragma unroll
            for (int mf = 0; mf < MW; ++mf)
                a[mf] = *(const short8*)(Ar + (size_t)(q * 32) + (size_t)(mf * 16) * Cs);
            #pragma unroll
            for (int mf = 0; mf < MW; ++mf)
                #pragma unroll
                for (int nt = 0; nt < 4; ++nt)
                    acc[mf][nt] = __builtin_amdgcn_mfma_f32_16x16x32_bf16(a[mf], b[nt], acc[mf][nt], 0, 0, 0);
        }
    }

    unsigned short* Orow = O0 + (size_t)gy * OP + (size_t)nb * 64;
    #pragma unroll
    for (int mf = 0; mf < MW; ++mf) {
        int gx = gx0 + mf * 16 + kq * 4;
        #pragma unroll
        for (int nt = 0; nt < 4; ++nt) {
            float bv = bias[nb * 64 + nt * 16 + ml];
            #pragma unroll
            for (int r = 0; r < 4; ++r) {
                float v = fmaxf(acc[mf][nt][r] + bv, 0.f);
                Orow[(size_t)(gx + r) * OMS + nt * 16 + ml] = f2bf(v);
            }
        }
    }
}

// ---------------------------------------------------------------------------
// 3x3 conv GEMM (CHUNKS>=2): B in LDS by (chunk,ky) 3-tap groups, dbuf,
// async global_load_lds staging. (R12)
// ---------------------------------------------------------------------------
template<int CHUNKS, int MW>
__global__ __launch_bounds__(TPB) void k_conv3s(
    const unsigned short* __restrict__ A0, const unsigned short* __restrict__ Wf,
    const float* __restrict__ bias, unsigned short* __restrict__ O0,
    int AP, int tilesX, int OMS, int OP, int NTtot)
{
    constexpr int Cs  = CHUNKS * 64;
    constexpr int KC2 = CHUNKS * 2;
    __shared__ unsigned short Bs[2][12288];

    int lane = threadIdx.x & 63, wave = threadIdx.x >> 6;
    int ml = lane & 15, kq = lane >> 4;
    int nb = blockIdx.y;
    int tileX = blockIdx.x % tilesX, gy = blockIdx.x / tilesX;
    int gx0 = tileX * (MW * 64) + wave * (MW * 16);

    const unsigned short* Abase = A0 + (size_t)(gy - 1) * AP
                                     + (size_t)(gx0 + ml - 1) * Cs + kq * 8;

    f32x4 acc[MW][4];
    #pragma unroll
    for (int mf = 0; mf < MW; ++mf)
        #pragma unroll
        for (int nt = 0; nt < 4; ++nt) acc[mf][nt] = (f32x4){0.f, 0.f, 0.f, 0.f};

    const int G = CHUNKS * 3;

    auto stageB = [&](int g) {
        int ch = g / 3, ky = g - (g / 3) * 3;
        unsigned short* bd = Bs[g & 1];
        #pragma unroll
        for (int it = 0; it < 6; ++it) {
            int u = threadIdx.x + it * TPB;
            int e = u * 8;
            int kxq = e >> 11;
            int rem = e & 2047;
            int kx = kxq >> 1, q = kxq & 1;
            const unsigned short* src = Wf
                + ((size_t)((ky * 3 + kx) * KC2 + ch * 2 + q) * NTtot + nb * 4) * 512 + rem;
            unsigned short* dst = &bd[(u & ~63) * 8];
            __builtin_amdgcn_global_load_lds(
                (const __attribute__((address_space(1))) unsigned int*)src,
                (__attribute__((address_space(3))) unsigned int*)dst, 16, 0, 0);
        }
    };

    stageB(0);
    __syncthreads();
    for (int g = 0; g < G; ++g) {
        if (g + 1 < G) stageB(g + 1);
        int ch = g / 3, ky = g - (g / 3) * 3;
        const unsigned short* Ar = Abase + (size_t)ky * AP + ch * 64;
        const unsigned short* Bb = &Bs[g & 1][lane * 8];
        #pragma unroll
        for (int kx = 0; kx < 3; ++kx) {
            #pragma unroll
            for (int q = 0; q < 2; ++q) {
                short8 b[4];
                #pragma unroll
                for (int nt = 0; nt < 4; ++nt)
                    b[nt] = *(const short8*)(Bb + (kx * 2 + q) * 2048 + nt * 512);
                short8 a[MW];
                #pragma unroll
                for (int mf = 0; mf < MW; ++mf)
                    a[mf] = *(const short8*)(Ar + (size_t)(kx + mf * 16) * Cs + q * 32);
                #pragma unroll
                for (int mf = 0; mf < MW; ++mf)
                    #pragma unroll
                    for (int nt = 0; nt < 4; ++nt)
                        acc[mf][nt] = __builtin_amdgcn_mfma_f32_16x16x32_bf16(a[mf], b[nt], acc[mf][nt], 0, 0, 0);
            }
        }
        __syncthreads();
    }

    unsigned short* Orow = O0 + (size_t)gy * OP + (size_t)nb * 64;
    #pragma unroll
    for (int mf = 0; mf < MW; ++mf) {
        int gx = gx0 + mf * 16 + kq * 4;
        #pragma unroll
        for (int nt = 0; nt < 4; ++nt) {
            float bv = bias[nb * 64 + nt * 16 + ml];
            #pragma unroll
            for (int r = 0; r < 4; ++r) {
                float v = fmaxf(acc[mf][nt][r] + bv, 0.f);
                Orow[(size_t)(gx + r) * OMS + nt * 16 + ml] = f2bf(v);
            }
        }
    }
}

// ---------------------------------------------------------------------------
// K-split GEMM (GNN + convT u3t). (R8-proven)
// ---------------------------------------------------------------------------
template<int KCW>
__global__ __launch_bounds__(TPB) void k_gemmS(
    const unsigned short* __restrict__ A0, const unsigned short* __restrict__ Wf,
    const float* __restrict__ bias, const unsigned short* __restrict__ resid,
    unsigned short* __restrict__ O0, int NTtot,
    int AP, int Wimg, int OMS, int OP, int relu, int ct, int ctDy, int ctDx)
{
    constexpr int K = KCW * 128;
    __shared__ float red[12 * 4 * 64 * 4];
    int lane = threadIdx.x & 63, wave = threadIdx.x >> 6;
    int ml = lane & 15, kq = lane >> 4;
    int m0 = blockIdx.x * 64, nb = blockIdx.y;

    const unsigned short* Wb = Wf;
    unsigned short* Ob = O0;
    if (ct) {
        int tp = blockIdx.z;
        Wb += (size_t)(tp * KCW * 4) * NTtot * 512;
        int dy = 1 - (tp >> 1), dx = 1 - (tp & 1);
        Ob += (size_t)dy * ctDy + (size_t)dx * ctDx;
    }

    const unsigned short* Ap[4];
    #pragma unroll
    for (int i = 0; i < 4; ++i) {
        int mf = (wave + i) & 3;
        int m = m0 + mf * 16;
        int y = m / Wimg, x = m - y * Wimg;
        Ap[i] = A0 + (size_t)y * AP + (size_t)(x + ml) * K + wave * (KCW * 32) + kq * 8;
    }
    const unsigned short* Bp = Wb + ((size_t)(wave * KCW) * NTtot + nb * 4) * 512 + lane * 8;

    f32x4 acc[4][4];
    #pragma unroll
    for (int i = 0; i < 4; ++i)
        #pragma unroll
        for (int nt = 0; nt < 4; ++nt) acc[i][nt] = (f32x4){0.f, 0.f, 0.f, 0.f};

    #pragma unroll
    for (int q = 0; q < KCW; ++q) {
        short8 b[4];
        #pragma unroll
        for (int nt = 0; nt < 4; ++nt)
            b[nt] = *(const short8*)(Bp + ((size_t)q * NTtot + nt) * 512);
        short8 a[4];
        #pragma unroll
        for (int i = 0; i < 4; ++i)
            a[i] = *(const short8*)(Ap[i] + q * 32);
        #pragma unroll
        for (int i = 0; i < 4; ++i)
            #pragma unroll
            for (int nt = 0; nt < 4; ++nt)
                acc[i][nt] = __builtin_amdgcn_mfma_f32_16x16x32_bf16(a[i], b[nt], acc[i][nt], 0, 0, 0);
    }

    #pragma unroll
    for (int i = 1; i < 4; ++i) {
        int s = wave * 3 + (i - 1);
        #pragma unroll
        for (int nt = 0; nt < 4; ++nt)
            *(f32x4*)&red[(((s * 4 + nt) * 64) + lane) * 4] = acc[i][nt];
    }
    __syncthreads();
    #pragma unroll
    for (int w2 = 0; w2 < 4; ++w2) {
        if (w2 == wave) continue;
        int i = (wave - w2) & 3;
        int s = w2 * 3 + (i - 1);
        #pragma unroll
        for (int nt = 0; nt < 4; ++nt) {
            f32x4 v = *(const f32x4*)&red[(((s * 4 + nt) * 64) + lane) * 4];
            acc[0][nt] += v;
        }
    }

    int mrow = m0 + wave * 16 + kq * 4;
    int y = mrow / Wimg, x = mrow - y * Wimg;
    unsigned short* Ot = Ob + (size_t)y * OP + (size_t)x * OMS + nb * 64;
    const unsigned short* Rt = resid ? resid + (size_t)mrow * OMS + nb * 64 : nullptr;
    #pragma unroll
    for (int nt = 0; nt < 4; ++nt) {
        float bv = bias[nb * 64 + nt * 16 + ml];
        #pragma unroll
        for (int r = 0; r < 4; ++r) {
            float v = acc[0][nt][r] + bv;
            if (relu) v = fmaxf(v, 0.f);
            if (Rt) v += bf2f(Rt[(size_t)r * OMS + nt * 16 + ml]);
            Ot[(size_t)r * OMS + nt * 16 + ml] = f2bf(v);
        }
    }
}

// ---------------------------------------------------------------------------
// No-split GEMM (convT u4t). (R8)
// ---------------------------------------------------------------------------
template<int KC>
__global__ __launch_bounds__(TPB) void k_gemmN(
    const unsigned short* __restrict__ A0, const unsigned short* __restrict__ Wf,
    const float* __restrict__ bias, unsigned short* __restrict__ O0,
    int Cs, int AP, int Wimg, int OMS, int OP, int NTtot, int relu,
    int ct, int ctDy, int ctDx)
{
    int lane = threadIdx.x & 63, wave = threadIdx.x >> 6;
    int ml = lane & 15, kq = lane >> 4;
    int nb = blockIdx.y;

    const unsigned short* Wb = Wf;
    unsigned short* Ob = O0;
    if (ct) {
        int tp = blockIdx.z;
        Wb += (size_t)(tp * KC) * NTtot * 512;
        int dy = 1 - (tp >> 1), dx = 1 - (tp & 1);
        Ob += (size_t)dy * ctDy + (size_t)dx * ctDx;
    }
    int m0 = blockIdx.x * 64 + wave * 16;
    int y = m0 / Wimg, x = m0 - y * Wimg;
    const unsigned short* Arow = A0 + (size_t)y * AP + (size_t)(x + ml) * Cs + kq * 8;
    const unsigned short* Bp = Wb + (size_t)(nb * 4) * 512 + lane * 8;

    f32x4 acc[4];
    #pragma unroll
    for (int nt = 0; nt < 4; ++nt) acc[nt] = (f32x4){0.f, 0.f, 0.f, 0.f};

    #pragma unroll
    for (int q = 0; q < KC; ++q) {
        short8 b[4];
        #pragma unroll
        for (int nt = 0; nt < 4; ++nt)
            b[nt] = *(const short8*)(Bp + ((size_t)q * NTtot + nt) * 512);
        short8 a = *(const short8*)(Arow + q * 32);
        #pragma unroll
        for (int nt = 0; nt < 4; ++nt)
            acc[nt] = __builtin_amdgcn_mfma_f32_16x16x32_bf16(a, b[nt], acc[nt], 0, 0, 0);
    }

    unsigned short* Ot = Ob + (size_t)y * OP + (size_t)(x + kq * 4) * OMS + (size_t)nb * 64;
    #pragma unroll
    for (int nt = 0; nt < 4; ++nt) {
        float bv = bias[nb * 64 + nt * 16 + ml];
        #pragma unroll
        for (int r = 0; r < 4; ++r) {
            float v = acc[nt][r] + bv;
            if (relu) v = fmaxf(v, 0.f);
            Ot[(size_t)r * OMS + nt * 16 + ml] = f2bf(v);
        }
    }
}

// ---------------------------------------------------------------------------
// Generic MFMA GEMM (global-direct) — conv1 (K=32 im2col).
// ---------------------------------------------------------------------------
template<int MW, int KC>
__global__ __launch_bounds__(TPB) void k_gemm(
    const unsigned short* __restrict__ A0, const unsigned short* __restrict__ Wf,
    const float* __restrict__ bias, unsigned short* __restrict__ O0,
    int Cs, int AP, int Wimg, int OMS, int OP,
    int T, TapOffs toffs, int NTtot, int relu)
{
    int lane = threadIdx.x & 63, wave = threadIdx.x >> 6;
    int ml = lane & 15, kq = lane >> 4;
    int nb = blockIdx.y;
    const unsigned short* WbB = Wf + (size_t)(nb * 4) * 512 + lane * 8;

    int fy[MW], fx[MW];
    const unsigned short* Af[MW];
    #pragma unroll
    for (int f = 0; f < MW; ++f) {
        int mf = (blockIdx.x * 4 + wave) * (16 * MW) + f * 16;
        int y = mf / Wimg, x = mf - y * Wimg;
        fy[f] = y; fx[f] = x;
        Af[f] = A0 + (size_t)y * AP + (size_t)(x + ml) * Cs + kq * 8;
    }

    f32x4 acc[MW][4];
    #pragma unroll
    for (int f = 0; f < MW; ++f)
        #pragma unroll
        for (int nt = 0; nt < 4; ++nt) acc[f][nt] = (f32x4){0.f, 0.f, 0.f, 0.f};

    for (int tp = 0; tp < T; ++tp) {
        int toff = toffs.o[tp];
        const unsigned short* Wt = WbB + (size_t)(tp * KC) * NTtot * 512;
        #pragma unroll
        for (int q = 0; q < KC; ++q) {
            short8 b[4];
            #pragma unroll
            for (int nt = 0; nt < 4; ++nt)
                b[nt] = *(const short8*)(Wt + (size_t)q * NTtot * 512 + nt * 512);
            short8 a[MW];
            #pragma unroll
            for (int f = 0; f < MW; ++f)
                a[f] = *(const short8*)(Af[f] + toff + q * 32);
            #pragma unroll
            for (int f = 0; f < MW; ++f)
                #pragma unroll
                for (int nt = 0; nt < 4; ++nt)
                    acc[f][nt] = __builtin_amdgcn_mfma_f32_16x16x32_bf16(a[f], b[nt], acc[f][nt], 0, 0, 0);
        }
    }

    #pragma unroll
    for (int f = 0; f < MW; ++f) {
        unsigned short* Ot = O0 + (size_t)fy[f] * OP + (size_t)(fx[f] + kq * 4) * OMS + (size_t)nb * 64;
        #pragma unroll
        for (int nt = 0; nt < 4; ++nt) {
            float bv = bias[nb * 64 + nt * 16 + ml];
            #pragma unroll
            for (int r = 0; r < 4; ++r) {
                float v = acc[f][nt][r] + bv;
                if (relu) v = fmaxf(v, 0.f);
                Ot[(size_t)r * OMS + nt * 16 + ml] = f2bf(v);
            }
        }
    }
}

// ---------------------------------------------------------------------------
// Fused prologue: pad-ring zeroing + weight packing + conv1 im2col in ONE
// dispatch (three independent jobs, partitioned by global thread index).
// Saves 2 serial launch boundaries vs R13.
// ---------------------------------------------------------------------------
struct PrepArgs {
    // zero job
    int zoff[10]; int zcum[11]; int zW2[10]; int zH2[10]; int zCs[10]; int ztot;
    // pack job
    const float* w[15]; int pcum[16];
    int mode[15], KC[15], NT[15], K[15], N[15]; int ptot;
};
__global__ __launch_bounds__(TPB) void k_prep(
    PrepArgs pa, const float* __restrict__ x,
    unsigned short* __restrict__ W, unsigned short* __restrict__ packDst,
    unsigned short* __restrict__ xcol, int total)
{
    int idx = blockIdx.x * TPB + threadIdx.x;
    if (idx >= total) return;
    if (idx < pa.ztot) {
        // ---- pad-ring zero ----
        int local = idx;
        int e = 0;
        #pragma unroll
        for (int i = 1; i < 10; ++i) e += (local >= pa.zcum[i]);
        local -= pa.zcum[e];
        int W2 = pa.zW2[e], H2 = pa.zH2[e], Cs = pa.zCs[e];
        int topbot = 2 * W2 * Cs;
        int iy, ix, c;
        if (local < topbot) {
            int row = local / (W2 * Cs); int rest = local - row * (W2 * Cs);
            iy = row ? (H2 - 1) : 0; ix = rest / Cs; c = rest - (rest / Cs) * Cs;
        } else {
            int idx2 = local - topbot;
            int per = (H2 - 2) * Cs;
            int side = idx2 / per; int rest = idx2 - side * per;
            iy = 1 + rest / Cs; ix = side ? (W2 - 1) : 0; c = rest - (rest / Cs) * Cs;
        }
        W[(size_t)pa.zoff[e] + ((size_t)iy * W2 + ix) * Cs + c] = 0;
        return;
    }
    idx -= pa.ztot;
    if (idx < pa.ptot) {
        // ---- weight pack ----
        int e = 0;
        #pragma unroll
        for (int i = 1; i < 15; ++i) e += (idx >= pa.pcum[i]);
        int local = idx - pa.pcum[e];
        const float* w = pa.w[e];
        int KC = pa.KC[e], NT = pa.NT[e], K = pa.K[e], N = pa.N[e], mode = pa.mode[e];
        int j = local & 7, l = (local >> 3) & 63;
        int r = local >> 9;
        int ntg = r % NT; int r2 = r / NT;
        int q = r2 % KC; int tp = r2 / KC;
        int k = q * 32 + (l >> 4) * 8 + j;
        int n = ntg * 16 + (l & 15);
        float v = 0.f;
        if (mode == 0) { int ky = tp / 3, kx = tp % 3; v = w[(size_t)(n * K + k) * 9 + ky * 3 + kx]; }
        else if (mode == 1) { v = w[(size_t)k * N + n]; }
        else if (mode == 2) { v = w[((size_t)tp * K + k) * N + n]; }
        else { if (k < 27) { int tap = k / 3, c = k % 3; int ky = tap / 3, kx = tap % 3;
                             v = w[((n * 3 + c) * 3 + ky) * 3 + kx]; } }
        packDst[idx] = f2bf(v);
        return;
    }
    idx -= pa.ptot;
    // ---- conv1 im2col: x fp32 [3][256][256] -> xcol bf16 [65536][32] ----
    {
        int k = idx & 31, m = idx >> 5;
        int y = m >> 8, xx = m & 255;
        float v = 0.f;
        if (k < 27) {
            int tap = k / 3, c = k - tap * 3;
            int ty = tap / 3, tx = tap % 3;
            int yy = y + ty - 1, xp = xx + tx - 1;
            if (yy >= 0 && yy < 256 && xp >= 0 && xp < 256)
                v = x[c * 65536 + yy * 256 + xp];
        }
        xcol[idx] = f2bf(v);
    }
}

// ---------------- maxpool 2x2 channels-last (strided in/out) ----------------
__global__ __launch_bounds__(TPB) void k_maxpool(
    const unsigned short* __restrict__ inI, unsigned short* __restrict__ outI,
    int Wo, int C4, int CsIn, int inPitch, int CsOut, int outPitch, int total)
{
    int idx = blockIdx.x * TPB + threadIdx.x;
    if (idx >= total) return;
    int c4 = idx % C4; int p = idx / C4;
    int x = p % Wo, y = p / Wo;
    const unsigned short* ip = inI + (size_t)(2 * y) * inPitch + (size_t)(2 * x) * CsIn + c4 * 4;
    ushort4 a = *(const ushort4*)(ip);
    ushort4 b = *(const ushort4*)(ip + CsIn);
    ushort4 c = *(const ushort4*)(ip + inPitch);
    ushort4 d = *(const ushort4*)(ip + inPitch + CsIn);
    ushort4 o;
    o.x = f2bf(fmaxf(fmaxf(bf2f(a.x), bf2f(b.x)), fmaxf(bf2f(c.x), bf2f(d.x))));
    o.y = f2bf(fmaxf(fmaxf(bf2f(a.y), bf2f(b.y)), fmaxf(bf2f(c.y), bf2f(d.y))));
    o.z = f2bf(fmaxf(fmaxf(bf2f(a.z), bf2f(b.z)), fmaxf(bf2f(c.z), bf2f(d.z))));
    o.w = f2bf(fmaxf(fmaxf(bf2f(a.w), bf2f(b.w)), fmaxf(bf2f(c.w), bf2f(d.w))));
    *(ushort4*)(outI + (size_t)y * outPitch + (size_t)x * CsOut + c4 * 4) = o;
}

// ---------------- graph aggregation on 66x66 grid, node-major bf16 ----------
__global__ __launch_bounds__(TPB) void k_gagg(
    const unsigned short* __restrict__ X, unsigned short* __restrict__ agg,
    int C, int total)
{
    int idx = blockIdx.x * TPB + threadIdx.x;
    if (idx >= total) return;
    int C4 = C >> 2;
    int c4 = idx % C4; int n = idx / C4;
    int i = n / 66, j = n - i * 66;
    size_t base = (size_t)n * C + c4 * 4;
    ushort4 s = *(const ushort4*)(X + base);
    float v0 = bf2f(s.x), v1 = bf2f(s.y), v2 = bf2f(s.z), v3 = bf2f(s.w);
    float cnt = 1.f;
    if (i > 0)  { ushort4 u = *(const ushort4*)(X + base - (size_t)66 * C);
                  v0 += bf2f(u.x); v1 += bf2f(u.y); v2 += bf2f(u.z); v3 += bf2f(u.w); cnt += 1.f; }
    if (i < 65) { ushort4 u = *(const ushort4*)(X + base + (size_t)66 * C);
                  v0 += bf2f(u.x); v1 += bf2f(u.y); v2 += bf2f(u.z); v3 += bf2f(u.w); cnt += 1.f; }
    if (j > 0)  { ushort4 u = *(const ushort4*)(X + base - C);
                  v0 += bf2f(u.x); v1 += bf2f(u.y); v2 += bf2f(u.z); v3 += bf2f(u.w); cnt += 1.f; }
    if (j < 65) { ushort4 u = *(const ushort4*)(X + base + C);
                  v0 += bf2f(u.x); v1 += bf2f(u.y); v2 += bf2f(u.z); v3 += bf2f(u.w); cnt += 1.f; }
    float inv = 1.f / cnt;
    ushort4 o;
    o.x = f2bf(v0 * inv); o.y = f2bf(v1 * inv); o.z = f2bf(v2 * inv); o.w = f2bf(v3 * inv);
    *(ushort4*)(agg + base) = o;
}

// ---------------- final conv 64->1, fp32 out --------------------------------
__global__ __launch_bounds__(TPB) void k_outconv(
    const unsigned short* __restrict__ vI, const float* __restrict__ ow,
    const float* __restrict__ ob, float* __restrict__ out)
{
    __shared__ float wl[576];
    for (int i = threadIdx.x; i < 576; i += TPB) wl[i] = ow[i];
    __syncthreads();
    int p = blockIdx.x * TPB + threadIdx.x;
    int y = p >> 8, x = p & 255;
    float acc = ob[0];
    #pragma unroll
    for (int ky = 0; ky < 3; ++ky)
        #pragma unroll
        for (int kx = 0; kx < 3; ++kx) {
            const unsigned short* ip = vI + (size_t)((y + ky - 1) * 258 + (x + kx - 1)) * 64;
            int wb = ky * 3 + kx;
            for (int c = 0; c < 64; c += 4) {
                ushort4 uv = *(const ushort4*)(ip + c);
                acc += bf2f(uv.x) * wl[c * 9 + wb] + bf2f(uv.y) * wl[(c + 1) * 9 + wb]
                     + bf2f(uv.z) * wl[(c + 2) * 9 + wb] + bf2f(uv.w) * wl[(c + 3) * 9 + wb];
            }
        }
    out[p] = acc;
}

static inline TapOffs zero_toffs() { TapOffs t = {}; return t; }

extern "C" void kernel_launch(void* const* d_in, const int* in_sizes, int n_in,
                              void* d_out, int out_size, void* d_ws, size_t ws_size,
                              hipStream_t stream) {
    const float* x    = (const float*)d_in[0];
    const float* d1w1 = (const float*)d_in[1];  const float* d1b1 = (const float*)d_in[2];
    const float* d1w2 = (const float*)d_in[3];  const float* d1b2 = (const float*)d_in[4];
    const float* d2w1 = (const float*)d_in[5];  const float* d2b1 = (const float*)d_in[6];
    const float* d2w2 = (const float*)d_in[7];  const float* d2b2 = (const float*)d_in[8];
    const float* md1w = (const float*)d_in[9];  const float* md1b = (const float*)d_in[10];
    const float* md2w = (const float*)d_in[11]; const float* md2b = (const float*)d_in[12];
    const float* mbw  = (const float*)d_in[13]; const float* mbb  = (const float*)d_in[14];
    const float* mu1w = (const float*)d_in[15]; const float* mu1b = (const float*)d_in[16];
    const float* mu2w = (const float*)d_in[17]; const float* mu2b = (const float*)d_in[18];
    const float* u3tw = (const float*)d_in[19]; const float* u3tb = (const float*)d_in[20];
    const float* u3w1 = (const float*)d_in[21]; const float* u3b1 = (const float*)d_in[22];
    const float* u3w2 = (const float*)d_in[23]; const float* u3b2 = (const float*)d_in[24];
    const float* u4tw = (const float*)d_in[25]; const float* u4tb = (const float*)d_in[26];
    const float* u4w1 = (const float*)d_in[27]; const float* u4b1 = (const float*)d_in[28];
    const float* u4w2 = (const float*)d_in[29]; const float* u4b2 = (const float*)d_in[30];
    const float* ow   = (const float*)d_in[31]; const float* ob   = (const float*)d_in[32];
    float* out = (float*)d_out;

    unsigned short* W = (unsigned short*)d_ws;

    // ---- flat arena (elem offsets, bf16) ----
    const size_t XCOL = 0;          // 2,097,152
    const size_t A1   = 2097152;    // 258*258*64
    const size_t CAT4 = 6357248;    // 258*258*128
    const size_t P1   = 14877440;   // 130*130*64
    const size_t T2   = 15959040;   // 130*130*128
    const size_t CAT3 = 18122240;   // 130*130*256
    const size_t X0   = 22448640;   // 66*66*128
    const size_t BP1  = 23006208;   // 4608*256
    const size_t BP2  = 24185856;   // 4608*512
    const size_t XB   = 26545152;   // 4608*1024
    const size_t XC   = 31263744;   // 4608*512
    const size_t XD   = 33623040;   // 4608*256
    const size_t V3A  = 34802688;   // 130*130*128
    const size_t V3B  = 36965888;   // 130*130*128
    const size_t V4A  = 39129088;   // 258*258*64
    const size_t V4B  = 43389184;   // 258*258*64
    const size_t AGG  = 47649280;   // 4608*1024
    const size_t WP   = 52367872;   // packed weights 2,320,384

    const size_t a1I   = A1 + 259 * 64;
    const size_t cat4I = CAT4 + 259 * 128;
    const size_t p1I   = P1 + 131 * 64;
    const size_t t2I   = T2 + 131 * 128;
    const size_t cat3I = CAT3 + 131 * 256;
    const size_t X0I   = X0 + 67 * 128;
    const size_t XdI   = XD + 67 * 256;
    const size_t v3aI  = V3A + 131 * 128;
    const size_t v3bI  = V3B + 131 * 128;
    const size_t v4aI  = V4A + 259 * 64;
    const size_t v4bI  = V4B + 259 * 64;

    dim3 blk(TPB);
    const int BIG = 1 << 28;

    // ---- fused prologue: rings + pack + im2col in ONE dispatch ----
    {
        PrepArgs pa;
        const int off[10] = {(int)A1,(int)CAT4,(int)P1,(int)T2,(int)CAT3,(int)V3A,(int)V3B,(int)V4A,(int)V4B,(int)X0};
        const int w2 [10] = {258,258,130,130,130,130,130,258,258,66};
        const int h2 [10] = {258,258,130,130,130,130,130,258,258,66};
        const int cs [10] = {64,128,64,128,256,128,128,64,64,128};
        int zc = 0;
        for (int i = 0; i < 10; ++i) {
            pa.zoff[i]=off[i]; pa.zW2[i]=w2[i]; pa.zH2[i]=h2[i]; pa.zCs[i]=cs[i];
            pa.zcum[i]=zc; zc += (w2[i]*h2[i] - (w2[i]-2)*(h2[i]-2))*cs[i];
        }
        pa.zcum[10]=zc; pa.ztot=zc;

        const float* ws_[15] = {d1w1,d1w2,d2w1,d2w2,md1w,md2w,mbw,mu1w,mu2w,u3tw,u3w1,u3w2,u4tw,u4w1,u4w2};
        const int mode[15] = {3,0,0,0,1,1,1,1,1,2,0,0,2,0,0};
        const int kc [15] = {1,2,2,4,4,8,16,32,16,8,8,4,4,4,2};
        const int nt [15] = {4,4,8,8,16,32,64,32,16,8,8,8,4,4,4};
        const int kk [15] = {32,64,64,128,128,256,512,1024,512,256,256,128,128,128,64};
        const int nn [15] = {64,64,128,128,256,512,1024,512,256,128,128,128,64,64,64};
        const int tt [15] = {1,9,9,9,1,1,1,1,1,4,9,9,4,9,9};
        int pc = 0;
        for (int i = 0; i < 15; ++i) {
            pa.w[i]=ws_[i]; pa.mode[i]=mode[i]; pa.KC[i]=kc[i]; pa.NT[i]=nt[i];
            pa.K[i]=kk[i]; pa.N[i]=nn[i]; pa.pcum[i]=pc;
            pc += tt[i]*kc[i]*nt[i]*512;
        }
        pa.pcum[15]=pc; pa.ptot=pc;

        int total = zc + pc + 65536 * 32;
        k_prep<<<dim3((total + TPB - 1) / TPB), blk, 0, stream>>>(
            pa, x, W, W + WP, W + XCOL, total);
    }
    const size_t pw_d1w1=WP+0, pw_d1w2=WP+2048, pw_d2w1=WP+38912, pw_d2w2=WP+112640,
        pw_md1=WP+260096, pw_md2=WP+292864, pw_mb=WP+423936, pw_mu1=WP+948224,
        pw_mu2=WP+1472512, pw_u3t=WP+1603584, pw_u3w1=WP+1734656, pw_u3w2=WP+2029568,
        pw_u4t=WP+2177024, pw_u4w1=WP+2209792, pw_u4w2=WP+2283520;

    // ---- encoder ----
    k_gemm<2,1><<<dim3(512,1), blk, 0, stream>>>(W + XCOL, W + pw_d1w1, d1b1,
        W + a1I, 32, 8192, 256, 64, 258*64, 1, zero_toffs(), 4, 1);
    k_conv3w<1,2><<<dim3(512,1), blk, 0, stream>>>(W + a1I, W + pw_d1w2, d1b2,
        W + cat4I, 258*64, 2, 128, 258*128, 4);
    k_maxpool<<<dim3(1024), blk, 0, stream>>>(W + cat4I, W + p1I, 128, 16, 128, 258*128, 64, 130*64, 128*128*16);
    k_conv3w<1,1><<<dim3(256,2), blk, 0, stream>>>(W + p1I, W + pw_d2w1, d2b1,
        W + t2I, 130*64, 2, 128, 130*128, 8);
    k_conv3s<2,1><<<dim3(256,2), blk, 0, stream>>>(W + t2I, W + pw_d2w2, d2b2,
        W + cat3I, 130*128, 2, 256, 130*256, 8);
    k_maxpool<<<dim3(512), blk, 0, stream>>>(W + cat3I, W + X0I, 64, 32, 256, 130*256, 128, 66*128, 64*64*32);

    // ---- GNN on 66x66 padded grid (separate gagg + K-split GEMMs) ----
    k_gagg<<<dim3(545), blk, 0, stream>>>(W + X0, W + AGG, 128, 4356*32);
    k_gemmS<1><<<dim3(72,4), blk, 0, stream>>>(W + AGG, W + pw_md1, md1b, nullptr,
        W + BP1, 16, 0, BIG, 256, 0, 1, 0, 0, 0);
    k_gagg<<<dim3(1089), blk, 0, stream>>>(W + BP1, W + AGG, 256, 4356*64);
    k_gemmS<2><<<dim3(72,8), blk, 0, stream>>>(W + AGG, W + pw_md2, md2b, nullptr,
        W + BP2, 32, 0, BIG, 512, 0, 1, 0, 0, 0);
    k_gagg<<<dim3(2178), blk, 0, stream>>>(W + BP2, W + AGG, 512, 4356*128);
    k_gemmS<4><<<dim3(72,16), blk, 0, stream>>>(W + AGG, W + pw_mb, mbb, nullptr,
        W + XB, 64, 0, BIG, 1024, 0, 1, 0, 0, 0);
    k_gagg<<<dim3(4356), blk, 0, stream>>>(W + XB, W + AGG, 1024, 4356*256);
    k_gemmS<8><<<dim3(72,8), blk, 0, stream>>>(W + AGG, W + pw_mu1, mu1b, W + BP2,
        W + XC, 32, 0, BIG, 512, 0, 1, 0, 0, 0);
    k_gagg<<<dim3(2178), blk, 0, stream>>>(W + XC, W + AGG, 512, 4356*128);
    k_gemmS<4><<<dim3(72,4), blk, 0, stream>>>(W + AGG, W + pw_mu2, mu2b, W + BP1,
        W + XD, 16, 0, BIG, 256, 0, 1, 0, 0, 0);

    // ---- decoder stage 3: convT (K-split, 4 taps via z) + 2 convs ----
    k_gemmS<2><<<dim3(64,2,4), blk, 0, stream>>>(W + XdI, W + pw_u3t, u3tb, nullptr,
        W + cat3I + 128, 8, 66*256, 64, 512, 2*130*256, 0, 1, 130*256, 256);
    k_conv3s<4,1><<<dim3(256,2), blk, 0, stream>>>(W + cat3I, W + pw_u3w1, u3b1,
        W + v3aI, 130*256, 2, 128, 130*128, 8);
    k_conv3s<2,1><<<dim3(256,2), blk, 0, stream>>>(W + v3aI, W + pw_u3w2, u3b2,
        W + v3bI, 130*128, 2, 128, 130*128, 8);

    // ---- decoder stage 4: convT (no-split, 4 taps via z) + 2 convs ----
    k_gemmN<4><<<dim3(256,1,4), blk, 0, stream>>>(W + v3bI, W + pw_u4t, u4tb,
        W + cat4I + 64, 128, 130*128, 128, 256, 2*258*128, 4, 0, 1, 258*128, 128);
    k_conv3s<2,2><<<dim3(512,1), blk, 0, stream>>>(W + cat4I, W + pw_u4w1, u4b1,
        W + v4aI, 258*128, 2, 64, 258*64, 4);
    k_conv3w<1,2><<<dim3(512,1), blk, 0, stream>>>(W + v4aI, W + pw_u4w2, u4b2,
        W + v4bI, 258*64, 2, 64, 258*64, 4);

    // ---- output conv 64->1, fp32 ----
    k_outconv<<<dim3(256), blk, 0, stream>>>(W + v4bI, ow, ob, out);
}